// Round 2
// baseline (372.554 us; speedup 1.0000x reference)
//
#include <hip/hip_runtime.h>
#include <hip/hip_bf16.h>

typedef __bf16 bf16_t;
typedef __bf16 bf16x8 __attribute__((ext_vector_type(8)));
typedef float floatx4 __attribute__((ext_vector_type(4)));
typedef unsigned int u32;

#define T_TOK 1024
#define DIM   1024
#define FF    512
#define NEXP  16

// ws layout
#define FLAG_OFF 0                 // int[6]
#define CNT_OFF  64                // int[16]
#define TOK_OFF  256               // int[16*1024], entry = token | (slot<<16)
#define SEL_OFF  65792             // int[1024*3] dense per-token expert ids
#define H_OFF    78080             // bf16[3072][512] (row = t*3+slot)
#define XBF_OFF  (H_OFF + (size_t)3072*512*2)   // bf16[1024][1024] = 2 MB
#define WS_NEED  (XBF_OFF + (size_t)T_TOK*DIM*2)

__device__ inline float swiglu(float g, float u) {
    float a = fminf(fmaxf(-g, -60.f), 60.f);
    return g * u / (1.0f + __expf(a));
}

__device__ __forceinline__ bf16x8 cvt8(float4 a, float4 b) {
    bf16x8 r;
    r[0]=(bf16_t)a.x; r[1]=(bf16_t)a.y; r[2]=(bf16_t)a.z; r[3]=(bf16_t)a.w;
    r[4]=(bf16_t)b.x; r[5]=(bf16_t)b.y; r[6]=(bf16_t)b.z; r[7]=(bf16_t)b.w;
    return r;
}

// compile-time-typed weight fragment: load raw now, convert at use
template<bool F32> struct Frag;
template<> struct Frag<true> {
    float4 a, b;
    __device__ __forceinline__ bf16x8 get() const { return cvt8(a, b); }
};
template<> struct Frag<false> {
    bf16x8 v;
    __device__ __forceinline__ bf16x8 get() const { return v; }
};
template<bool F32>
__device__ __forceinline__ Frag<F32> loadFrag(const void* base, size_t off) {
    Frag<F32> f;
    if constexpr (F32) {
        const float4* p = (const float4*)((const float*)base + off);
        f.a = p[0]; f.b = p[1];
    } else {
        f.v = *(const bf16x8*)((const bf16_t*)base + off);
    }
    return f;
}

// ---------------- per-input dtype detect (verified r4) ----------------
__global__ __launch_bounds__(64) void detect_kernel(
    const void* p0, const void* p1, const void* p2,
    const void* p3, const void* p4, const void* p5,
    int* __restrict__ flags)
{
    const void* ps[6] = {p0, p1, p2, p3, p4, p5};
    int j = blockIdx.x;
    int lane = threadIdx.x;
    const unsigned short* h = (const unsigned short*)ps[j];
    unsigned int bad = 0;
    for (int i = lane; i < 4096; i += 64) {
        unsigned int e = ((unsigned int)h[i] >> 7) & 0xFFu;
        if (e >= 0x90u) bad = 1;
    }
    unsigned long long b = __ballot(bad);
    if (lane == 0) flags[j] = (b != 0ull) ? 1 : 0;
}

// ---- runtime-typed loader (fallback only) ----
__device__ inline bf16x8 loadB8r(const void* base, size_t off, bool f32) {
    if (f32) {
        const float4* p = (const float4*)((const float*)base + off);
        float4 v0 = p[0], v1 = p[1];
        bf16x8 r;
        r[0]=(bf16_t)v0.x; r[1]=(bf16_t)v0.y; r[2]=(bf16_t)v0.z; r[3]=(bf16_t)v0.w;
        r[4]=(bf16_t)v1.x; r[5]=(bf16_t)v1.y; r[6]=(bf16_t)v1.z; r[7]=(bf16_t)v1.w;
        return r;
    } else {
        return *(const bf16x8*)((const bf16_t*)base + off);
    }
}

// ---------------- Router: 256 blocks x 4 tokens; no LDS staging, no atomics ----------------
__global__ __launch_bounds__(256) void router_kernel(
    const void* __restrict__ x,
    const void* __restrict__ w_out,   // [8,1024]
    const void* __restrict__ w_in,    // [16,1024]
    float* __restrict__ selw_out,     // [T,3] fp32
    const int* __restrict__ flags,
    int* __restrict__ sel_ids,        // [T,3] expert ids (dense)
    bf16_t* __restrict__ xb)          // optional bf16 copy of x
{
    const bool xf  = flags[0] != 0;
    const bool gof = flags[1] != 0;
    const bool gif = flags[2] != 0;
    const int tid = threadIdx.x;

    __shared__ float Ls[4][24];

    const int wave = tid >> 6, lane = tid & 63;
    const int t = blockIdx.x * 4 + wave;

    float xv[16];
    if (xf) {
        const float* xp = (const float*)x + (size_t)t * DIM;
        #pragma unroll
        for (int i = 0; i < 16; i++) xv[i] = xp[lane + 64 * i];
    } else {
        const bf16_t* xp = (const bf16_t*)x + (size_t)t * DIM;
        #pragma unroll
        for (int i = 0; i < 16; i++) xv[i] = (float)xp[lane + 64 * i];
    }

    if (xb) {
        #pragma unroll
        for (int i = 0; i < 16; i++)
            xb[(size_t)t * DIM + lane + 64 * i] = (bf16_t)xv[i];
    }

    for (int j = 0; j < 24; j++) {
        const void* gb; int row; bool gf;
        if (j < 8) { gb = w_out; row = j;     gf = gof; }
        else       { gb = w_in;  row = j - 8; gf = gif; }
        float s = 0.f;
        if (gf) {
            const float* gp = (const float*)gb + (size_t)row * DIM;
            #pragma unroll
            for (int i = 0; i < 16; i++) s += xv[i] * gp[lane + 64 * i];
        } else {
            const bf16_t* gp = (const bf16_t*)gb + (size_t)row * DIM;
            #pragma unroll
            for (int i = 0; i < 16; i++) s += xv[i] * (float)gp[lane + 64 * i];
        }
        #pragma unroll
        for (int m = 32; m >= 1; m >>= 1) s += __shfl_xor(s, m, 64);
        if (lane == 0) Ls[wave][j] = s;
    }

    if (lane == 0) {
        const float* logits = Ls[wave];
        float mx = logits[0];
        for (int o = 1; o < 8; o++) mx = fmaxf(mx, logits[o]);
        float p[8];
        for (int o = 0; o < 8; o++) p[o] = __expf(logits[o] - mx);
        int i0 = 0;
        for (int o = 1; o < 8; o++) if (logits[o] > logits[i0]) i0 = o;
        int i1 = (i0 == 0) ? 1 : 0;
        for (int o = 0; o < 8; o++) if (o != i0 && logits[o] > logits[i1]) i1 = o;
        float rsum = p[i0] + p[i1];
        float rw0 = p[i0] / rsum, rw1 = p[i1] / rsum;

        float a0 = logits[8 + i0 * 2], a1 = logits[8 + i0 * 2 + 1];
        int j00 = (a1 > a0) ? 1 : 0;
        float b0 = logits[8 + i1 * 2], b1 = logits[8 + i1 * 2 + 1];
        int j10 = (b1 > b0) ? 1 : 0;

        int   ids[3] = { i0 * 2 + j00, i0 * 2 + (1 - j00), i1 * 2 + j10 };
        float w[3]   = { rw0, rw0, rw1 };

        #pragma unroll
        for (int k = 0; k < 3; k++) {
            selw_out[t * 3 + k] = w[k];
            sel_ids[t * 3 + k]  = ids[k];
        }
    }
}

// ---------------- binning: 1 block, LDS atomics only ----------------
__global__ __launch_bounds__(1024) void bin_kernel(
    const int* __restrict__ sel_ids,
    int* __restrict__ cnt, int* __restrict__ tok_enc)
{
    __shared__ int lc[NEXP];
    const int tid = threadIdx.x;
    if (tid < NEXP) lc[tid] = 0;
    __syncthreads();
    #pragma unroll
    for (int k = 0; k < 3; k++) {
        int e = sel_ids[tid * 3 + k];
        if (e >= 0 && e < NEXP) {
            int pos = atomicAdd(&lc[e], 1);
            if (pos < T_TOK) tok_enc[e * T_TOK + pos] = tid | (k << 16);
        }
    }
    __syncthreads();
    if (tid < NEXP) cnt[tid] = lc[tid];
}

// ---- gate+up+SwiGLU -> H : grid (e, mt=8 x 128tok, ft=8 x 64f) ----
// No LDS tiles: A-frags direct from L2-resident xb, W-frags in registers
// with 1-chunk software pipeline. No barriers in the K-loop.
template<bool GF, bool UF>
__device__ __forceinline__ void gateup_body(
    const bf16_t* __restrict__ xb,
    const void* __restrict__ wg, const void* __restrict__ wu,
    const int* __restrict__ cnt, const int* __restrict__ tok_enc,
    bf16_t* __restrict__ H, int* toks, int* hrow)
{
    const int e = blockIdx.x, mt = blockIdx.y, ft = blockIdx.z;
    int C = cnt[e]; if (C > T_TOK) C = T_TOK; if (C < 0) C = 0;
    if (mt * 128 >= C) return;

    const int tid = threadIdx.x;
    if (tid < 128) {
        int idx = mt * 128 + tid, t = 0, hr = -1;
        if (idx < C) {
            int enc = tok_enc[e * T_TOK + idx];
            int tt = enc & 0xFFFF, kk = (enc >> 16) & 0xFFFF;
            if (tt < T_TOK && kk < 3) { t = tt; hr = tt * 3 + kk; }
        }
        toks[tid] = t; hrow[tid] = hr;
    }
    __syncthreads();

    const int wave = tid >> 6, lane = tid & 63;
    const int mh = wave >> 1, fh = wave & 1;
    const int rsel = lane & 15, kq = lane >> 4;
    const int mbase = mh * 64;
    const int f0 = ft * 64 + fh * 32;

    const bf16_t* arow[4];
    #pragma unroll
    for (int ms = 0; ms < 4; ms++)
        arow[ms] = xb + (size_t)toks[mbase + ms * 16 + rsel] * DIM + kq * 8;
    size_t wrow[2];
    #pragma unroll
    for (int nt = 0; nt < 2; nt++)
        wrow[nt] = (size_t)(e * FF + f0 + nt * 16 + rsel) * DIM + kq * 8;

    floatx4 ag[4][2], au[4][2];
    #pragma unroll
    for (int ms = 0; ms < 4; ms++)
        #pragma unroll
        for (int nt = 0; nt < 2; nt++) { ag[ms][nt] = (floatx4){0,0,0,0}; au[ms][nt] = (floatx4){0,0,0,0}; }

    bf16x8 Ac[4][2], Gc[2][2], Uc[2][2];
    {
        Frag<GF> tg[2][2]; Frag<UF> tu[2][2];
        #pragma unroll
        for (int nt = 0; nt < 2; nt++)
            #pragma unroll
            for (int i = 0; i < 2; i++) {
                tg[nt][i] = loadFrag<GF>(wg, wrow[nt] + i * 32);
                tu[nt][i] = loadFrag<UF>(wu, wrow[nt] + i * 32);
            }
        #pragma unroll
        for (int ms = 0; ms < 4; ms++)
            #pragma unroll
            for (int i = 0; i < 2; i++)
                Ac[ms][i] = *(const bf16x8*)(arow[ms] + i * 32);
        #pragma unroll
        for (int nt = 0; nt < 2; nt++)
            #pragma unroll
            for (int i = 0; i < 2; i++) { Gc[nt][i] = tg[nt][i].get(); Uc[nt][i] = tu[nt][i].get(); }
    }

    #pragma unroll
    for (int kc = 0; kc < 16; kc++) {
        bf16x8 An[4][2]; Frag<GF> tg[2][2]; Frag<UF> tu[2][2];
        if (kc < 15) {
            const int ko = (kc + 1) * 64;
            #pragma unroll
            for (int ms = 0; ms < 4; ms++)
                #pragma unroll
                for (int i = 0; i < 2; i++)
                    An[ms][i] = *(const bf16x8*)(arow[ms] + ko + i * 32);
            #pragma unroll
            for (int nt = 0; nt < 2; nt++)
                #pragma unroll
                for (int i = 0; i < 2; i++) {
                    tg[nt][i] = loadFrag<GF>(wg, wrow[nt] + ko + i * 32);
                    tu[nt][i] = loadFrag<UF>(wu, wrow[nt] + ko + i * 32);
                }
        }
        #pragma unroll
        for (int i = 0; i < 2; i++)
            #pragma unroll
            for (int ms = 0; ms < 4; ms++)
                #pragma unroll
                for (int nt = 0; nt < 2; nt++) {
                    ag[ms][nt] = __builtin_amdgcn_mfma_f32_16x16x32_bf16(Ac[ms][i], Gc[nt][i], ag[ms][nt], 0, 0, 0);
                    au[ms][nt] = __builtin_amdgcn_mfma_f32_16x16x32_bf16(Ac[ms][i], Uc[nt][i], au[ms][nt], 0, 0, 0);
                }
        if (kc < 15) {
            #pragma unroll
            for (int ms = 0; ms < 4; ms++)
                #pragma unroll
                for (int i = 0; i < 2; i++) Ac[ms][i] = An[ms][i];
            #pragma unroll
            for (int nt = 0; nt < 2; nt++)
                #pragma unroll
                for (int i = 0; i < 2; i++) { Gc[nt][i] = tg[nt][i].get(); Uc[nt][i] = tu[nt][i].get(); }
        }
    }

    #pragma unroll
    for (int ms = 0; ms < 4; ms++)
        #pragma unroll
        for (int nt = 0; nt < 2; nt++)
            #pragma unroll
            for (int r = 0; r < 4; r++) {
                int m = mbase + ms * 16 + kq * 4 + r;
                int hr = hrow[m];
                if (hr >= 0)
                    H[(size_t)hr * FF + f0 + nt * 16 + rsel] = (bf16_t)swiglu(ag[ms][nt][r], au[ms][nt][r]);
            }
}

__global__ __launch_bounds__(256, 2) void gateup_kernel(
    const bf16_t* __restrict__ xb,
    const void* __restrict__ wg, const void* __restrict__ wu,
    const int* __restrict__ flags, const int* __restrict__ cnt,
    const int* __restrict__ tok_enc, bf16_t* __restrict__ H)
{
    __shared__ int toks[128];
    __shared__ int hrow[128];
    const bool gf = flags[3] != 0, uf = flags[4] != 0;
    if (gf) {
        if (uf) gateup_body<true,  true >(xb, wg, wu, cnt, tok_enc, H, toks, hrow);
        else    gateup_body<true,  false>(xb, wg, wu, cnt, tok_enc, H, toks, hrow);
    } else {
        if (uf) gateup_body<false, true >(xb, wg, wu, cnt, tok_enc, H, toks, hrow);
        else    gateup_body<false, false>(xb, wg, wu, cnt, tok_enc, H, toks, hrow);
    }
}

// ---- down-proj + combine : grid (e, mt=16 x 64tok, dt=16 x 64d) ----
// A-frags direct from L2-resident H; W-frags register-pipelined; no LDS tiles.
template<bool DF>
__device__ __forceinline__ void down_body(
    const void* __restrict__ wd,
    const int* __restrict__ cnt, const int* __restrict__ tok_enc,
    const float* __restrict__ selw, const bf16_t* __restrict__ H,
    float* __restrict__ outp, int* toks, int* hrs, float* wts)
{
    const int e = blockIdx.x, mt = blockIdx.y, dt = blockIdx.z;
    int C = cnt[e]; if (C > T_TOK) C = T_TOK; if (C < 0) C = 0;
    if (mt * 64 >= C) return;

    const int tid = threadIdx.x;
    if (tid < 64) {
        int idx = mt * 64 + tid, t = -1, hr = 0; float w = 0.f;
        if (idx < C) {
            int enc = tok_enc[e * T_TOK + idx];
            int tt = enc & 0xFFFF, kk = (enc >> 16) & 0xFFFF;
            if (tt < T_TOK && kk < 3) { t = tt; hr = tt * 3 + kk; w = selw[tt * 3 + kk]; }
        }
        toks[tid] = t; hrs[tid] = hr; wts[tid] = w;
    }
    __syncthreads();

    const int wave = tid >> 6, lane = tid & 63;
    const int mh = wave >> 1, fh = wave & 1;
    const int rsel = lane & 15, kq = lane >> 4;
    const int mbase = mh * 32;
    const int d0 = dt * 64 + fh * 32;

    const bf16_t* arow[2];
    #pragma unroll
    for (int ms = 0; ms < 2; ms++)
        arow[ms] = H + (size_t)hrs[mbase + ms * 16 + rsel] * FF + kq * 8;
    size_t wrow[2];
    #pragma unroll
    for (int nt = 0; nt < 2; nt++)
        wrow[nt] = (size_t)(e * DIM + d0 + nt * 16 + rsel) * FF + kq * 8;

    floatx4 acc[2][2];
    #pragma unroll
    for (int ms = 0; ms < 2; ms++)
        #pragma unroll
        for (int nt = 0; nt < 2; nt++) acc[ms][nt] = (floatx4){0,0,0,0};

    bf16x8 Ac[2][2], Dc[2][2];
    {
        Frag<DF> td[2][2];
        #pragma unroll
        for (int nt = 0; nt < 2; nt++)
            #pragma unroll
            for (int i = 0; i < 2; i++) td[nt][i] = loadFrag<DF>(wd, wrow[nt] + i * 32);
        #pragma unroll
        for (int ms = 0; ms < 2; ms++)
            #pragma unroll
            for (int i = 0; i < 2; i++) Ac[ms][i] = *(const bf16x8*)(arow[ms] + i * 32);
        #pragma unroll
        for (int nt = 0; nt < 2; nt++)
            #pragma unroll
            for (int i = 0; i < 2; i++) Dc[nt][i] = td[nt][i].get();
    }

    #pragma unroll
    for (int kc = 0; kc < 8; kc++) {
        bf16x8 An[2][2]; Frag<DF> td[2][2];
        if (kc < 7) {
            const int ko = (kc + 1) * 64;
            #pragma unroll
            for (int ms = 0; ms < 2; ms++)
                #pragma unroll
                for (int i = 0; i < 2; i++)
                    An[ms][i] = *(const bf16x8*)(arow[ms] + ko + i * 32);
            #pragma unroll
            for (int nt = 0; nt < 2; nt++)
                #pragma unroll
                for (int i = 0; i < 2; i++)
                    td[nt][i] = loadFrag<DF>(wd, wrow[nt] + ko + i * 32);
        }
        #pragma unroll
        for (int i = 0; i < 2; i++)
            #pragma unroll
            for (int ms = 0; ms < 2; ms++)
                #pragma unroll
                for (int nt = 0; nt < 2; nt++)
                    acc[ms][nt] = __builtin_amdgcn_mfma_f32_16x16x32_bf16(Ac[ms][i], Dc[nt][i], acc[ms][nt], 0, 0, 0);
        if (kc < 7) {
            #pragma unroll
            for (int ms = 0; ms < 2; ms++)
                #pragma unroll
                for (int i = 0; i < 2; i++) Ac[ms][i] = An[ms][i];
            #pragma unroll
            for (int nt = 0; nt < 2; nt++)
                #pragma unroll
                for (int i = 0; i < 2; i++) Dc[nt][i] = td[nt][i].get();
        }
    }

    #pragma unroll
    for (int ms = 0; ms < 2; ms++)
        #pragma unroll
        for (int nt = 0; nt < 2; nt++)
            #pragma unroll
            for (int r = 0; r < 4; r++) {
                int m = mbase + ms * 16 + kq * 4 + r, t = toks[m];
                if (t >= 0)
                    atomicAdd(outp + (size_t)t * DIM + d0 + nt * 16 + rsel, acc[ms][nt][r] * wts[m]);
            }
}

__global__ __launch_bounds__(256, 2) void down_kernel(
    const void* __restrict__ wd,
    const int* __restrict__ flags, const int* __restrict__ cnt,
    const int* __restrict__ tok_enc,
    const float* __restrict__ selw, const bf16_t* __restrict__ H,
    float* __restrict__ outp)
{
    __shared__ int toks[64];
    __shared__ int hrs[64];
    __shared__ float wts[64];
    const bool df = flags[5] != 0;
    if (df) down_body<true >(wd, cnt, tok_enc, selw, H, outp, toks, hrs, wts);
    else    down_body<false>(wd, cnt, tok_enc, selw, H, outp, toks, hrs, wts);
}

// ---------------- fallback fused FFN (verified r4) ----------------
__global__ __launch_bounds__(256) void ffn_kernel(
    const void* __restrict__ x,
    const void* __restrict__ wg, const void* __restrict__ wu, const void* __restrict__ wd,
    const int* __restrict__ flags, const int* __restrict__ cnt, const int* __restrict__ tok_enc,
    const float* __restrict__ selw, float* __restrict__ outp)
{
    const int e = blockIdx.x, tile = blockIdx.y;
    int C = cnt[e]; if (C > T_TOK) C = T_TOK; if (C < 0) C = 0;
    if (tile * 16 >= C) return;
    const bool xf = flags[0] != 0, gf = flags[3] != 0, uf = flags[4] != 0, df = flags[5] != 0;

    __shared__ __align__(16) bf16_t Xs[16][1032];
    __shared__ __align__(16) bf16_t Hs[16][520];
    __shared__ int toks[16];
    __shared__ float wts[16];
    const int tid = threadIdx.x;
    if (tid < 16) {
        int idx = tile * 16 + tid, t = -1; float w = 0.f;
        if (idx < C) {
            int enc = tok_enc[e * T_TOK + idx];
            int tt = enc & 0xFFFF, kk = (enc >> 16) & 0xFFFF;
            if (tt < T_TOK && kk < 3) { t = tt; w = selw[tt * 3 + kk]; }
        }
        toks[tid] = t; wts[tid] = w;
    }
    __syncthreads();
    {
        int row = tid >> 4, chunk = tid & 15;
        int t = toks[row];
        bf16x8* dst = (bf16x8*)&Xs[row][chunk * 64];
        if (t >= 0) {
            #pragma unroll
            for (int i = 0; i < 8; i++)
                dst[i] = loadB8r(x, (size_t)t * DIM + chunk * 64 + i * 8, xf);
        } else {
            bf16x8 z;
            #pragma unroll
            for (int kz = 0; kz < 8; kz++) z[kz] = (bf16_t)0.0f;
            #pragma unroll
            for (int i = 0; i < 8; i++) dst[i] = z;
        }
    }
    __syncthreads();

    const int wave = tid >> 6, lane = tid & 63;
    const int rsel = lane & 15, kq = lane >> 4;
    const size_t eoffF = (size_t)e * FF * DIM;
    for (int nt = 0; nt < 8; nt++) {
        const int f0 = wave * 128 + nt * 16;
        const size_t boff = eoffF + (size_t)(f0 + rsel) * DIM + kq * 8;
        const bf16_t* ap = &Xs[rsel][kq * 8];
        floatx4 accg = {0.f,0.f,0.f,0.f};
        floatx4 accu = {0.f,0.f,0.f,0.f};
        for (int k0 = 0; k0 < DIM; k0 += 32) {
            bf16x8 a  = *(const bf16x8*)(ap + k0);
            bf16x8 bg = loadB8r(wg, boff + k0, gf);
            bf16x8 bu = loadB8r(wu, boff + k0, uf);
            accg = __builtin_amdgcn_mfma_f32_16x16x32_bf16(a, bg, accg, 0, 0, 0);
            accu = __builtin_amdgcn_mfma_f32_16x16x32_bf16(a, bu, accu, 0, 0, 0);
        }
        #pragma unroll
        for (int r = 0; r < 4; r++)
            Hs[kq * 4 + r][f0 + rsel] = (bf16_t)swiglu(accg[r], accu[r]);
    }
    __syncthreads();
    const size_t eoffD = (size_t)e * DIM * FF;
    for (int nt = 0; nt < 16; nt++) {
        const int d0 = wave * 256 + nt * 16;
        const size_t boff = eoffD + (size_t)(d0 + rsel) * FF + kq * 8;
        const bf16_t* ap = &Hs[rsel][kq * 8];
        floatx4 acc = {0.f,0.f,0.f,0.f};
        for (int k0 = 0; k0 < FF; k0 += 32) {
            bf16x8 a = *(const bf16x8*)(ap + k0);
            bf16x8 b = loadB8r(wd, boff + k0, df);
            acc = __builtin_amdgcn_mfma_f32_16x16x32_bf16(a, b, acc, 0, 0, 0);
        }
        #pragma unroll
        for (int r = 0; r < 4; r++) {
            int m = kq * 4 + r, t = toks[m];
            if (t >= 0) atomicAdd(outp + (size_t)t * DIM + d0 + rsel, acc[r] * wts[m]);
        }
    }
}

extern "C" void kernel_launch(void* const* d_in, const int* in_sizes, int n_in,
                              void* d_out, int out_size, void* d_ws, size_t ws_size,
                              hipStream_t stream)
{
    const void* x     = d_in[0];
    const void* w_out = d_in[1];
    const void* w_in  = d_in[2];
    const void* wg    = d_in[3];
    const void* wu    = d_in[4];
    const void* wd    = d_in[5];
    float* out  = (float*)d_out;
    float* selw = out + (size_t)T_TOK * DIM;

    char* ws = (char*)d_ws;
    int*    flags = (int*)(ws + FLAG_OFF);
    int*    cnt   = (int*)(ws + CNT_OFF);
    int*    tok   = (int*)(ws + TOK_OFF);
    int*    sel   = (int*)(ws + SEL_OFF);
    bf16_t* H     = (bf16_t*)(ws + H_OFF);
    bf16_t* xbf   = (bf16_t*)(ws + XBF_OFF);

    const bool full = ws_size >= (size_t)WS_NEED;

    hipMemsetAsync(out, 0, (size_t)T_TOK * DIM * sizeof(float), stream);

    detect_kernel<<<dim3(6), dim3(64), 0, stream>>>(x, w_out, w_in, wg, wu, wd, flags);

    router_kernel<<<dim3(T_TOK / 4), dim3(256), 0, stream>>>(
        x, w_out, w_in, selw, flags, sel, full ? xbf : (bf16_t*)nullptr);

    bin_kernel<<<dim3(1), dim3(1024), 0, stream>>>(sel, cnt, tok);

    if (full) {
        gateup_kernel<<<dim3(NEXP, 8, 8), dim3(256), 0, stream>>>(
            xbf, wg, wu, flags, cnt, tok, H);
        down_kernel<<<dim3(NEXP, 16, 16), dim3(256), 0, stream>>>(
            wd, flags, cnt, tok, selw, H, out);
    } else {
        ffn_kernel<<<dim3(NEXP, 64), dim3(256), 0, stream>>>(
            x, wg, wu, wd, flags, cnt, tok, selw, out);
    }
}

// Round 3
// 251.407 us; speedup vs baseline: 1.4819x; 1.4819x over previous
//
#include <hip/hip_runtime.h>
#include <hip/hip_bf16.h>

typedef __bf16 bf16_t;
typedef __bf16 bf16x4 __attribute__((ext_vector_type(4)));
typedef __bf16 bf16x8 __attribute__((ext_vector_type(8)));
typedef float floatx4 __attribute__((ext_vector_type(4)));
typedef unsigned int u32;

#define T_TOK 1024
#define DIM   1024
#define FF    512
#define NEXP  16

// ws layout
#define FLAG_OFF 0                 // int[6]
#define CNT_OFF  64                // int[16]
#define TOK_OFF  256               // int[16*1024], entry = token | (slot<<16)
#define SEL_OFF  65792             // int[1024*3] dense per-token expert ids
#define H_OFF    78080             // bf16[3072][512] (row = t*3+slot)
#define XBF_OFF  (H_OFF + (size_t)3072*512*2)   // bf16[1024][1024] = 2 MB
#define WS_NEED  (XBF_OFF + (size_t)T_TOK*DIM*2)

__device__ inline float swiglu(float g, float u) {
    float a = fminf(fmaxf(-g, -60.f), 60.f);
    return g * u / (1.0f + __expf(a));
}

// ---------------- per-input dtype detect (verified r4) ----------------
__global__ __launch_bounds__(64) void detect_kernel(
    const void* p0, const void* p1, const void* p2,
    const void* p3, const void* p4, const void* p5,
    int* __restrict__ flags)
{
    const void* ps[6] = {p0, p1, p2, p3, p4, p5};
    int j = blockIdx.x;
    int lane = threadIdx.x;
    const unsigned short* h = (const unsigned short*)ps[j];
    unsigned int bad = 0;
    for (int i = lane; i < 4096; i += 64) {
        unsigned int e = ((unsigned int)h[i] >> 7) & 0xFFu;
        if (e >= 0x90u) bad = 1;
    }
    unsigned long long b = __ballot(bad);
    if (lane == 0) flags[j] = (b != 0ull) ? 1 : 0;
}

// ---- runtime-typed loader (fallback only) ----
__device__ inline bf16x8 loadB8r(const void* base, size_t off, bool f32) {
    if (f32) {
        const float4* p = (const float4*)((const float*)base + off);
        float4 v0 = p[0], v1 = p[1];
        bf16x8 r;
        r[0]=(bf16_t)v0.x; r[1]=(bf16_t)v0.y; r[2]=(bf16_t)v0.z; r[3]=(bf16_t)v0.w;
        r[4]=(bf16_t)v1.x; r[5]=(bf16_t)v1.y; r[6]=(bf16_t)v1.z; r[7]=(bf16_t)v1.w;
        return r;
    } else {
        return *(const bf16x8*)((const bf16_t*)base + off);
    }
}

// ---------------- weight chunk staging: global -> reg -> (cvt) -> swizzled LDS ----
// LDS chunk layout: ROWS rows x 128 bf16 (256B row); 16B slot s of row r stored
// at slot s ^ (r & 15)  (T2 XOR swizzle; read side mirrors it).
template<int ROWS, bool F32>
__device__ __forceinline__ void w_issue(const void* w, size_t e0, int rstride, int tid,
                                        float4 (&f)[ROWS/8], bf16x8 (&h)[ROWS/16]) {
    if constexpr (F32) {
        const int r0 = tid >> 5, c = tid & 31;      // 8 rows per pass, 512B/row contiguous
        const float* p = (const float*)w;
        #pragma unroll
        for (int q = 0; q < ROWS/8; q++)
            f[q] = *(const float4*)(p + e0 + (size_t)(q*8 + r0) * rstride + c*4);
    } else {
        const int r0 = tid >> 4, c = tid & 15;      // 16 rows per pass, 256B/row contiguous
        const bf16_t* p = (const bf16_t*)w;
        #pragma unroll
        for (int q = 0; q < ROWS/16; q++)
            h[q] = *(const bf16x8*)(p + e0 + (size_t)(q*16 + r0) * rstride + c*8);
    }
}

template<int ROWS, bool F32>
__device__ __forceinline__ void w_commit(bf16_t* lb, int tid,
                                         const float4 (&f)[ROWS/8], const bf16x8 (&h)[ROWS/16]) {
    if constexpr (F32) {
        const int r0 = tid >> 5, c = tid & 31, b = c >> 1, hh = c & 1;
        #pragma unroll
        for (int q = 0; q < ROWS/8; q++) {
            int r = q*8 + r0;
            float4 v = f[q];
            bf16x4 t; t[0]=(bf16_t)v.x; t[1]=(bf16_t)v.y; t[2]=(bf16_t)v.z; t[3]=(bf16_t)v.w;
            *(bf16x4*)((char*)lb + r*256 + ((b ^ (r & 15)) << 4) + hh*8) = t;
        }
    } else {
        const int r0 = tid >> 4, c = tid & 15;
        #pragma unroll
        for (int q = 0; q < ROWS/16; q++) {
            int r = q*16 + r0;
            *(bf16x8*)((char*)lb + r*256 + ((c ^ (r & 15)) << 4)) = h[q];
        }
    }
}

// swizzled LDS read of one 16B B-fragment: row r, 16B-slot b (k = b*8..b*8+7)
__device__ __forceinline__ bf16x8 rdW(const bf16_t* lb, int r, int b) {
    return *(const bf16x8*)((const char*)lb + r*256 + ((b ^ (r & 15)) << 4));
}

// ---------------- Router: 256 blocks x 4 tokens; no atomics ----------------
__global__ __launch_bounds__(256) void router_kernel(
    const void* __restrict__ x,
    const void* __restrict__ w_out,   // [8,1024]
    const void* __restrict__ w_in,    // [16,1024]
    float* __restrict__ selw_out,     // [T,3] fp32
    const int* __restrict__ flags,
    int* __restrict__ sel_ids,        // [T,3] expert ids (dense)
    bf16_t* __restrict__ xb)          // optional bf16 copy of x
{
    const bool xf  = flags[0] != 0;
    const bool gof = flags[1] != 0;
    const bool gif = flags[2] != 0;
    const int tid = threadIdx.x;

    __shared__ float Ls[4][24];

    const int wave = tid >> 6, lane = tid & 63;
    const int t = blockIdx.x * 4 + wave;

    float xv[16];
    if (xf) {
        const float* xp = (const float*)x + (size_t)t * DIM;
        #pragma unroll
        for (int i = 0; i < 16; i++) xv[i] = xp[lane + 64 * i];
    } else {
        const bf16_t* xp = (const bf16_t*)x + (size_t)t * DIM;
        #pragma unroll
        for (int i = 0; i < 16; i++) xv[i] = (float)xp[lane + 64 * i];
    }

    if (xb) {
        #pragma unroll
        for (int i = 0; i < 16; i++)
            xb[(size_t)t * DIM + lane + 64 * i] = (bf16_t)xv[i];
    }

    for (int j = 0; j < 24; j++) {
        const void* gb; int row; bool gf;
        if (j < 8) { gb = w_out; row = j;     gf = gof; }
        else       { gb = w_in;  row = j - 8; gf = gif; }
        float s = 0.f;
        if (gf) {
            const float* gp = (const float*)gb + (size_t)row * DIM;
            #pragma unroll
            for (int i = 0; i < 16; i++) s += xv[i] * gp[lane + 64 * i];
        } else {
            const bf16_t* gp = (const bf16_t*)gb + (size_t)row * DIM;
            #pragma unroll
            for (int i = 0; i < 16; i++) s += xv[i] * (float)gp[lane + 64 * i];
        }
        #pragma unroll
        for (int m = 32; m >= 1; m >>= 1) s += __shfl_xor(s, m, 64);
        if (lane == 0) Ls[wave][j] = s;
    }

    if (lane == 0) {
        const float* logits = Ls[wave];
        float mx = logits[0];
        for (int o = 1; o < 8; o++) mx = fmaxf(mx, logits[o]);
        float p[8];
        for (int o = 0; o < 8; o++) p[o] = __expf(logits[o] - mx);
        int i0 = 0;
        for (int o = 1; o < 8; o++) if (logits[o] > logits[i0]) i0 = o;
        int i1 = (i0 == 0) ? 1 : 0;
        for (int o = 0; o < 8; o++) if (o != i0 && logits[o] > logits[i1]) i1 = o;
        float rsum = p[i0] + p[i1];
        float rw0 = p[i0] / rsum, rw1 = p[i1] / rsum;

        float a0 = logits[8 + i0 * 2], a1 = logits[8 + i0 * 2 + 1];
        int j00 = (a1 > a0) ? 1 : 0;
        float b0 = logits[8 + i1 * 2], b1 = logits[8 + i1 * 2 + 1];
        int j10 = (b1 > b0) ? 1 : 0;

        int   ids[3] = { i0 * 2 + j00, i0 * 2 + (1 - j00), i1 * 2 + j10 };
        float w[3]   = { rw0, rw0, rw1 };

        #pragma unroll
        for (int k = 0; k < 3; k++) {
            selw_out[t * 3 + k] = w[k];
            sel_ids[t * 3 + k]  = ids[k];
        }
    }
}

// ---------------- binning: 1 block, LDS atomics only ----------------
__global__ __launch_bounds__(1024) void bin_kernel(
    const int* __restrict__ sel_ids,
    int* __restrict__ cnt, int* __restrict__ tok_enc)
{
    __shared__ int lc[NEXP];
    const int tid = threadIdx.x;
    if (tid < NEXP) lc[tid] = 0;
    __syncthreads();
    #pragma unroll
    for (int k = 0; k < 3; k++) {
        int e = sel_ids[tid * 3 + k];
        if (e >= 0 && e < NEXP) {
            int pos = atomicAdd(&lc[e], 1);
            if (pos < T_TOK) tok_enc[e * T_TOK + pos] = tid | (k << 16);
        }
    }
    __syncthreads();
    if (tid < NEXP) cnt[tid] = lc[tid];
}

// ---- gate+up+SwiGLU -> H : grid (ft=16 x 32f, mt=8 x 128tok, e=16) ----
// W chunk (both mats) shared block-wide via swizzled LDS dbuf (each W byte
// read from cache exactly once per block); A per-lane from L2-hot xb.
template<bool GF, bool UF>
__device__ __forceinline__ void gateup_body(
    const bf16_t* __restrict__ xb,
    const void* __restrict__ wg, const void* __restrict__ wu,
    const int* __restrict__ cnt, const int* __restrict__ tok_enc,
    bf16_t* __restrict__ H, bf16_t* Wl /*[2][2][32*128]*/, int* toks, int* hrow)
{
    const int ft = blockIdx.x, mt = blockIdx.y, e = blockIdx.z;
    int C = cnt[e]; if (C > T_TOK) C = T_TOK; if (C < 0) C = 0;
    if (mt * 128 >= C) return;

    const int tid = threadIdx.x;
    if (tid < 128) {
        int idx = mt * 128 + tid, t = 0, hr = -1;
        if (idx < C) {
            int enc = tok_enc[e * T_TOK + idx];
            int tt = enc & 0xFFFF, kk = (enc >> 16) & 0xFFFF;
            if (tt < T_TOK && kk < 3) { t = tt; hr = tt * 3 + kk; }
        }
        toks[tid] = t; hrow[tid] = hr;
    }
    __syncthreads();

    const int wave = tid >> 6, lane = tid & 63;
    const int mh = wave >> 1, fh = wave & 1;
    const int rsel = lane & 15, kq = lane >> 4;

    const size_t w0 = ((size_t)e * FF + (size_t)ft * 32) * DIM;
    const bf16_t* arow[4];
    #pragma unroll
    for (int ms = 0; ms < 4; ms++)
        arow[ms] = xb + (size_t)toks[mh * 64 + ms * 16 + rsel] * DIM + kq * 8;

    float4 fg[4], fu[4]; bf16x8 hg[2], hu[2];
    w_issue<32, GF>(wg, w0, DIM, tid, fg, hg);
    w_issue<32, UF>(wu, w0, DIM, tid, fu, hu);
    w_commit<32, GF>(Wl + 0 * 4096, tid, fg, hg);
    w_commit<32, UF>(Wl + 1 * 4096, tid, fu, hu);

    floatx4 ag[4], au[4];
    #pragma unroll
    for (int ms = 0; ms < 4; ms++) { ag[ms] = (floatx4){0,0,0,0}; au[ms] = (floatx4){0,0,0,0}; }

    __syncthreads();

    for (int kc = 0; kc < 8; kc++) {
        if (kc < 7) {
            w_issue<32, GF>(wg, w0 + (kc + 1) * 128, DIM, tid, fg, hg);
            w_issue<32, UF>(wu, w0 + (kc + 1) * 128, DIM, tid, fu, hu);
        }
        bf16x8 Ac[4][4];
        #pragma unroll
        for (int ms = 0; ms < 4; ms++)
            #pragma unroll
            for (int i = 0; i < 4; i++)
                Ac[ms][i] = *(const bf16x8*)(arow[ms] + kc * 128 + i * 32);

        const bf16_t* Lg = Wl + ((kc & 1) * 2 + 0) * 4096;
        const bf16_t* Lu = Wl + ((kc & 1) * 2 + 1) * 4096;
        const int brow = fh * 16 + rsel;
        #pragma unroll
        for (int i = 0; i < 4; i++) {
            bf16x8 bg = rdW(Lg, brow, i * 4 + kq);
            bf16x8 bu = rdW(Lu, brow, i * 4 + kq);
            #pragma unroll
            for (int ms = 0; ms < 4; ms++) {
                ag[ms] = __builtin_amdgcn_mfma_f32_16x16x32_bf16(Ac[ms][i], bg, ag[ms], 0, 0, 0);
                au[ms] = __builtin_amdgcn_mfma_f32_16x16x32_bf16(Ac[ms][i], bu, au[ms], 0, 0, 0);
            }
        }
        if (kc < 7) {
            w_commit<32, GF>(Wl + (((kc + 1) & 1) * 2 + 0) * 4096, tid, fg, hg);
            w_commit<32, UF>(Wl + (((kc + 1) & 1) * 2 + 1) * 4096, tid, fu, hu);
        }
        __syncthreads();
    }

    const int f = ft * 32 + fh * 16 + rsel;
    #pragma unroll
    for (int ms = 0; ms < 4; ms++)
        #pragma unroll
        for (int r = 0; r < 4; r++) {
            int m = mh * 64 + ms * 16 + kq * 4 + r;
            int hr = hrow[m];
            if (hr >= 0)
                H[(size_t)hr * FF + f] = (bf16_t)swiglu(ag[ms][r], au[ms][r]);
        }
}

__global__ __launch_bounds__(256, 2) void gateup_kernel(
    const bf16_t* __restrict__ xb,
    const void* __restrict__ wg, const void* __restrict__ wu,
    const int* __restrict__ flags, const int* __restrict__ cnt,
    const int* __restrict__ tok_enc, bf16_t* __restrict__ H)
{
    __shared__ __align__(16) bf16_t Wl[2 * 2 * 32 * 128];   // 32 KB
    __shared__ int toks[128];
    __shared__ int hrow[128];
    const bool gf = flags[3] != 0, uf = flags[4] != 0;
    if (gf) {
        if (uf) gateup_body<true,  true >(xb, wg, wu, cnt, tok_enc, H, Wl, toks, hrow);
        else    gateup_body<true,  false>(xb, wg, wu, cnt, tok_enc, H, Wl, toks, hrow);
    } else {
        if (uf) gateup_body<false, true >(xb, wg, wu, cnt, tok_enc, H, Wl, toks, hrow);
        else    gateup_body<false, false>(xb, wg, wu, cnt, tok_enc, H, Wl, toks, hrow);
    }
}

// ---- down-proj + combine : grid (dt=16 x 64d, mt=8 x 128tok, e=16) ----
template<bool DF>
__device__ __forceinline__ void down_body(
    const void* __restrict__ wd,
    const int* __restrict__ cnt, const int* __restrict__ tok_enc,
    const float* __restrict__ selw, const bf16_t* __restrict__ H,
    float* __restrict__ outp, bf16_t* Wl /*[2][64*128]*/,
    int* toks, int* hrs, float* wts)
{
    const int dt = blockIdx.x, mt = blockIdx.y, e = blockIdx.z;
    int C = cnt[e]; if (C > T_TOK) C = T_TOK; if (C < 0) C = 0;
    if (mt * 128 >= C) return;

    const int tid = threadIdx.x;
    if (tid < 128) {
        int idx = mt * 128 + tid, t = -1, hr = 0; float w = 0.f;
        if (idx < C) {
            int enc = tok_enc[e * T_TOK + idx];
            int tt = enc & 0xFFFF, kk = (enc >> 16) & 0xFFFF;
            if (tt < T_TOK && kk < 3) { t = tt; hr = tt * 3 + kk; w = selw[tt * 3 + kk]; }
        }
        toks[tid] = t; hrs[tid] = hr; wts[tid] = w;
    }
    __syncthreads();

    const int wave = tid >> 6, lane = tid & 63;
    const int mh = wave >> 1, fh = wave & 1;
    const int rsel = lane & 15, kq = lane >> 4;

    const size_t w0 = ((size_t)e * DIM + (size_t)dt * 64) * FF;
    const bf16_t* arow[4];
    #pragma unroll
    for (int ms = 0; ms < 4; ms++)
        arow[ms] = H + (size_t)hrs[mh * 64 + ms * 16 + rsel] * FF + kq * 8;

    float4 fd[8]; bf16x8 hd[4];
    w_issue<64, DF>(wd, w0, FF, tid, fd, hd);
    w_commit<64, DF>(Wl, tid, fd, hd);

    floatx4 acc[4][2];
    #pragma unroll
    for (int ms = 0; ms < 4; ms++)
        #pragma unroll
        for (int nt = 0; nt < 2; nt++) acc[ms][nt] = (floatx4){0,0,0,0};

    __syncthreads();

    for (int kc = 0; kc < 4; kc++) {
        if (kc < 3)
            w_issue<64, DF>(wd, w0 + (kc + 1) * 128, FF, tid, fd, hd);

        bf16x8 Ac[4][4];
        #pragma unroll
        for (int ms = 0; ms < 4; ms++)
            #pragma unroll
            for (int i = 0; i < 4; i++)
                Ac[ms][i] = *(const bf16x8*)(arow[ms] + kc * 128 + i * 32);

        const bf16_t* Lb = Wl + (kc & 1) * 8192;
        #pragma unroll
        for (int i = 0; i < 4; i++) {
            bf16x8 bd[2];
            #pragma unroll
            for (int nt = 0; nt < 2; nt++)
                bd[nt] = rdW(Lb, fh * 32 + nt * 16 + rsel, i * 4 + kq);
            #pragma unroll
            for (int ms = 0; ms < 4; ms++)
                #pragma unroll
                for (int nt = 0; nt < 2; nt++)
                    acc[ms][nt] = __builtin_amdgcn_mfma_f32_16x16x32_bf16(Ac[ms][i], bd[nt], acc[ms][nt], 0, 0, 0);
        }
        if (kc < 3)
            w_commit<64, DF>(Wl + ((kc + 1) & 1) * 8192, tid, fd, hd);
        __syncthreads();
    }

    const int d0 = dt * 64 + fh * 32;
    #pragma unroll
    for (int ms = 0; ms < 4; ms++)
        #pragma unroll
        for (int nt = 0; nt < 2; nt++)
            #pragma unroll
            for (int r = 0; r < 4; r++) {
                int m = mh * 64 + ms * 16 + kq * 4 + r, t = toks[m];
                if (t >= 0)
                    atomicAdd(outp + (size_t)t * DIM + d0 + nt * 16 + rsel, acc[ms][nt][r] * wts[m]);
            }
}

__global__ __launch_bounds__(256, 2) void down_kernel(
    const void* __restrict__ wd,
    const int* __restrict__ flags, const int* __restrict__ cnt,
    const int* __restrict__ tok_enc,
    const float* __restrict__ selw, const bf16_t* __restrict__ H,
    float* __restrict__ outp)
{
    __shared__ __align__(16) bf16_t Wl[2 * 64 * 128];   // 32 KB
    __shared__ int toks[128];
    __shared__ int hrs[128];
    __shared__ float wts[128];
    const bool df = flags[5] != 0;
    if (df) down_body<true >(wd, cnt, tok_enc, selw, H, outp, Wl, toks, hrs, wts);
    else    down_body<false>(wd, cnt, tok_enc, selw, H, outp, Wl, toks, hrs, wts);
}

// ---------------- fallback fused FFN (verified r4) ----------------
__global__ __launch_bounds__(256) void ffn_kernel(
    const void* __restrict__ x,
    const void* __restrict__ wg, const void* __restrict__ wu, const void* __restrict__ wd,
    const int* __restrict__ flags, const int* __restrict__ cnt, const int* __restrict__ tok_enc,
    const float* __restrict__ selw, float* __restrict__ outp)
{
    const int e = blockIdx.x, tile = blockIdx.y;
    int C = cnt[e]; if (C > T_TOK) C = T_TOK; if (C < 0) C = 0;
    if (tile * 16 >= C) return;
    const bool xf = flags[0] != 0, gf = flags[3] != 0, uf = flags[4] != 0, df = flags[5] != 0;

    __shared__ __align__(16) bf16_t Xs[16][1032];
    __shared__ __align__(16) bf16_t Hs[16][520];
    __shared__ int toks[16];
    __shared__ float wts[16];
    const int tid = threadIdx.x;
    if (tid < 16) {
        int idx = tile * 16 + tid, t = -1; float w = 0.f;
        if (idx < C) {
            int enc = tok_enc[e * T_TOK + idx];
            int tt = enc & 0xFFFF, kk = (enc >> 16) & 0xFFFF;
            if (tt < T_TOK && kk < 3) { t = tt; w = selw[tt * 3 + kk]; }
        }
        toks[tid] = t; wts[tid] = w;
    }
    __syncthreads();
    {
        int row = tid >> 4, chunk = tid & 15;
        int t = toks[row];
        bf16x8* dst = (bf16x8*)&Xs[row][chunk * 64];
        if (t >= 0) {
            #pragma unroll
            for (int i = 0; i < 8; i++)
                dst[i] = loadB8r(x, (size_t)t * DIM + chunk * 64 + i * 8, xf);
        } else {
            bf16x8 z;
            #pragma unroll
            for (int kz = 0; kz < 8; kz++) z[kz] = (bf16_t)0.0f;
            #pragma unroll
            for (int i = 0; i < 8; i++) dst[i] = z;
        }
    }
    __syncthreads();

    const int wave = tid >> 6, lane = tid & 63;
    const int rsel = lane & 15, kq = lane >> 4;
    const size_t eoffF = (size_t)e * FF * DIM;
    for (int nt = 0; nt < 8; nt++) {
        const int f0 = wave * 128 + nt * 16;
        const size_t boff = eoffF + (size_t)(f0 + rsel) * DIM + kq * 8;
        const bf16_t* ap = &Xs[rsel][kq * 8];
        floatx4 accg = {0.f,0.f,0.f,0.f};
        floatx4 accu = {0.f,0.f,0.f,0.f};
        for (int k0 = 0; k0 < DIM; k0 += 32) {
            bf16x8 a  = *(const bf16x8*)(ap + k0);
            bf16x8 bg = loadB8r(wg, boff + k0, gf);
            bf16x8 bu = loadB8r(wu, boff + k0, uf);
            accg = __builtin_amdgcn_mfma_f32_16x16x32_bf16(a, bg, accg, 0, 0, 0);
            accu = __builtin_amdgcn_mfma_f32_16x16x32_bf16(a, bu, accu, 0, 0, 0);
        }
        #pragma unroll
        for (int r = 0; r < 4; r++)
            Hs[kq * 4 + r][f0 + rsel] = (bf16_t)swiglu(accg[r], accu[r]);
    }
    __syncthreads();
    const size_t eoffD = (size_t)e * DIM * FF;
    for (int nt = 0; nt < 16; nt++) {
        const int d0 = wave * 256 + nt * 16;
        const size_t boff = eoffD + (size_t)(d0 + rsel) * FF + kq * 8;
        const bf16_t* ap = &Hs[rsel][kq * 8];
        floatx4 acc = {0.f,0.f,0.f,0.f};
        for (int k0 = 0; k0 < FF; k0 += 32) {
            bf16x8 a = *(const bf16x8*)(ap + k0);
            bf16x8 b = loadB8r(wd, boff + k0, df);
            acc = __builtin_amdgcn_mfma_f32_16x16x32_bf16(a, b, acc, 0, 0, 0);
        }
        #pragma unroll
        for (int r = 0; r < 4; r++) {
            int m = kq * 4 + r, t = toks[m];
            if (t >= 0) atomicAdd(outp + (size_t)t * DIM + d0 + rsel, acc[r] * wts[m]);
        }
    }
}

extern "C" void kernel_launch(void* const* d_in, const int* in_sizes, int n_in,
                              void* d_out, int out_size, void* d_ws, size_t ws_size,
                              hipStream_t stream)
{
    const void* x     = d_in[0];
    const void* w_out = d_in[1];
    const void* w_in  = d_in[2];
    const void* wg    = d_in[3];
    const void* wu    = d_in[4];
    const void* wd    = d_in[5];
    float* out  = (float*)d_out;
    float* selw = out + (size_t)T_TOK * DIM;

    char* ws = (char*)d_ws;
    int*    flags = (int*)(ws + FLAG_OFF);
    int*    cnt   = (int*)(ws + CNT_OFF);
    int*    tok   = (int*)(ws + TOK_OFF);
    int*    sel   = (int*)(ws + SEL_OFF);
    bf16_t* H     = (bf16_t*)(ws + H_OFF);
    bf16_t* xbf   = (bf16_t*)(ws + XBF_OFF);

    const bool full = ws_size >= (size_t)WS_NEED;

    hipMemsetAsync(out, 0, (size_t)T_TOK * DIM * sizeof(float), stream);

    detect_kernel<<<dim3(6), dim3(64), 0, stream>>>(x, w_out, w_in, wg, wu, wd, flags);

    router_kernel<<<dim3(T_TOK / 4), dim3(256), 0, stream>>>(
        x, w_out, w_in, selw, flags, sel, full ? xbf : (bf16_t*)nullptr);

    bin_kernel<<<dim3(1), dim3(1024), 0, stream>>>(sel, cnt, tok);

    if (full) {
        gateup_kernel<<<dim3(16, 8, 16), dim3(256), 0, stream>>>(
            xbf, wg, wu, flags, cnt, tok, H);
        down_kernel<<<dim3(16, 8, 16), dim3(256), 0, stream>>>(
            wd, flags, cnt, tok, selw, H, out);
    } else {
        ffn_kernel<<<dim3(NEXP, 64), dim3(256), 0, stream>>>(
            x, wg, wu, wd, flags, cnt, tok, selw, out);
    }
}

// Round 4
// 239.516 us; speedup vs baseline: 1.5554x; 1.0496x over previous
//
#include <hip/hip_runtime.h>
#include <hip/hip_bf16.h>

typedef __bf16 bf16_t;
typedef __bf16 bf16x4 __attribute__((ext_vector_type(4)));
typedef __bf16 bf16x8 __attribute__((ext_vector_type(8)));
typedef float floatx4 __attribute__((ext_vector_type(4)));
typedef unsigned int u32;

#define T_TOK 1024
#define DIM   1024
#define FF    512
#define NEXP  16

// ws layout
#define FLAG_OFF 0                 // int[6]
#define CNT_OFF  64                // int[16]
#define TOK_OFF  256               // int[16*1024]
#define SEL_OFF  65792             // int[1024*3]
#define H_OFF    78080             // bf16[3072][512]
#define XBF_OFF  (H_OFF + (size_t)3072*512*2)        // bf16 x  (2 MB)
#define WGB_OFF  (XBF_OFF + (size_t)T_TOK*DIM*2)     // bf16 wg (16 MB)
#define WUB_OFF  (WGB_OFF + (size_t)NEXP*FF*DIM*2)   // bf16 wu (16 MB)
#define WDB_OFF  (WUB_OFF + (size_t)NEXP*FF*DIM*2)   // bf16 wd (16 MB)
#define WS_FULL  (WDB_OFF + (size_t)NEXP*DIM*FF*2)
#define WS_MID   (WGB_OFF)

__device__ inline float swiglu(float g, float u) {
    float a = fminf(fmaxf(-g, -60.f), 60.f);
    return g * u / (1.0f + __expf(a));
}

// async 16B global->LDS; dst must be wave-uniform base (HW adds lane*16)
__device__ __forceinline__ void gload_lds16(const void* g, void* l) {
    __builtin_amdgcn_global_load_lds((const __attribute__((address_space(1))) u32*)g,
                                     (__attribute__((address_space(3))) u32*)l, 16, 0, 0);
}

__device__ __forceinline__ bf16x8 cvt8(float4 a, float4 b) {
    bf16x8 r;
    r[0]=(bf16_t)a.x; r[1]=(bf16_t)a.y; r[2]=(bf16_t)a.z; r[3]=(bf16_t)a.w;
    r[4]=(bf16_t)b.x; r[5]=(bf16_t)b.y; r[6]=(bf16_t)b.z; r[7]=(bf16_t)b.w;
    return r;
}

// swizzled LDS tile read: row stride 128 bf16, 16B slot q stored at q^(row&15)
__device__ __forceinline__ bf16x8 rd128(const bf16_t* L, int row, int q) {
    return *(const bf16x8*)(L + row * 128 + ((q ^ (row & 15)) << 3));
}

// ---------------- per-input dtype detect ----------------
__global__ __launch_bounds__(64) void detect_kernel(
    const void* p0, const void* p1, const void* p2,
    const void* p3, const void* p4, const void* p5,
    int* __restrict__ flags)
{
    const void* ps[6] = {p0, p1, p2, p3, p4, p5};
    int j = blockIdx.x;
    int lane = threadIdx.x;
    const unsigned short* h = (const unsigned short*)ps[j];
    unsigned int bad = 0;
    for (int i = lane; i < 4096; i += 64) {
        unsigned int e = ((unsigned int)h[i] >> 7) & 0xFFu;
        if (e >= 0x90u) bad = 1;
    }
    unsigned long long b = __ballot(bad);
    if (lane == 0) flags[j] = (b != 0ull) ? 1 : 0;
}

// ---------------- weight fp32 -> bf16 conversion (streaming) ----------------
__global__ __launch_bounds__(256) void wcvt_kernel(
    const void* __restrict__ wg, const void* __restrict__ wu, const void* __restrict__ wd,
    const int* __restrict__ flags,
    bf16_t* __restrict__ gb, bf16_t* __restrict__ ub, bf16_t* __restrict__ db)
{
    const int z = blockIdx.y;
    const void* src; bf16_t* dst; int f;
    if (z == 0)      { src = wg; dst = gb; f = flags[3]; }
    else if (z == 1) { src = wu; dst = ub; f = flags[4]; }
    else             { src = wd; dst = db; f = flags[5]; }
    if (!f) return;
    size_t i = ((size_t)blockIdx.x * 256 + threadIdx.x) * 8;
    const float4* p = (const float4*)((const float*)src + i);
    float4 a = p[0], b = p[1];
    *(bf16x8*)(dst + i) = cvt8(a, b);
}

// ---- runtime-typed loader (fallback only) ----
__device__ inline bf16x8 loadB8r(const void* base, size_t off, bool f32) {
    if (f32) {
        const float4* p = (const float4*)((const float*)base + off);
        float4 v0 = p[0], v1 = p[1];
        return cvt8(v0, v1);
    } else {
        return *(const bf16x8*)((const bf16_t*)base + off);
    }
}

// ---------------- Router ----------------
__global__ __launch_bounds__(256) void router_kernel(
    const void* __restrict__ x,
    const void* __restrict__ w_out,
    const void* __restrict__ w_in,
    float* __restrict__ selw_out,
    const int* __restrict__ flags,
    int* __restrict__ sel_ids,
    bf16_t* __restrict__ xb)
{
    const bool xf  = flags[0] != 0;
    const bool gof = flags[1] != 0;
    const bool gif = flags[2] != 0;
    const int tid = threadIdx.x;

    __shared__ float Ls[4][24];

    const int wave = tid >> 6, lane = tid & 63;
    const int t = blockIdx.x * 4 + wave;

    float xv[16];
    if (xf) {
        const float* xp = (const float*)x + (size_t)t * DIM;
        #pragma unroll
        for (int i = 0; i < 16; i++) xv[i] = xp[lane + 64 * i];
    } else {
        const bf16_t* xp = (const bf16_t*)x + (size_t)t * DIM;
        #pragma unroll
        for (int i = 0; i < 16; i++) xv[i] = (float)xp[lane + 64 * i];
    }

    if (xb) {
        #pragma unroll
        for (int i = 0; i < 16; i++)
            xb[(size_t)t * DIM + lane + 64 * i] = (bf16_t)xv[i];
    }

    for (int j = 0; j < 24; j++) {
        const void* gb; int row; bool gf;
        if (j < 8) { gb = w_out; row = j;     gf = gof; }
        else       { gb = w_in;  row = j - 8; gf = gif; }
        float s = 0.f;
        if (gf) {
            const float* gp = (const float*)gb + (size_t)row * DIM;
            #pragma unroll
            for (int i = 0; i < 16; i++) s += xv[i] * gp[lane + 64 * i];
        } else {
            const bf16_t* gp = (const bf16_t*)gb + (size_t)row * DIM;
            #pragma unroll
            for (int i = 0; i < 16; i++) s += xv[i] * (float)gp[lane + 64 * i];
        }
        #pragma unroll
        for (int m = 32; m >= 1; m >>= 1) s += __shfl_xor(s, m, 64);
        if (lane == 0) Ls[wave][j] = s;
    }

    if (lane == 0) {
        const float* logits = Ls[wave];
        float mx = logits[0];
        for (int o = 1; o < 8; o++) mx = fmaxf(mx, logits[o]);
        float p[8];
        for (int o = 0; o < 8; o++) p[o] = __expf(logits[o] - mx);
        int i0 = 0;
        for (int o = 1; o < 8; o++) if (logits[o] > logits[i0]) i0 = o;
        int i1 = (i0 == 0) ? 1 : 0;
        for (int o = 0; o < 8; o++) if (o != i0 && logits[o] > logits[i1]) i1 = o;
        float rsum = p[i0] + p[i1];
        float rw0 = p[i0] / rsum, rw1 = p[i1] / rsum;

        float a0 = logits[8 + i0 * 2], a1 = logits[8 + i0 * 2 + 1];
        int j00 = (a1 > a0) ? 1 : 0;
        float b0 = logits[8 + i1 * 2], b1 = logits[8 + i1 * 2 + 1];
        int j10 = (b1 > b0) ? 1 : 0;

        int   ids[3] = { i0 * 2 + j00, i0 * 2 + (1 - j00), i1 * 2 + j10 };
        float w[3]   = { rw0, rw0, rw1 };

        #pragma unroll
        for (int k = 0; k < 3; k++) {
            selw_out[t * 3 + k] = w[k];
            sel_ids[t * 3 + k]  = ids[k];
        }
    }
}

// ---------------- binning: 1 block, LDS atomics ----------------
__global__ __launch_bounds__(1024) void bin_kernel(
    const int* __restrict__ sel_ids,
    int* __restrict__ cnt, int* __restrict__ tok_enc)
{
    __shared__ int lc[NEXP];
    const int tid = threadIdx.x;
    if (tid < NEXP) lc[tid] = 0;
    __syncthreads();
    #pragma unroll
    for (int k = 0; k < 3; k++) {
        int e = sel_ids[tid * 3 + k];
        if (e >= 0 && e < NEXP) {
            int pos = atomicAdd(&lc[e], 1);
            if (pos < T_TOK) tok_enc[e * T_TOK + pos] = tid | (k << 16);
        }
    }
    __syncthreads();
    if (tid < NEXP) cnt[tid] = lc[tid];
}

// ================= FULL path: all-DMA MFMA kernels (bf16 weights) =================

// gate+up -> H : grid (ft=8 x 64f, mt=8 x 128tok, e=16); 4 waves (2m x 2f)
__global__ __launch_bounds__(256, 1) void gateup2_kernel(
    const bf16_t* __restrict__ xb,
    const void* __restrict__ wg, const void* __restrict__ wu,
    const bf16_t* __restrict__ wgb, const bf16_t* __restrict__ wub,
    const int* __restrict__ flags, const int* __restrict__ cnt,
    const int* __restrict__ tok_enc, bf16_t* __restrict__ H)
{
    __shared__ __align__(16) bf16_t Xs[2][128 * 128];   // 64 KB
    __shared__ __align__(16) bf16_t Gs[2][64 * 128];    // 32 KB
    __shared__ __align__(16) bf16_t Us[2][64 * 128];    // 32 KB
    __shared__ int toks[128];
    __shared__ int hrow[128];

    const int ft = blockIdx.x, mt = blockIdx.y, e = blockIdx.z;
    int C = cnt[e]; if (C > T_TOK) C = T_TOK; if (C < 0) C = 0;
    if (mt * 128 >= C) return;

    const bf16_t* wgp = (flags[3] != 0) ? wgb : (const bf16_t*)wg;
    const bf16_t* wup = (flags[4] != 0) ? wub : (const bf16_t*)wu;

    const int tid = threadIdx.x;
    if (tid < 128) {
        int idx = mt * 128 + tid, t = 0, hr = -1;
        if (idx < C) {
            int enc = tok_enc[e * T_TOK + idx];
            int tt = enc & 0xFFFF, kk = (enc >> 16) & 0xFFFF;
            if (tt < T_TOK && kk < 3) { t = tt; hr = tt * 3 + kk; }
        }
        toks[tid] = t; hrow[tid] = hr;
    }
    __syncthreads();

    const int wave = tid >> 6, lane = tid & 63;
    const int mh = wave >> 1, fh = wave & 1;
    const int rsel = lane & 15, kq = lane >> 4;

    // per-lane inverse-swizzled source pointers (dst is linear DMA)
    const bf16_t* sx[8];
    #pragma unroll
    for (int j = 0; j < 8; j++) {
        int n = (wave * 8 + j) * 64 + lane, r = n >> 4, s = n & 15;
        sx[j] = xb + (size_t)toks[r] * DIM + ((s ^ (r & 15)) << 3);
    }
    const bf16_t* sg[4]; const bf16_t* su[4];
    #pragma unroll
    for (int j = 0; j < 4; j++) {
        int n = (wave * 4 + j) * 64 + lane, r = n >> 4, s = n & 15;
        size_t off = (size_t)(e * FF + ft * 64 + r) * DIM + ((s ^ (r & 15)) << 3);
        sg[j] = wgp + off; su[j] = wup + off;
    }

    // stage chunk 0
    #pragma unroll
    for (int j = 0; j < 8; j++) gload_lds16(sx[j], &Xs[0][(wave * 8 + j) * 512]);
    #pragma unroll
    for (int j = 0; j < 4; j++) gload_lds16(sg[j], &Gs[0][(wave * 4 + j) * 512]);
    #pragma unroll
    for (int j = 0; j < 4; j++) gload_lds16(su[j], &Us[0][(wave * 4 + j) * 512]);

    floatx4 ag[4][2], au[4][2];
    #pragma unroll
    for (int ms = 0; ms < 4; ms++)
        #pragma unroll
        for (int nt = 0; nt < 2; nt++) { ag[ms][nt] = (floatx4){0,0,0,0}; au[ms][nt] = (floatx4){0,0,0,0}; }

    __syncthreads();

    for (int kc = 0; kc < 8; kc++) {
        if (kc < 7) {
            const int b = (kc + 1) & 1, ko = (kc + 1) * 128;
            #pragma unroll
            for (int j = 0; j < 8; j++) gload_lds16(sx[j] + ko, &Xs[b][(wave * 8 + j) * 512]);
            #pragma unroll
            for (int j = 0; j < 4; j++) gload_lds16(sg[j] + ko, &Gs[b][(wave * 4 + j) * 512]);
            #pragma unroll
            for (int j = 0; j < 4; j++) gload_lds16(su[j] + ko, &Us[b][(wave * 4 + j) * 512]);
        }
        const bf16_t* X = Xs[kc & 1];
        const bf16_t* G = Gs[kc & 1];
        const bf16_t* U = Us[kc & 1];
        #pragma unroll
        for (int i = 0; i < 4; i++) {
            const int q = i * 4 + kq;
            bf16x8 a[4], bg[2], bu[2];
            #pragma unroll
            for (int ms = 0; ms < 4; ms++) a[ms] = rd128(X, mh * 64 + ms * 16 + rsel, q);
            #pragma unroll
            for (int nt = 0; nt < 2; nt++) {
                bg[nt] = rd128(G, fh * 32 + nt * 16 + rsel, q);
                bu[nt] = rd128(U, fh * 32 + nt * 16 + rsel, q);
            }
            #pragma unroll
            for (int ms = 0; ms < 4; ms++)
                #pragma unroll
                for (int nt = 0; nt < 2; nt++) {
                    ag[ms][nt] = __builtin_amdgcn_mfma_f32_16x16x32_bf16(a[ms], bg[nt], ag[ms][nt], 0, 0, 0);
                    au[ms][nt] = __builtin_amdgcn_mfma_f32_16x16x32_bf16(a[ms], bu[nt], au[ms][nt], 0, 0, 0);
                }
        }
        __syncthreads();
    }

    #pragma unroll
    for (int ms = 0; ms < 4; ms++)
        #pragma unroll
        for (int nt = 0; nt < 2; nt++)
            #pragma unroll
            for (int r = 0; r < 4; r++) {
                int m = mh * 64 + ms * 16 + kq * 4 + r;
                int hr = hrow[m];
                if (hr >= 0)
                    H[(size_t)hr * FF + ft * 64 + fh * 32 + nt * 16 + rsel] =
                        (bf16_t)swiglu(ag[ms][nt][r], au[ms][nt][r]);
            }
}

// down-proj + combine : grid (dt=8 x 128d, mt=8 x 128tok, e=16); 4 waves (2m x 2d)
__global__ __launch_bounds__(256, 1) void down2_kernel(
    const void* __restrict__ wd, const bf16_t* __restrict__ wdb,
    const int* __restrict__ flags, const int* __restrict__ cnt,
    const int* __restrict__ tok_enc,
    const float* __restrict__ selw, const bf16_t* __restrict__ H,
    float* __restrict__ outp)
{
    __shared__ __align__(16) bf16_t Hs[2][128 * 128];   // 64 KB
    __shared__ __align__(16) bf16_t Ds[2][128 * 128];   // 64 KB
    __shared__ int toks[128];
    __shared__ int hrs[128];
    __shared__ float wts[128];

    const int dt = blockIdx.x, mt = blockIdx.y, e = blockIdx.z;
    int C = cnt[e]; if (C > T_TOK) C = T_TOK; if (C < 0) C = 0;
    if (mt * 128 >= C) return;

    const bf16_t* wdp = (flags[5] != 0) ? wdb : (const bf16_t*)wd;

    const int tid = threadIdx.x;
    if (tid < 128) {
        int idx = mt * 128 + tid, t = -1, hr = 0; float w = 0.f;
        if (idx < C) {
            int enc = tok_enc[e * T_TOK + idx];
            int tt = enc & 0xFFFF, kk = (enc >> 16) & 0xFFFF;
            if (tt < T_TOK && kk < 3) { t = tt; hr = tt * 3 + kk; w = selw[tt * 3 + kk]; }
        }
        toks[tid] = t; hrs[tid] = hr; wts[tid] = w;
    }
    __syncthreads();

    const int wave = tid >> 6, lane = tid & 63;
    const int mh = wave >> 1, fh = wave & 1;
    const int rsel = lane & 15, kq = lane >> 4;

    const bf16_t* sh[8]; const bf16_t* sd[8];
    #pragma unroll
    for (int j = 0; j < 8; j++) {
        int n = (wave * 8 + j) * 64 + lane, r = n >> 4, s = n & 15;
        sh[j] = H + (size_t)hrs[r] * FF + ((s ^ (r & 15)) << 3);
        sd[j] = wdp + (size_t)(e * DIM + dt * 128 + r) * FF + ((s ^ (r & 15)) << 3);
    }

    #pragma unroll
    for (int j = 0; j < 8; j++) gload_lds16(sh[j], &Hs[0][(wave * 8 + j) * 512]);
    #pragma unroll
    for (int j = 0; j < 8; j++) gload_lds16(sd[j], &Ds[0][(wave * 8 + j) * 512]);

    floatx4 acc[4][4];
    #pragma unroll
    for (int ms = 0; ms < 4; ms++)
        #pragma unroll
        for (int nt = 0; nt < 4; nt++) acc[ms][nt] = (floatx4){0,0,0,0};

    __syncthreads();

    for (int kc = 0; kc < 4; kc++) {
        if (kc < 3) {
            const int b = (kc + 1) & 1, ko = (kc + 1) * 128;
            #pragma unroll
            for (int j = 0; j < 8; j++) gload_lds16(sh[j] + ko, &Hs[b][(wave * 8 + j) * 512]);
            #pragma unroll
            for (int j = 0; j < 8; j++) gload_lds16(sd[j] + ko, &Ds[b][(wave * 8 + j) * 512]);
        }
        const bf16_t* Hb = Hs[kc & 1];
        const bf16_t* Db = Ds[kc & 1];
        #pragma unroll
        for (int i = 0; i < 4; i++) {
            const int q = i * 4 + kq;
            bf16x8 a[4], bd[4];
            #pragma unroll
            for (int ms = 0; ms < 4; ms++) a[ms] = rd128(Hb, mh * 64 + ms * 16 + rsel, q);
            #pragma unroll
            for (int nt = 0; nt < 4; nt++) bd[nt] = rd128(Db, fh * 64 + nt * 16 + rsel, q);
            #pragma unroll
            for (int ms = 0; ms < 4; ms++)
                #pragma unroll
                for (int nt = 0; nt < 4; nt++)
                    acc[ms][nt] = __builtin_amdgcn_mfma_f32_16x16x32_bf16(a[ms], bd[nt], acc[ms][nt], 0, 0, 0);
        }
        __syncthreads();
    }

    #pragma unroll
    for (int ms = 0; ms < 4; ms++)
        #pragma unroll
        for (int nt = 0; nt < 4; nt++)
            #pragma unroll
            for (int r = 0; r < 4; r++) {
                int m = mh * 64 + ms * 16 + kq * 4 + r, t = toks[m];
                if (t >= 0)
                    atomicAdd(outp + (size_t)t * DIM + dt * 128 + fh * 64 + nt * 16 + rsel,
                              acc[ms][nt][r] * wts[m]);
            }
}

// ================= MID path (r3 kernels, fp32-capable, smaller ws) =================

template<int ROWS, bool F32>
__device__ __forceinline__ void w_issue(const void* w, size_t e0, int rstride, int tid,
                                        float4 (&f)[ROWS/8], bf16x8 (&h)[ROWS/16]) {
    if constexpr (F32) {
        const int r0 = tid >> 5, c = tid & 31;
        const float* p = (const float*)w;
        #pragma unroll
        for (int q = 0; q < ROWS/8; q++)
            f[q] = *(const float4*)(p + e0 + (size_t)(q*8 + r0) * rstride + c*4);
    } else {
        const int r0 = tid >> 4, c = tid & 15;
        const bf16_t* p = (const bf16_t*)w;
        #pragma unroll
        for (int q = 0; q < ROWS/16; q++)
            h[q] = *(const bf16x8*)(p + e0 + (size_t)(q*16 + r0) * rstride + c*8);
    }
}

template<int ROWS, bool F32>
__device__ __forceinline__ void w_commit(bf16_t* lb, int tid,
                                         const float4 (&f)[ROWS/8], const bf16x8 (&h)[ROWS/16]) {
    if constexpr (F32) {
        const int r0 = tid >> 5, c = tid & 31, b = c >> 1, hh = c & 1;
        #pragma unroll
        for (int q = 0; q < ROWS/8; q++) {
            int r = q*8 + r0;
            float4 v = f[q];
            bf16x4 t; t[0]=(bf16_t)v.x; t[1]=(bf16_t)v.y; t[2]=(bf16_t)v.z; t[3]=(bf16_t)v.w;
            *(bf16x4*)((char*)lb + r*256 + ((b ^ (r & 15)) << 4) + hh*8) = t;
        }
    } else {
        const int r0 = tid >> 4, c = tid & 15;
        #pragma unroll
        for (int q = 0; q < ROWS/16; q++) {
            int r = q*16 + r0;
            *(bf16x8*)((char*)lb + r*256 + ((c ^ (r & 15)) << 4)) = h[q];
        }
    }
}

__device__ __forceinline__ bf16x8 rdW(const bf16_t* lb, int r, int b) {
    return *(const bf16x8*)((const char*)lb + r*256 + ((b ^ (r & 15)) << 4));
}

template<bool GF, bool UF>
__device__ __forceinline__ void gateup_body(
    const bf16_t* __restrict__ xb,
    const void* __restrict__ wg, const void* __restrict__ wu,
    const int* __restrict__ cnt, const int* __restrict__ tok_enc,
    bf16_t* __restrict__ H, bf16_t* Wl, int* toks, int* hrow)
{
    const int ft = blockIdx.x, mt = blockIdx.y, e = blockIdx.z;
    int C = cnt[e]; if (C > T_TOK) C = T_TOK; if (C < 0) C = 0;
    if (mt * 128 >= C) return;

    const int tid = threadIdx.x;
    if (tid < 128) {
        int idx = mt * 128 + tid, t = 0, hr = -1;
        if (idx < C) {
            int enc = tok_enc[e * T_TOK + idx];
            int tt = enc & 0xFFFF, kk = (enc >> 16) & 0xFFFF;
            if (tt < T_TOK && kk < 3) { t = tt; hr = tt * 3 + kk; }
        }
        toks[tid] = t; hrow[tid] = hr;
    }
    __syncthreads();

    const int wave = tid >> 6, lane = tid & 63;
    const int mh = wave >> 1, fh = wave & 1;
    const int rsel = lane & 15, kq = lane >> 4;

    const size_t w0 = ((size_t)e * FF + (size_t)ft * 32) * DIM;
    const bf16_t* arow[4];
    #pragma unroll
    for (int ms = 0; ms < 4; ms++)
        arow[ms] = xb + (size_t)toks[mh * 64 + ms * 16 + rsel] * DIM + kq * 8;

    float4 fg[4], fu[4]; bf16x8 hg[2], hu[2];
    w_issue<32, GF>(wg, w0, DIM, tid, fg, hg);
    w_issue<32, UF>(wu, w0, DIM, tid, fu, hu);
    w_commit<32, GF>(Wl + 0 * 4096, tid, fg, hg);
    w_commit<32, UF>(Wl + 1 * 4096, tid, fu, hu);

    floatx4 ag[4], au[4];
    #pragma unroll
    for (int ms = 0; ms < 4; ms++) { ag[ms] = (floatx4){0,0,0,0}; au[ms] = (floatx4){0,0,0,0}; }

    __syncthreads();

    for (int kc = 0; kc < 8; kc++) {
        if (kc < 7) {
            w_issue<32, GF>(wg, w0 + (kc + 1) * 128, DIM, tid, fg, hg);
            w_issue<32, UF>(wu, w0 + (kc + 1) * 128, DIM, tid, fu, hu);
        }
        bf16x8 Ac[4][4];
        #pragma unroll
        for (int ms = 0; ms < 4; ms++)
            #pragma unroll
            for (int i = 0; i < 4; i++)
                Ac[ms][i] = *(const bf16x8*)(arow[ms] + kc * 128 + i * 32);

        const bf16_t* Lg = Wl + ((kc & 1) * 2 + 0) * 4096;
        const bf16_t* Lu = Wl + ((kc & 1) * 2 + 1) * 4096;
        const int brow = fh * 16 + rsel;
        #pragma unroll
        for (int i = 0; i < 4; i++) {
            bf16x8 bg = rdW(Lg, brow, i * 4 + kq);
            bf16x8 bu = rdW(Lu, brow, i * 4 + kq);
            #pragma unroll
            for (int ms = 0; ms < 4; ms++) {
                ag[ms] = __builtin_amdgcn_mfma_f32_16x16x32_bf16(Ac[ms][i], bg, ag[ms], 0, 0, 0);
                au[ms] = __builtin_amdgcn_mfma_f32_16x16x32_bf16(Ac[ms][i], bu, au[ms], 0, 0, 0);
            }
        }
        if (kc < 7) {
            w_commit<32, GF>(Wl + (((kc + 1) & 1) * 2 + 0) * 4096, tid, fg, hg);
            w_commit<32, UF>(Wl + (((kc + 1) & 1) * 2 + 1) * 4096, tid, fu, hu);
        }
        __syncthreads();
    }

    const int f = ft * 32 + fh * 16 + rsel;
    #pragma unroll
    for (int ms = 0; ms < 4; ms++)
        #pragma unroll
        for (int r = 0; r < 4; r++) {
            int m = mh * 64 + ms * 16 + kq * 4 + r;
            int hr = hrow[m];
            if (hr >= 0)
                H[(size_t)hr * FF + f] = (bf16_t)swiglu(ag[ms][r], au[ms][r]);
        }
}

__global__ __launch_bounds__(256, 2) void gateup_kernel(
    const bf16_t* __restrict__ xb,
    const void* __restrict__ wg, const void* __restrict__ wu,
    const int* __restrict__ flags, const int* __restrict__ cnt,
    const int* __restrict__ tok_enc, bf16_t* __restrict__ H)
{
    __shared__ __align__(16) bf16_t Wl[2 * 2 * 32 * 128];
    __shared__ int toks[128];
    __shared__ int hrow[128];
    const bool gf = flags[3] != 0, uf = flags[4] != 0;
    if (gf) {
        if (uf) gateup_body<true,  true >(xb, wg, wu, cnt, tok_enc, H, Wl, toks, hrow);
        else    gateup_body<true,  false>(xb, wg, wu, cnt, tok_enc, H, Wl, toks, hrow);
    } else {
        if (uf) gateup_body<false, true >(xb, wg, wu, cnt, tok_enc, H, Wl, toks, hrow);
        else    gateup_body<false, false>(xb, wg, wu, cnt, tok_enc, H, Wl, toks, hrow);
    }
}

template<bool DF>
__device__ __forceinline__ void down_body(
    const void* __restrict__ wd,
    const int* __restrict__ cnt, const int* __restrict__ tok_enc,
    const float* __restrict__ selw, const bf16_t* __restrict__ H,
    float* __restrict__ outp, bf16_t* Wl,
    int* toks, int* hrs, float* wts)
{
    const int dt = blockIdx.x, mt = blockIdx.y, e = blockIdx.z;
    int C = cnt[e]; if (C > T_TOK) C = T_TOK; if (C < 0) C = 0;
    if (mt * 128 >= C) return;

    const int tid = threadIdx.x;
    if (tid < 128) {
        int idx = mt * 128 + tid, t = -1, hr = 0; float w = 0.f;
        if (idx < C) {
            int enc = tok_enc[e * T_TOK + idx];
            int tt = enc & 0xFFFF, kk = (enc >> 16) & 0xFFFF;
            if (tt < T_TOK && kk < 3) { t = tt; hr = tt * 3 + kk; w = selw[tt * 3 + kk]; }
        }
        toks[tid] = t; hrs[tid] = hr; wts[tid] = w;
    }
    __syncthreads();

    const int wave = tid >> 6, lane = tid & 63;
    const int mh = wave >> 1, fh = wave & 1;
    const int rsel = lane & 15, kq = lane >> 4;

    const size_t w0 = ((size_t)e * DIM + (size_t)dt * 64) * FF;
    const bf16_t* arow[4];
    #pragma unroll
    for (int ms = 0; ms < 4; ms++)
        arow[ms] = H + (size_t)hrs[mh * 64 + ms * 16 + rsel] * FF + kq * 8;

    float4 fd[8]; bf16x8 hd[4];
    w_issue<64, DF>(wd, w0, FF, tid, fd, hd);
    w_commit<64, DF>(Wl, tid, fd, hd);

    floatx4 acc[4][2];
    #pragma unroll
    for (int ms = 0; ms < 4; ms++)
        #pragma unroll
        for (int nt = 0; nt < 2; nt++) acc[ms][nt] = (floatx4){0,0,0,0};

    __syncthreads();

    for (int kc = 0; kc < 4; kc++) {
        if (kc < 3)
            w_issue<64, DF>(wd, w0 + (kc + 1) * 128, FF, tid, fd, hd);

        bf16x8 Ac[4][4];
        #pragma unroll
        for (int ms = 0; ms < 4; ms++)
            #pragma unroll
            for (int i = 0; i < 4; i++)
                Ac[ms][i] = *(const bf16x8*)(arow[ms] + kc * 128 + i * 32);

        const bf16_t* Lb = Wl + (kc & 1) * 8192;
        #pragma unroll
        for (int i = 0; i < 4; i++) {
            bf16x8 bd[2];
            #pragma unroll
            for (int nt = 0; nt < 2; nt++)
                bd[nt] = rdW(Lb, fh * 32 + nt * 16 + rsel, i * 4 + kq);
            #pragma unroll
            for (int ms = 0; ms < 4; ms++)
                #pragma unroll
                for (int nt = 0; nt < 2; nt++)
                    acc[ms][nt] = __builtin_amdgcn_mfma_f32_16x16x32_bf16(Ac[ms][i], bd[nt], acc[ms][nt], 0, 0, 0);
        }
        if (kc < 3)
            w_commit<64, DF>(Wl + ((kc + 1) & 1) * 8192, tid, fd, hd);
        __syncthreads();
    }

    const int d0 = dt * 64 + fh * 32;
    #pragma unroll
    for (int ms = 0; ms < 4; ms++)
        #pragma unroll
        for (int nt = 0; nt < 2; nt++)
            #pragma unroll
            for (int r = 0; r < 4; r++) {
                int m = mh * 64 + ms * 16 + kq * 4 + r, t = toks[m];
                if (t >= 0)
                    atomicAdd(outp + (size_t)t * DIM + d0 + nt * 16 + rsel, acc[ms][nt][r] * wts[m]);
            }
}

__global__ __launch_bounds__(256, 2) void down_kernel(
    const void* __restrict__ wd,
    const int* __restrict__ flags, const int* __restrict__ cnt,
    const int* __restrict__ tok_enc,
    const float* __restrict__ selw, const bf16_t* __restrict__ H,
    float* __restrict__ outp)
{
    __shared__ __align__(16) bf16_t Wl[2 * 64 * 128];
    __shared__ int toks[128];
    __shared__ int hrs[128];
    __shared__ float wts[128];
    const bool df = flags[5] != 0;
    if (df) down_body<true >(wd, cnt, tok_enc, selw, H, outp, Wl, toks, hrs, wts);
    else    down_body<false>(wd, cnt, tok_enc, selw, H, outp, Wl, toks, hrs, wts);
}

// ---------------- fallback fused FFN ----------------
__global__ __launch_bounds__(256) void ffn_kernel(
    const void* __restrict__ x,
    const void* __restrict__ wg, const void* __restrict__ wu, const void* __restrict__ wd,
    const int* __restrict__ flags, const int* __restrict__ cnt, const int* __restrict__ tok_enc,
    const float* __restrict__ selw, float* __restrict__ outp)
{
    const int e = blockIdx.x, tile = blockIdx.y;
    int C = cnt[e]; if (C > T_TOK) C = T_TOK; if (C < 0) C = 0;
    if (tile * 16 >= C) return;
    const bool xf = flags[0] != 0, gf = flags[3] != 0, uf = flags[4] != 0, df = flags[5] != 0;

    __shared__ __align__(16) bf16_t Xs[16][1032];
    __shared__ __align__(16) bf16_t Hs[16][520];
    __shared__ int toks[16];
    __shared__ float wts[16];
    const int tid = threadIdx.x;
    if (tid < 16) {
        int idx = tile * 16 + tid, t = -1; float w = 0.f;
        if (idx < C) {
            int enc = tok_enc[e * T_TOK + idx];
            int tt = enc & 0xFFFF, kk = (enc >> 16) & 0xFFFF;
            if (tt < T_TOK && kk < 3) { t = tt; w = selw[tt * 3 + kk]; }
        }
        toks[tid] = t; wts[tid] = w;
    }
    __syncthreads();
    {
        int row = tid >> 4, chunk = tid & 15;
        int t = toks[row];
        bf16x8* dst = (bf16x8*)&Xs[row][chunk * 64];
        if (t >= 0) {
            #pragma unroll
            for (int i = 0; i < 8; i++)
                dst[i] = loadB8r(x, (size_t)t * DIM + chunk * 64 + i * 8, xf);
        } else {
            bf16x8 z;
            #pragma unroll
            for (int kz = 0; kz < 8; kz++) z[kz] = (bf16_t)0.0f;
            #pragma unroll
            for (int i = 0; i < 8; i++) dst[i] = z;
        }
    }
    __syncthreads();

    const int wave = tid >> 6, lane = tid & 63;
    const int rsel = lane & 15, kq = lane >> 4;
    const size_t eoffF = (size_t)e * FF * DIM;
    for (int nt = 0; nt < 8; nt++) {
        const int f0 = wave * 128 + nt * 16;
        const size_t boff = eoffF + (size_t)(f0 + rsel) * DIM + kq * 8;
        const bf16_t* ap = &Xs[rsel][kq * 8];
        floatx4 accg = {0.f,0.f,0.f,0.f};
        floatx4 accu = {0.f,0.f,0.f,0.f};
        for (int k0 = 0; k0 < DIM; k0 += 32) {
            bf16x8 a  = *(const bf16x8*)(ap + k0);
            bf16x8 bg = loadB8r(wg, boff + k0, gf);
            bf16x8 bu = loadB8r(wu, boff + k0, uf);
            accg = __builtin_amdgcn_mfma_f32_16x16x32_bf16(a, bg, accg, 0, 0, 0);
            accu = __builtin_amdgcn_mfma_f32_16x16x32_bf16(a, bu, accu, 0, 0, 0);
        }
        #pragma unroll
        for (int r = 0; r < 4; r++)
            Hs[kq * 4 + r][f0 + rsel] = (bf16_t)swiglu(accg[r], accu[r]);
    }
    __syncthreads();
    const size_t eoffD = (size_t)e * DIM * FF;
    for (int nt = 0; nt < 16; nt++) {
        const int d0 = wave * 256 + nt * 16;
        const size_t boff = eoffD + (size_t)(d0 + rsel) * FF + kq * 8;
        const bf16_t* ap = &Hs[rsel][kq * 8];
        floatx4 acc = {0.f,0.f,0.f,0.f};
        for (int k0 = 0; k0 < FF; k0 += 32) {
            bf16x8 a = *(const bf16x8*)(ap + k0);
            bf16x8 b = loadB8r(wd, boff + k0, df);
            acc = __builtin_amdgcn_mfma_f32_16x16x32_bf16(a, b, acc, 0, 0, 0);
        }
        #pragma unroll
        for (int r = 0; r < 4; r++) {
            int m = kq * 4 + r, t = toks[m];
            if (t >= 0) atomicAdd(outp + (size_t)t * DIM + d0 + rsel, acc[r] * wts[m]);
        }
    }
}

extern "C" void kernel_launch(void* const* d_in, const int* in_sizes, int n_in,
                              void* d_out, int out_size, void* d_ws, size_t ws_size,
                              hipStream_t stream)
{
    const void* x     = d_in[0];
    const void* w_out = d_in[1];
    const void* w_in  = d_in[2];
    const void* wg    = d_in[3];
    const void* wu    = d_in[4];
    const void* wd    = d_in[5];
    float* out  = (float*)d_out;
    float* selw = out + (size_t)T_TOK * DIM;

    char* ws = (char*)d_ws;
    int*    flags = (int*)(ws + FLAG_OFF);
    int*    cnt   = (int*)(ws + CNT_OFF);
    int*    tok   = (int*)(ws + TOK_OFF);
    int*    sel   = (int*)(ws + SEL_OFF);
    bf16_t* H     = (bf16_t*)(ws + H_OFF);
    bf16_t* xbf   = (bf16_t*)(ws + XBF_OFF);
    bf16_t* wgb   = (bf16_t*)(ws + WGB_OFF);
    bf16_t* wub   = (bf16_t*)(ws + WUB_OFF);
    bf16_t* wdb   = (bf16_t*)(ws + WDB_OFF);

    const bool full = ws_size >= (size_t)WS_FULL;
    const bool mid  = !full && ws_size >= (size_t)WS_MID;

    hipMemsetAsync(out, 0, (size_t)T_TOK * DIM * sizeof(float), stream);

    detect_kernel<<<dim3(6), dim3(64), 0, stream>>>(x, w_out, w_in, wg, wu, wd, flags);

    if (full)
        wcvt_kernel<<<dim3(4096, 3), dim3(256), 0, stream>>>(wg, wu, wd, flags, wgb, wub, wdb);

    router_kernel<<<dim3(T_TOK / 4), dim3(256), 0, stream>>>(
        x, w_out, w_in, selw, flags, sel, (full || mid) ? xbf : (bf16_t*)nullptr);

    bin_kernel<<<dim3(1), dim3(1024), 0, stream>>>(sel, cnt, tok);

    if (full) {
        gateup2_kernel<<<dim3(8, 8, 16), dim3(256), 0, stream>>>(
            xbf, wg, wu, wgb, wub, flags, cnt, tok, H);
        down2_kernel<<<dim3(8, 8, 16), dim3(256), 0, stream>>>(
            wd, wdb, flags, cnt, tok, selw, H, out);
    } else if (mid) {
        gateup_kernel<<<dim3(16, 8, 16), dim3(256), 0, stream>>>(
            xbf, wg, wu, flags, cnt, tok, H);
        down_kernel<<<dim3(16, 8, 16), dim3(256), 0, stream>>>(
            wd, flags, cnt, tok, selw, H, out);
    } else {
        ffn_kernel<<<dim3(NEXP, 64), dim3(256), 0, stream>>>(
            x, wg, wu, wd, flags, cnt, tok, selw, out);
    }
}

// Round 5
// 215.699 us; speedup vs baseline: 1.7272x; 1.1104x over previous
//
#include <hip/hip_runtime.h>
#include <hip/hip_bf16.h>

typedef __bf16 bf16_t;
typedef __bf16 bf16x8 __attribute__((ext_vector_type(8)));
typedef float floatx4 __attribute__((ext_vector_type(4)));
typedef unsigned int u32;

#define T_TOK 1024
#define DIM   1024
#define FF    512
#define NEXP  16

// ws layout
#define FLAG_OFF 0                 // int[6]
#define CNT_OFF  64                // int[16]
#define TOK_OFF  256               // int[16*1024]
#define SEL_OFF  65792             // int[1024*3]
#define H_OFF    78080             // bf16[3072][512]
#define XBF_OFF  (H_OFF + (size_t)3072*512*2)        // bf16 x  (2 MB)
#define WGB_OFF  (XBF_OFF + (size_t)T_TOK*DIM*2)     // bf16 wg (16 MB)
#define WUB_OFF  (WGB_OFF + (size_t)NEXP*FF*DIM*2)   // bf16 wu (16 MB)
#define WDB_OFF  (WUB_OFF + (size_t)NEXP*FF*DIM*2)   // bf16 wd (16 MB)
#define Y_OFF    (WDB_OFF + (size_t)NEXP*DIM*FF*2)   // fp32 Y[3072][1024] (12 MB)
#define WS_FULL  (Y_OFF + (size_t)3072*DIM*4)

__device__ inline float swiglu(float g, float u) {
    float a = fminf(fmaxf(-g, -60.f), 60.f);
    return g * u / (1.0f + __expf(a));
}

// async 16B global->LDS; dst must be wave-uniform base (HW adds lane*16)
__device__ __forceinline__ void gload_lds16(const void* g, void* l) {
    __builtin_amdgcn_global_load_lds((const __attribute__((address_space(1))) u32*)g,
                                     (__attribute__((address_space(3))) u32*)l, 16, 0, 0);
}

__device__ __forceinline__ bf16x8 cvt8(float4 a, float4 b) {
    bf16x8 r;
    r[0]=(bf16_t)a.x; r[1]=(bf16_t)a.y; r[2]=(bf16_t)a.z; r[3]=(bf16_t)a.w;
    r[4]=(bf16_t)b.x; r[5]=(bf16_t)b.y; r[6]=(bf16_t)b.z; r[7]=(bf16_t)b.w;
    return r;
}

// swizzled LDS tile read: row stride 128 bf16, 16B slot q stored at q^(row&15)
__device__ __forceinline__ bf16x8 rd128(const bf16_t* L, int row, int q) {
    return *(const bf16x8*)(L + row * 128 + ((q ^ (row & 15)) << 3));
}

// ---------------- per-input dtype detect ----------------
__global__ __launch_bounds__(64) void detect_kernel(
    const void* p0, const void* p1, const void* p2,
    const void* p3, const void* p4, const void* p5,
    int* __restrict__ flags)
{
    const void* ps[6] = {p0, p1, p2, p3, p4, p5};
    int j = blockIdx.x;
    int lane = threadIdx.x;
    const unsigned short* h = (const unsigned short*)ps[j];
    unsigned int bad = 0;
    for (int i = lane; i < 4096; i += 64) {
        unsigned int e = ((unsigned int)h[i] >> 7) & 0xFFu;
        if (e >= 0x90u) bad = 1;
    }
    unsigned long long b = __ballot(bad);
    if (lane == 0) flags[j] = (b != 0ull) ? 1 : 0;
}

// ---------------- weight fp32 -> bf16 conversion (streaming) ----------------
__global__ __launch_bounds__(256) void wcvt_kernel(
    const void* __restrict__ wg, const void* __restrict__ wu, const void* __restrict__ wd,
    const int* __restrict__ flags,
    bf16_t* __restrict__ gb, bf16_t* __restrict__ ub, bf16_t* __restrict__ db)
{
    const int z = blockIdx.y;
    const void* src; bf16_t* dst; int f;
    if (z == 0)      { src = wg; dst = gb; f = flags[3]; }
    else if (z == 1) { src = wu; dst = ub; f = flags[4]; }
    else             { src = wd; dst = db; f = flags[5]; }
    if (!f) return;
    size_t i = ((size_t)blockIdx.x * 256 + threadIdx.x) * 8;
    const float4* p = (const float4*)((const float*)src + i);
    float4 a = p[0], b = p[1];
    *(bf16x8*)(dst + i) = cvt8(a, b);
}

// ---- runtime-typed loader (fallback only) ----
__device__ inline bf16x8 loadB8r(const void* base, size_t off, bool f32) {
    if (f32) {
        const float4* p = (const float4*)((const float*)base + off);
        float4 v0 = p[0], v1 = p[1];
        return cvt8(v0, v1);
    } else {
        return *(const bf16x8*)((const bf16_t*)base + off);
    }
}

// ---------------- Router: 1 token/block, 24 logits split over 4 waves ----------------
__global__ __launch_bounds__(256) void router3_kernel(
    const void* __restrict__ x,
    const void* __restrict__ w_out,
    const void* __restrict__ w_in,
    float* __restrict__ selw_out,
    const int* __restrict__ flags,
    int* __restrict__ sel_ids,
    bf16_t* __restrict__ xb)
{
    const bool xf  = flags[0] != 0;
    const bool gof = flags[1] != 0;
    const bool gif = flags[2] != 0;
    const int tid = threadIdx.x;
    const int wave = tid >> 6, lane = tid & 63;
    const int t = blockIdx.x;

    __shared__ float Ls[24];

    float xv[16];
    if (xf) {
        const float* xp = (const float*)x + (size_t)t * DIM;
        #pragma unroll
        for (int i = 0; i < 16; i++) xv[i] = xp[lane + 64 * i];
    } else {
        const bf16_t* xp = (const bf16_t*)x + (size_t)t * DIM;
        #pragma unroll
        for (int i = 0; i < 16; i++) xv[i] = (float)xp[lane + 64 * i];
    }

    if (wave == 0 && xb) {
        #pragma unroll
        for (int i = 0; i < 16; i++)
            xb[(size_t)t * DIM + lane + 64 * i] = (bf16_t)xv[i];
    }

    #pragma unroll
    for (int jj = 0; jj < 6; jj++) {
        const int j = wave * 6 + jj;
        const void* gb; int row; bool gf;
        if (j < 8) { gb = w_out; row = j;     gf = gof; }
        else       { gb = w_in;  row = j - 8; gf = gif; }
        float s = 0.f;
        if (gf) {
            const float* gp = (const float*)gb + (size_t)row * DIM;
            #pragma unroll
            for (int i = 0; i < 16; i++) s += xv[i] * gp[lane + 64 * i];
        } else {
            const bf16_t* gp = (const bf16_t*)gb + (size_t)row * DIM;
            #pragma unroll
            for (int i = 0; i < 16; i++) s += xv[i] * (float)gp[lane + 64 * i];
        }
        #pragma unroll
        for (int m = 32; m >= 1; m >>= 1) s += __shfl_xor(s, m, 64);
        if (lane == 0) Ls[j] = s;
    }
    __syncthreads();

    if (tid == 0) {
        const float* logits = Ls;
        float mx = logits[0];
        for (int o = 1; o < 8; o++) mx = fmaxf(mx, logits[o]);
        float p[8];
        for (int o = 0; o < 8; o++) p[o] = __expf(logits[o] - mx);
        int i0 = 0;
        for (int o = 1; o < 8; o++) if (logits[o] > logits[i0]) i0 = o;
        int i1 = (i0 == 0) ? 1 : 0;
        for (int o = 0; o < 8; o++) if (o != i0 && logits[o] > logits[i1]) i1 = o;
        float rsum = p[i0] + p[i1];
        float rw0 = p[i0] / rsum, rw1 = p[i1] / rsum;

        float a0 = logits[8 + i0 * 2], a1 = logits[8 + i0 * 2 + 1];
        int j00 = (a1 > a0) ? 1 : 0;
        float b0 = logits[8 + i1 * 2], b1 = logits[8 + i1 * 2 + 1];
        int j10 = (b1 > b0) ? 1 : 0;

        int   ids[3] = { i0 * 2 + j00, i0 * 2 + (1 - j00), i1 * 2 + j10 };
        float w[3]   = { rw0, rw0, rw1 };

        #pragma unroll
        for (int k = 0; k < 3; k++) {
            selw_out[t * 3 + k] = w[k];
            sel_ids[t * 3 + k]  = ids[k];
        }
    }
}

// ---------------- binning: 16 blocks (1/expert), ballot prefix ----------------
__global__ __launch_bounds__(1024) void bin2_kernel(
    const int* __restrict__ sel_ids,
    int* __restrict__ cnt, int* __restrict__ tok_enc)
{
    const int e = blockIdx.x, tid = threadIdx.x;
    const int wave = tid >> 6, lane = tid & 63;
    __shared__ int wbase[16];

    int my = -1;
    #pragma unroll
    for (int k = 0; k < 3; k++) {
        int id = sel_ids[tid * 3 + k];
        if (id == e) my = tid | (k << 16);   // ids within a token are distinct
    }
    unsigned long long b = __ballot(my >= 0);
    if (lane == 0) wbase[wave] = __popcll(b);
    __syncthreads();
    if (tid == 0) {
        int s = 0;
        for (int w = 0; w < 16; w++) { int c = wbase[w]; wbase[w] = s; s += c; }
        cnt[e] = s;
    }
    __syncthreads();
    if (my >= 0) {
        int pos = wbase[wave] + __popcll(b & ((1ull << lane) - 1ull));
        if (pos < T_TOK) tok_enc[e * T_TOK + pos] = my;
    }
}

// ================= FULL path: all-DMA MFMA kernels, 512 threads =================

// gate+up -> H : grid (ft=8 x 64f, mt=8 x 128tok, e=16); 8 waves (2m x 4f)
__global__ __launch_bounds__(512, 1) void gateup3_kernel(
    const bf16_t* __restrict__ xb,
    const void* __restrict__ wg, const void* __restrict__ wu,
    const bf16_t* __restrict__ wgb, const bf16_t* __restrict__ wub,
    const int* __restrict__ flags, const int* __restrict__ cnt,
    const int* __restrict__ tok_enc, bf16_t* __restrict__ H)
{
    __shared__ __align__(16) bf16_t Xs[2][128 * 128];   // 64 KB
    __shared__ __align__(16) bf16_t Gs[2][64 * 128];    // 32 KB
    __shared__ __align__(16) bf16_t Us[2][64 * 128];    // 32 KB
    __shared__ int toks[128];
    __shared__ int hrow[128];

    const int ft = blockIdx.x, mt = blockIdx.y, e = blockIdx.z;
    int C = cnt[e]; if (C > T_TOK) C = T_TOK; if (C < 0) C = 0;
    if (mt * 128 >= C) return;

    const bf16_t* wgp = (flags[3] != 0) ? wgb : (const bf16_t*)wg;
    const bf16_t* wup = (flags[4] != 0) ? wub : (const bf16_t*)wu;

    const int tid = threadIdx.x;
    if (tid < 128) {
        int idx = mt * 128 + tid, t = 0, hr = -1;
        if (idx < C) {
            int enc = tok_enc[e * T_TOK + idx];
            int tt = enc & 0xFFFF, kk = (enc >> 16) & 0xFFFF;
            if (tt < T_TOK && kk < 3) { t = tt; hr = tt * 3 + kk; }
        }
        toks[tid] = t; hrow[tid] = hr;
    }
    __syncthreads();

    const int wave = tid >> 6, lane = tid & 63;
    const int mh = wave >> 2, fq = wave & 3;
    const int rsel = lane & 15, kq = lane >> 4;

    // per-lane inverse-swizzled source pointers (dst is linear DMA)
    const bf16_t* sx[4];
    #pragma unroll
    for (int j = 0; j < 4; j++) {
        int n = (j * 8 + wave) * 64 + lane, r = n >> 4, s = n & 15;
        sx[j] = xb + (size_t)toks[r] * DIM + ((s ^ (r & 15)) << 3);
    }
    const bf16_t* sg[2]; const bf16_t* su[2];
    #pragma unroll
    for (int j = 0; j < 2; j++) {
        int n = (j * 8 + wave) * 64 + lane, r = n >> 4, s = n & 15;
        size_t off = (size_t)(e * FF + ft * 64 + r) * DIM + ((s ^ (r & 15)) << 3);
        sg[j] = wgp + off; su[j] = wup + off;
    }

    // stage chunk 0
    #pragma unroll
    for (int j = 0; j < 4; j++) gload_lds16(sx[j], &Xs[0][(j * 8 + wave) * 512]);
    #pragma unroll
    for (int j = 0; j < 2; j++) gload_lds16(sg[j], &Gs[0][(j * 8 + wave) * 512]);
    #pragma unroll
    for (int j = 0; j < 2; j++) gload_lds16(su[j], &Us[0][(j * 8 + wave) * 512]);

    floatx4 ag[4], au[4];
    #pragma unroll
    for (int ms = 0; ms < 4; ms++) { ag[ms] = (floatx4){0,0,0,0}; au[ms] = (floatx4){0,0,0,0}; }

    __syncthreads();

    for (int kc = 0; kc < 8; kc++) {
        if (kc < 7) {
            const int b = (kc + 1) & 1, ko = (kc + 1) * 128;
            #pragma unroll
            for (int j = 0; j < 4; j++) gload_lds16(sx[j] + ko, &Xs[b][(j * 8 + wave) * 512]);
            #pragma unroll
            for (int j = 0; j < 2; j++) gload_lds16(sg[j] + ko, &Gs[b][(j * 8 + wave) * 512]);
            #pragma unroll
            for (int j = 0; j < 2; j++) gload_lds16(su[j] + ko, &Us[b][(j * 8 + wave) * 512]);
        }
        const bf16_t* X = Xs[kc & 1];
        const bf16_t* G = Gs[kc & 1];
        const bf16_t* U = Us[kc & 1];
        #pragma unroll
        for (int i = 0; i < 4; i++) {
            const int q = i * 4 + kq;
            bf16x8 a[4];
            #pragma unroll
            for (int ms = 0; ms < 4; ms++) a[ms] = rd128(X, mh * 64 + ms * 16 + rsel, q);
            bf16x8 bg = rd128(G, fq * 16 + rsel, q);
            bf16x8 bu = rd128(U, fq * 16 + rsel, q);
            #pragma unroll
            for (int ms = 0; ms < 4; ms++) {
                ag[ms] = __builtin_amdgcn_mfma_f32_16x16x32_bf16(a[ms], bg, ag[ms], 0, 0, 0);
                au[ms] = __builtin_amdgcn_mfma_f32_16x16x32_bf16(a[ms], bu, au[ms], 0, 0, 0);
            }
        }
        __syncthreads();
    }

    const int f = ft * 64 + fq * 16 + rsel;
    #pragma unroll
    for (int ms = 0; ms < 4; ms++)
        #pragma unroll
        for (int r = 0; r < 4; r++) {
            int m = mh * 64 + ms * 16 + kq * 4 + r;
            int hr = hrow[m];
            if (hr >= 0)
                H[(size_t)hr * FF + f] = (bf16_t)swiglu(ag[ms][r], au[ms][r]);
        }
}

// down-proj -> Y (unweighted fp32 partials, no atomics)
// grid (dt=8 x 128d, mt=8 x 128tok, e=16); 8 waves (2m x 4d)
__global__ __launch_bounds__(512, 1) void down3_kernel(
    const void* __restrict__ wd, const bf16_t* __restrict__ wdb,
    const int* __restrict__ flags, const int* __restrict__ cnt,
    const int* __restrict__ tok_enc, const bf16_t* __restrict__ H,
    float* __restrict__ Y)
{
    __shared__ __align__(16) bf16_t Hs[2][128 * 128];   // 64 KB
    __shared__ __align__(16) bf16_t Ds[2][128 * 128];   // 64 KB
    __shared__ int hsrc[128];
    __shared__ int hdst[128];

    const int dt = blockIdx.x, mt = blockIdx.y, e = blockIdx.z;
    int C = cnt[e]; if (C > T_TOK) C = T_TOK; if (C < 0) C = 0;
    if (mt * 128 >= C) return;

    const bf16_t* wdp = (flags[5] != 0) ? wdb : (const bf16_t*)wd;

    const int tid = threadIdx.x;
    if (tid < 128) {
        int idx = mt * 128 + tid, hr = -1;
        if (idx < C) {
            int enc = tok_enc[e * T_TOK + idx];
            int tt = enc & 0xFFFF, kk = (enc >> 16) & 0xFFFF;
            if (tt < T_TOK && kk < 3) hr = tt * 3 + kk;
        }
        hsrc[tid] = (hr >= 0) ? hr : 0;
        hdst[tid] = hr;
    }
    __syncthreads();

    const int wave = tid >> 6, lane = tid & 63;
    const int mh = wave >> 2, dq = wave & 3;
    const int rsel = lane & 15, kq = lane >> 4;

    const bf16_t* sh[4]; const bf16_t* sd[4];
    #pragma unroll
    for (int j = 0; j < 4; j++) {
        int n = (j * 8 + wave) * 64 + lane, r = n >> 4, s = n & 15;
        sh[j] = H + (size_t)hsrc[r] * FF + ((s ^ (r & 15)) << 3);
        sd[j] = wdp + (size_t)(e * DIM + dt * 128 + r) * FF + ((s ^ (r & 15)) << 3);
    }

    #pragma unroll
    for (int j = 0; j < 4; j++) gload_lds16(sh[j], &Hs[0][(j * 8 + wave) * 512]);
    #pragma unroll
    for (int j = 0; j < 4; j++) gload_lds16(sd[j], &Ds[0][(j * 8 + wave) * 512]);

    floatx4 acc[4][2];
    #pragma unroll
    for (int ms = 0; ms < 4; ms++)
        #pragma unroll
        for (int nt = 0; nt < 2; nt++) acc[ms][nt] = (floatx4){0,0,0,0};

    __syncthreads();

    for (int kc = 0; kc < 4; kc++) {
        if (kc < 3) {
            const int b = (kc + 1) & 1, ko = (kc + 1) * 128;
            #pragma unroll
            for (int j = 0; j < 4; j++) gload_lds16(sh[j] + ko, &Hs[b][(j * 8 + wave) * 512]);
            #pragma unroll
            for (int j = 0; j < 4; j++) gload_lds16(sd[j] + ko, &Ds[b][(j * 8 + wave) * 512]);
        }
        const bf16_t* Hb = Hs[kc & 1];
        const bf16_t* Db = Ds[kc & 1];
        #pragma unroll
        for (int i = 0; i < 4; i++) {
            const int q = i * 4 + kq;
            bf16x8 a[4], bd[2];
            #pragma unroll
            for (int ms = 0; ms < 4; ms++) a[ms] = rd128(Hb, mh * 64 + ms * 16 + rsel, q);
            #pragma unroll
            for (int nt = 0; nt < 2; nt++) bd[nt] = rd128(Db, dq * 32 + nt * 16 + rsel, q);
            #pragma unroll
            for (int ms = 0; ms < 4; ms++)
                #pragma unroll
                for (int nt = 0; nt < 2; nt++)
                    acc[ms][nt] = __builtin_amdgcn_mfma_f32_16x16x32_bf16(a[ms], bd[nt], acc[ms][nt], 0, 0, 0);
        }
        __syncthreads();
    }

    #pragma unroll
    for (int ms = 0; ms < 4; ms++)
        #pragma unroll
        for (int nt = 0; nt < 2; nt++)
            #pragma unroll
            for (int r = 0; r < 4; r++) {
                int m = mh * 64 + ms * 16 + kq * 4 + r;
                int hr = hdst[m];
                if (hr >= 0)
                    Y[(size_t)hr * DIM + dt * 128 + dq * 32 + nt * 16 + rsel] = acc[ms][nt][r];
            }
}

// weighted combine: out[t][d] = sum_k selw[t,k] * Y[t*3+k][d]
__global__ __launch_bounds__(256) void combine_kernel(
    const float* __restrict__ Y, const float* __restrict__ selw,
    float* __restrict__ outp)
{
    int idx = blockIdx.x * 256 + threadIdx.x;   // T*D/4 threads
    int t = idx >> 8;
    int d = (idx & 255) * 4;
    float w0 = selw[t * 3 + 0], w1 = selw[t * 3 + 1], w2 = selw[t * 3 + 2];
    float4 y0 = *(const float4*)(Y + (size_t)(t * 3 + 0) * DIM + d);
    float4 y1 = *(const float4*)(Y + (size_t)(t * 3 + 1) * DIM + d);
    float4 y2 = *(const float4*)(Y + (size_t)(t * 3 + 2) * DIM + d);
    float4 o;
    o.x = w0 * y0.x + w1 * y1.x + w2 * y2.x;
    o.y = w0 * y0.y + w1 * y1.y + w2 * y2.y;
    o.z = w0 * y0.z + w1 * y1.z + w2 * y2.z;
    o.w = w0 * y0.w + w1 * y1.w + w2 * y2.w;
    *(float4*)(outp + (size_t)t * DIM + d) = o;
}

// ---------------- fallback fused FFN ----------------
__global__ __launch_bounds__(256) void ffn_kernel(
    const void* __restrict__ x,
    const void* __restrict__ wg, const void* __restrict__ wu, const void* __restrict__ wd,
    const int* __restrict__ flags, const int* __restrict__ cnt, const int* __restrict__ tok_enc,
    const float* __restrict__ selw, float* __restrict__ outp)
{
    const int e = blockIdx.x, tile = blockIdx.y;
    int C = cnt[e]; if (C > T_TOK) C = T_TOK; if (C < 0) C = 0;
    if (tile * 16 >= C) return;
    const bool xf = flags[0] != 0, gf = flags[3] != 0, uf = flags[4] != 0, df = flags[5] != 0;

    __shared__ __align__(16) bf16_t Xs[16][1032];
    __shared__ __align__(16) bf16_t Hs[16][520];
    __shared__ int toks[16];
    __shared__ float wts[16];
    const int tid = threadIdx.x;
    if (tid < 16) {
        int idx = tile * 16 + tid, t = -1; float w = 0.f;
        if (idx < C) {
            int enc = tok_enc[e * T_TOK + idx];
            int tt = enc & 0xFFFF, kk = (enc >> 16) & 0xFFFF;
            if (tt < T_TOK && kk < 3) { t = tt; w = selw[tt * 3 + kk]; }
        }
        toks[tid] = t; wts[tid] = w;
    }
    __syncthreads();
    {
        int row = tid >> 4, chunk = tid & 15;
        int t = toks[row];
        bf16x8* dst = (bf16x8*)&Xs[row][chunk * 64];
        if (t >= 0) {
            #pragma unroll
            for (int i = 0; i < 8; i++)
                dst[i] = loadB8r(x, (size_t)t * DIM + chunk * 64 + i * 8, xf);
        } else {
            bf16x8 z;
            #pragma unroll
            for (int kz = 0; kz < 8; kz++) z[kz] = (bf16_t)0.0f;
            #pragma unroll
            for (int i = 0; i < 8; i++) dst[i] = z;
        }
    }
    __syncthreads();

    const int wave = tid >> 6, lane = tid & 63;
    const int rsel = lane & 15, kq = lane >> 4;
    const size_t eoffF = (size_t)e * FF * DIM;
    for (int nt = 0; nt < 8; nt++) {
        const int f0 = wave * 128 + nt * 16;
        const size_t boff = eoffF + (size_t)(f0 + rsel) * DIM + kq * 8;
        const bf16_t* ap = &Xs[rsel][kq * 8];
        floatx4 accg = {0.f,0.f,0.f,0.f};
        floatx4 accu = {0.f,0.f,0.f,0.f};
        for (int k0 = 0; k0 < DIM; k0 += 32) {
            bf16x8 a  = *(const bf16x8*)(ap + k0);
            bf16x8 bg = loadB8r(wg, boff + k0, gf);
            bf16x8 bu = loadB8r(wu, boff + k0, uf);
            accg = __builtin_amdgcn_mfma_f32_16x16x32_bf16(a, bg, accg, 0, 0, 0);
            accu = __builtin_amdgcn_mfma_f32_16x16x32_bf16(a, bu, accu, 0, 0, 0);
        }
        #pragma unroll
        for (int r = 0; r < 4; r++)
            Hs[kq * 4 + r][f0 + rsel] = (bf16_t)swiglu(accg[r], accu[r]);
    }
    __syncthreads();
    const size_t eoffD = (size_t)e * DIM * FF;
    for (int nt = 0; nt < 16; nt++) {
        const int d0 = wave * 256 + nt * 16;
        const size_t boff = eoffD + (size_t)(d0 + rsel) * FF + kq * 8;
        const bf16_t* ap = &Hs[rsel][kq * 8];
        floatx4 acc = {0.f,0.f,0.f,0.f};
        for (int k0 = 0; k0 < FF; k0 += 32) {
            bf16x8 a = *(const bf16x8*)(ap + k0);
            bf16x8 b = loadB8r(wd, boff + k0, df);
            acc = __builtin_amdgcn_mfma_f32_16x16x32_bf16(a, b, acc, 0, 0, 0);
        }
        #pragma unroll
        for (int r = 0; r < 4; r++) {
            int m = kq * 4 + r, t = toks[m];
            if (t >= 0) atomicAdd(outp + (size_t)t * DIM + d0 + rsel, acc[r] * wts[m]);
        }
    }
}

extern "C" void kernel_launch(void* const* d_in, const int* in_sizes, int n_in,
                              void* d_out, int out_size, void* d_ws, size_t ws_size,
                              hipStream_t stream)
{
    const void* x     = d_in[0];
    const void* w_out = d_in[1];
    const void* w_in  = d_in[2];
    const void* wg    = d_in[3];
    const void* wu    = d_in[4];
    const void* wd    = d_in[5];
    float* out  = (float*)d_out;
    float* selw = out + (size_t)T_TOK * DIM;

    char* ws = (char*)d_ws;
    int*    flags = (int*)(ws + FLAG_OFF);
    int*    cnt   = (int*)(ws + CNT_OFF);
    int*    tok   = (int*)(ws + TOK_OFF);
    int*    sel   = (int*)(ws + SEL_OFF);
    bf16_t* H     = (bf16_t*)(ws + H_OFF);
    bf16_t* xbf   = (bf16_t*)(ws + XBF_OFF);
    bf16_t* wgb   = (bf16_t*)(ws + WGB_OFF);
    bf16_t* wub   = (bf16_t*)(ws + WUB_OFF);
    bf16_t* wdb   = (bf16_t*)(ws + WDB_OFF);
    float*  Y     = (float*)(ws + Y_OFF);

    const bool full = ws_size >= (size_t)WS_FULL;

    detect_kernel<<<dim3(6), dim3(64), 0, stream>>>(x, w_out, w_in, wg, wu, wd, flags);

    if (full) {
        hipMemsetAsync(Y, 0, (size_t)3072 * DIM * sizeof(float), stream);
        wcvt_kernel<<<dim3(4096, 3), dim3(256), 0, stream>>>(wg, wu, wd, flags, wgb, wub, wdb);
    } else {
        hipMemsetAsync(out, 0, (size_t)T_TOK * DIM * sizeof(float), stream);
    }

    router3_kernel<<<dim3(T_TOK), dim3(256), 0, stream>>>(
        x, w_out, w_in, selw, flags, sel, full ? xbf : (bf16_t*)nullptr);

    bin2_kernel<<<dim3(NEXP), dim3(1024), 0, stream>>>(sel, cnt, tok);

    if (full) {
        gateup3_kernel<<<dim3(8, 8, 16), dim3(512), 0, stream>>>(
            xbf, wg, wu, wgb, wub, flags, cnt, tok, H);
        down3_kernel<<<dim3(8, 8, 16), dim3(512), 0, stream>>>(
            wd, wdb, flags, cnt, tok, H, Y);
        combine_kernel<<<dim3(T_TOK * DIM / 1024), dim3(256), 0, stream>>>(Y, selw, out);
    } else {
        ffn_kernel<<<dim3(NEXP, 64), dim3(256), 0, stream>>>(
            x, wg, wu, wd, flags, cnt, tok, selw, out);
    }
}

// Round 6
// 201.500 us; speedup vs baseline: 1.8489x; 1.0705x over previous
//
#include <hip/hip_runtime.h>
#include <hip/hip_bf16.h>

typedef __bf16 bf16_t;
typedef __bf16 bf16x8 __attribute__((ext_vector_type(8)));
typedef float floatx4 __attribute__((ext_vector_type(4)));
typedef unsigned int u32;

#define T_TOK 1024
#define DIM   1024
#define FF    512
#define NEXP  16

// ws layout
#define FLAG_OFF 0                 // int[6]
#define CNT_OFF  64                // int[16]
#define TOK_OFF  256               // int[16*1024]
#define SEL_OFF  65792             // int[1024*3]
#define H_OFF    78080             // bf16[3072][512] (3 MB)
#define XBF_OFF  (H_OFF + (size_t)3072*512*2)     // bf16 x (2 MB)
#define Y_OFF    (XBF_OFF + (size_t)T_TOK*DIM*2)  // fp32 Y[3072][1024] (12 MB)
#define WS_FULL  (Y_OFF + (size_t)3072*DIM*4)

__device__ inline float swiglu(float g, float u) {
    float a = fminf(fmaxf(-g, -60.f), 60.f);
    return g * u / (1.0f + __expf(a));
}

// async 16B global->LDS; dst wave-uniform base (HW adds lane*16)
__device__ __forceinline__ void gload_lds16(const void* g, void* l) {
    __builtin_amdgcn_global_load_lds((const __attribute__((address_space(1))) u32*)g,
                                     (__attribute__((address_space(3))) u32*)l, 16, 0, 0);
}

template<int N> __device__ __forceinline__ void waitv() {
    asm volatile("s_waitcnt vmcnt(%0)" :: "n"(N) : "memory");
}
__device__ __forceinline__ void barrier_raw() { __builtin_amdgcn_s_barrier(); }

__device__ __forceinline__ bf16x8 cvt8(float4 a, float4 b) {
    bf16x8 r;
    r[0]=(bf16_t)a.x; r[1]=(bf16_t)a.y; r[2]=(bf16_t)a.z; r[3]=(bf16_t)a.w;
    r[4]=(bf16_t)b.x; r[5]=(bf16_t)b.y; r[6]=(bf16_t)b.z; r[7]=(bf16_t)b.w;
    return r;
}

// A-tile read: bf16 rows of 64 elems (8 x 16B slots), slot q stored at q^(r&7)
__device__ __forceinline__ bf16x8 rdA(const char* L, int r, int q) {
    return *(const bf16x8*)(L + r * 128 + ((q ^ (r & 7)) << 4));
}
// B-tile read: rows of 64 k-elems; fp32 rows = 16 slots (swz r&15), bf16 rows = 8 slots (swz r&7)
template<bool F32>
__device__ __forceinline__ bf16x8 rdB(const char* L, int r, int q) {
    if constexpr (F32) {
        const float* p = (const float*)(L + r * 256);
        float4 a = *(const float4*)(p + ((((2*q)    ) ^ (r & 15)) << 2));
        float4 b = *(const float4*)(p + ((((2*q) + 1) ^ (r & 15)) << 2));
        return cvt8(a, b);
    } else {
        return *(const bf16x8*)(L + r * 128 + ((q ^ (r & 7)) << 4));
    }
}

// ---- runtime-typed loader (fallback only) ----
__device__ inline bf16x8 loadB8r(const void* base, size_t off, bool f32) {
    if (f32) {
        const float4* p = (const float4*)((const float*)base + off);
        return cvt8(p[0], p[1]);
    } else {
        return *(const bf16x8*)((const bf16_t*)base + off);
    }
}

// block-wide fp32-vs-bf16 detect (scan first 4096 halfwords)
__device__ int blk_f32(const void* p, int tid, int* tmp) {
    const unsigned short* h = (const unsigned short*)p;
    unsigned bad = 0;
    for (int i = tid; i < 4096; i += 256) {
        unsigned e = ((unsigned)h[i] >> 7) & 0xFFu;
        if (e >= 0x90u) bad = 1;
    }
    unsigned long long bl = __ballot(bad != 0);
    __syncthreads();
    if ((tid & 63) == 0) tmp[tid >> 6] = (bl != 0ull) ? 1 : 0;
    __syncthreads();
    return tmp[0] | tmp[1] | tmp[2] | tmp[3];
}

// ---------------- prep: router (blocks 0..1023, self-detect) + flags (blocks 1024..1029) ----------------
__global__ __launch_bounds__(256) void prep_kernel(
    const void* __restrict__ x, const void* __restrict__ w_out, const void* __restrict__ w_in,
    const void* __restrict__ wg, const void* __restrict__ wu, const void* __restrict__ wd,
    float* __restrict__ selw_out, int* __restrict__ sel_ids,
    bf16_t* __restrict__ xb, int* __restrict__ flags)
{
    const int b = blockIdx.x;
    const int tid = threadIdx.x;
    __shared__ int tmp[4];
    __shared__ float Ls[24];

    if (b >= T_TOK) {
        const int j = b - T_TOK;
        const void* ps[6] = {x, w_out, w_in, wg, wu, wd};
        const unsigned short* h = (const unsigned short*)ps[j];
        unsigned bad = 0;
        for (int i = tid; i < 4096; i += 256) {
            unsigned e = ((unsigned)h[i] >> 7) & 0xFFu;
            if (e >= 0x90u) bad = 1;
        }
        unsigned long long bl = __ballot(bad != 0);
        if ((tid & 63) == 0) tmp[tid >> 6] = (bl != 0ull) ? 1 : 0;
        __syncthreads();
        if (tid == 0) flags[j] = tmp[0] | tmp[1] | tmp[2] | tmp[3];
        return;
    }

    const bool xf  = blk_f32(x, tid, tmp) != 0;
    const bool gof = blk_f32(w_out, tid, tmp) != 0;
    const bool gif = blk_f32(w_in, tid, tmp) != 0;

    const int wave = tid >> 6, lane = tid & 63;
    const int t = b;

    float xv[16];
    if (xf) {
        const float* xp = (const float*)x + (size_t)t * DIM;
        #pragma unroll
        for (int i = 0; i < 16; i++) xv[i] = xp[lane + 64 * i];
    } else {
        const bf16_t* xp = (const bf16_t*)x + (size_t)t * DIM;
        #pragma unroll
        for (int i = 0; i < 16; i++) xv[i] = (float)xp[lane + 64 * i];
    }

    if (wave == 0 && xb) {
        #pragma unroll
        for (int i = 0; i < 16; i++)
            xb[(size_t)t * DIM + lane + 64 * i] = (bf16_t)xv[i];
    }

    #pragma unroll
    for (int jj = 0; jj < 6; jj++) {
        const int j = wave * 6 + jj;
        const void* gb; int row; bool gf;
        if (j < 8) { gb = w_out; row = j;     gf = gof; }
        else       { gb = w_in;  row = j - 8; gf = gif; }
        float s = 0.f;
        if (gf) {
            const float* gp = (const float*)gb + (size_t)row * DIM;
            #pragma unroll
            for (int i = 0; i < 16; i++) s += xv[i] * gp[lane + 64 * i];
        } else {
            const bf16_t* gp = (const bf16_t*)gb + (size_t)row * DIM;
            #pragma unroll
            for (int i = 0; i < 16; i++) s += xv[i] * (float)gp[lane + 64 * i];
        }
        #pragma unroll
        for (int m = 32; m >= 1; m >>= 1) s += __shfl_xor(s, m, 64);
        if (lane == 0) Ls[j] = s;
    }
    __syncthreads();

    if (tid == 0) {
        const float* logits = Ls;
        float mx = logits[0];
        for (int o = 1; o < 8; o++) mx = fmaxf(mx, logits[o]);
        float p[8];
        for (int o = 0; o < 8; o++) p[o] = __expf(logits[o] - mx);
        int i0 = 0;
        for (int o = 1; o < 8; o++) if (logits[o] > logits[i0]) i0 = o;
        int i1 = (i0 == 0) ? 1 : 0;
        for (int o = 0; o < 8; o++) if (o != i0 && logits[o] > logits[i1]) i1 = o;
        float rsum = p[i0] + p[i1];
        float rw0 = p[i0] / rsum, rw1 = p[i1] / rsum;

        float a0 = logits[8 + i0 * 2], a1 = logits[8 + i0 * 2 + 1];
        int j00 = (a1 > a0) ? 1 : 0;
        float b0 = logits[8 + i1 * 2], b1 = logits[8 + i1 * 2 + 1];
        int j10 = (b1 > b0) ? 1 : 0;

        int   ids[3] = { i0 * 2 + j00, i0 * 2 + (1 - j00), i1 * 2 + j10 };
        float w[3]   = { rw0, rw0, rw1 };

        #pragma unroll
        for (int k = 0; k < 3; k++) {
            selw_out[t * 3 + k] = w[k];
            sel_ids[t * 3 + k]  = ids[k];
        }
    }
}

// ---------------- binning: 16 blocks (1/expert), ballot prefix ----------------
__global__ __launch_bounds__(1024) void bin2_kernel(
    const int* __restrict__ sel_ids,
    int* __restrict__ cnt, int* __restrict__ tok_enc)
{
    const int e = blockIdx.x, tid = threadIdx.x;
    const int wave = tid >> 6, lane = tid & 63;
    __shared__ int wbase[16];

    int my = -1;
    #pragma unroll
    for (int k = 0; k < 3; k++) {
        int id = sel_ids[tid * 3 + k];
        if (id == e) my = tid | (k << 16);
    }
    unsigned long long b = __ballot(my >= 0);
    if (lane == 0) wbase[wave] = __popcll(b);
    __syncthreads();
    if (tid == 0) {
        int s = 0;
        for (int w = 0; w < 16; w++) { int c = wbase[w]; wbase[w] = s; s += c; }
        cnt[e] = s;
    }
    __syncthreads();
    if (my >= 0) {
        int pos = wbase[wave] + __popcll(b & ((1ull << lane) - 1ull));
        if (pos < T_TOK) tok_enc[e * T_TOK + pos] = my;
    }
}

// ================= FULL path: triple-buffered DMA pipeline, BK=64, counted vmcnt =================

// gate+up -> H : grid (ft=8 x 64f, mt=8 x 128tok, e=16); 8 waves (2m x 4f)
template<bool GF, bool UF>
__device__ __forceinline__ void gateup4_body(
    const bf16_t* __restrict__ xb,
    const void* __restrict__ wg, const void* __restrict__ wu,
    const int* __restrict__ cnt, const int* __restrict__ tok_enc,
    bf16_t* __restrict__ H,
    char* Xs, char* Gs, char* Us, int* toks, int* hrow)
{
    const int ft = blockIdx.x, mt = blockIdx.y, e = blockIdx.z;
    int C = cnt[e]; if (C > T_TOK) C = T_TOK; if (C < 0) C = 0;
    if (mt * 128 >= C) return;

    const int tid = threadIdx.x;
    if (tid < 128) {
        int idx = mt * 128 + tid, t = 0, hr = -1;
        if (idx < C) {
            int enc = tok_enc[e * T_TOK + idx];
            int tt = enc & 0xFFFF, kk = (enc >> 16) & 0xFFFF;
            if (tt < T_TOK && kk < 3) { t = tt; hr = tt * 3 + kk; }
        }
        toks[tid] = t; hrow[tid] = hr;
    }
    __syncthreads();

    const int wave = tid >> 6, lane = tid & 63;
    const int mh = wave >> 2, fq = wave & 3;
    const int rsel = lane & 15, kq = lane >> 4;

    constexpr int NC  = 16;                 // K/64 chunks
    constexpr int NG  = GF ? 2 : 1;
    constexpr int NU  = UF ? 2 : 1;
    constexpr int PER = 2 + NG + NU;        // DMAs per wave per chunk
    constexpr int GSTR = GF ? 16384 : 8192;
    constexpr int USTR = UF ? 16384 : 8192;
    const int wrow0 = e * FF + ft * 64;

    // precomputed per-lane source base pointers (inverse-swizzled)
    const bf16_t* px[2];
    #pragma unroll
    for (int j = 0; j < 2; j++) {
        int n = (j * 8 + wave) * 64 + lane, r = n >> 3, s = n & 7;
        px[j] = xb + (size_t)toks[r] * DIM + ((s ^ (r & 7)) << 3);
    }
    const float*  pgf[2]; const bf16_t* pgh = nullptr;
    const float*  puf[2]; const bf16_t* puh = nullptr;
    if constexpr (GF) {
        #pragma unroll
        for (int j = 0; j < 2; j++) {
            int n = (j * 8 + wave) * 64 + lane, r = n >> 4, s = n & 15;
            pgf[j] = (const float*)wg + (size_t)(wrow0 + r) * DIM + ((s ^ (r & 15)) << 2);
        }
    } else {
        int n = wave * 64 + lane, r = n >> 3, s = n & 7;
        pgh = (const bf16_t*)wg + (size_t)(wrow0 + r) * DIM + ((s ^ (r & 7)) << 3);
    }
    if constexpr (UF) {
        #pragma unroll
        for (int j = 0; j < 2; j++) {
            int n = (j * 8 + wave) * 64 + lane, r = n >> 4, s = n & 15;
            puf[j] = (const float*)wu + (size_t)(wrow0 + r) * DIM + ((s ^ (r & 15)) << 2);
        }
    } else {
        int n = wave * 64 + lane, r = n >> 3, s = n & 7;
        puh = (const bf16_t*)wu + (size_t)(wrow0 + r) * DIM + ((s ^ (r & 7)) << 3);
    }

    auto issue = [&](int kc) {
        const int buf = kc % 3;
        #pragma unroll
        for (int j = 0; j < 2; j++)
            gload_lds16(px[j] + kc * 64, Xs + buf * 16384 + (j * 8 + wave) * 1024);
        if constexpr (GF) {
            #pragma unroll
            for (int j = 0; j < 2; j++)
                gload_lds16(pgf[j] + kc * 64, Gs + buf * GSTR + (j * 8 + wave) * 1024);
        } else {
            gload_lds16(pgh + kc * 64, Gs + buf * GSTR + wave * 1024);
        }
        if constexpr (UF) {
            #pragma unroll
            for (int j = 0; j < 2; j++)
                gload_lds16(puf[j] + kc * 64, Us + buf * USTR + (j * 8 + wave) * 1024);
        } else {
            gload_lds16(puh + kc * 64, Us + buf * USTR + wave * 1024);
        }
    };

    floatx4 ag[4], au[4];
    #pragma unroll
    for (int ms = 0; ms < 4; ms++) { ag[ms] = (floatx4){0,0,0,0}; au[ms] = (floatx4){0,0,0,0}; }

    issue(0);
    issue(1);

    #pragma unroll
    for (int kc = 0; kc < NC; kc++) {
        if (kc + 2 < NC) issue(kc + 2);
        if (kc + 2 < NC)      waitv<2 * PER>();
        else if (kc + 1 < NC) waitv<PER>();
        else                  waitv<0>();
        barrier_raw();
        __builtin_amdgcn_sched_barrier(0);

        const char* X = Xs + (kc % 3) * 16384;
        const char* G = Gs + (kc % 3) * GSTR;
        const char* U = Us + (kc % 3) * USTR;
        #pragma unroll
        for (int i = 0; i < 2; i++) {
            const int q = i * 4 + kq;
            bf16x8 a[4];
            #pragma unroll
            for (int ms = 0; ms < 4; ms++) a[ms] = rdA(X, mh * 64 + ms * 16 + rsel, q);
            bf16x8 bg = rdB<GF>(G, fq * 16 + rsel, q);
            bf16x8 bu = rdB<UF>(U, fq * 16 + rsel, q);
            #pragma unroll
            for (int ms = 0; ms < 4; ms++) {
                ag[ms] = __builtin_amdgcn_mfma_f32_16x16x32_bf16(a[ms], bg, ag[ms], 0, 0, 0);
                au[ms] = __builtin_amdgcn_mfma_f32_16x16x32_bf16(a[ms], bu, au[ms], 0, 0, 0);
            }
        }
        barrier_raw();
    }

    const int f = ft * 64 + fq * 16 + rsel;
    #pragma unroll
    for (int ms = 0; ms < 4; ms++)
        #pragma unroll
        for (int r = 0; r < 4; r++) {
            int m = mh * 64 + ms * 16 + kq * 4 + r;
            int hr = hrow[m];
            if (hr >= 0)
                H[(size_t)hr * FF + f] = (bf16_t)swiglu(ag[ms][r], au[ms][r]);
        }
}

__global__ __launch_bounds__(512, 1) void gateup4_kernel(
    const bf16_t* __restrict__ xb,
    const void* __restrict__ wg, const void* __restrict__ wu,
    const int* __restrict__ flags, const int* __restrict__ cnt,
    const int* __restrict__ tok_enc, bf16_t* __restrict__ H)
{
    __shared__ __align__(16) char Xs[3 * 16384];   // 48 KB
    __shared__ __align__(16) char Gs[3 * 16384];   // 48 KB (fp32 worst case)
    __shared__ __align__(16) char Us[3 * 16384];   // 48 KB
    __shared__ int toks[128];
    __shared__ int hrow[128];
    const bool gf = flags[3] != 0, uf = flags[4] != 0;
    if (gf) {
        if (uf) gateup4_body<true,  true >(xb, wg, wu, cnt, tok_enc, H, Xs, Gs, Us, toks, hrow);
        else    gateup4_body<true,  false>(xb, wg, wu, cnt, tok_enc, H, Xs, Gs, Us, toks, hrow);
    } else {
        if (uf) gateup4_body<false, true >(xb, wg, wu, cnt, tok_enc, H, Xs, Gs, Us, toks, hrow);
        else    gateup4_body<false, false>(xb, wg, wu, cnt, tok_enc, H, Xs, Gs, Us, toks, hrow);
    }
}

// down-proj -> Y : grid (dt=8 x 128d, mt=8 x 128tok, e=16); 8 waves (2m x 4d)
template<bool DF>
__device__ __forceinline__ void down4_body(
    const void* __restrict__ wd,
    const int* __restrict__ cnt, const int* __restrict__ tok_enc,
    const bf16_t* __restrict__ H, float* __restrict__ Y,
    char* Hs, char* Ds, int* hsrc, int* hdst)
{
    const int dt = blockIdx.x, mt = blockIdx.y, e = blockIdx.z;
    int C = cnt[e]; if (C > T_TOK) C = T_TOK; if (C < 0) C = 0;
    if (mt * 128 >= C) return;

    const int tid = threadIdx.x;
    if (tid < 128) {
        int idx = mt * 128 + tid, hr = -1;
        if (idx < C) {
            int enc = tok_enc[e * T_TOK + idx];
            int tt = enc & 0xFFFF, kk = (enc >> 16) & 0xFFFF;
            if (tt < T_TOK && kk < 3) hr = tt * 3 + kk;
        }
        hsrc[tid] = (hr >= 0) ? hr : 0;
        hdst[tid] = hr;
    }
    __syncthreads();

    const int wave = tid >> 6, lane = tid & 63;
    const int mh = wave >> 2, dq = wave & 3;
    const int rsel = lane & 15, kq = lane >> 4;

    constexpr int NC  = 8;                  // FF/64 chunks
    constexpr int ND  = DF ? 4 : 2;
    constexpr int PER = 2 + ND;
    constexpr int DSTR = DF ? 32768 : 16384;
    const int wrow0 = e * DIM + dt * 128;

    const bf16_t* ph[2];
    #pragma unroll
    for (int j = 0; j < 2; j++) {
        int n = (j * 8 + wave) * 64 + lane, r = n >> 3, s = n & 7;
        ph[j] = H + (size_t)hsrc[r] * FF + ((s ^ (r & 7)) << 3);
    }
    const float*  pdf[4]; const bf16_t* pdh[2];
    if constexpr (DF) {
        #pragma unroll
        for (int j = 0; j < 4; j++) {
            int n = (j * 8 + wave) * 64 + lane, r = n >> 4, s = n & 15;
            pdf[j] = (const float*)wd + (size_t)(wrow0 + r) * FF + ((s ^ (r & 15)) << 2);
        }
    } else {
        #pragma unroll
        for (int j = 0; j < 2; j++) {
            int n = (j * 8 + wave) * 64 + lane, r = n >> 3, s = n & 7;
            pdh[j] = (const bf16_t*)wd + (size_t)(wrow0 + r) * FF + ((s ^ (r & 7)) << 3);
        }
    }

    auto issue = [&](int kc) {
        const int buf = kc % 3;
        #pragma unroll
        for (int j = 0; j < 2; j++)
            gload_lds16(ph[j] + kc * 64, Hs + buf * 16384 + (j * 8 + wave) * 1024);
        if constexpr (DF) {
            #pragma unroll
            for (int j = 0; j < 4; j++)
                gload_lds16(pdf[j] + kc * 64, Ds + buf * DSTR + (j * 8 + wave) * 1024);
        } else {
            #pragma unroll
            for (int j = 0; j < 2; j++)
                gload_lds16(pdh[j] + kc * 64, Ds + buf * DSTR + (j * 8 + wave) * 1024);
        }
    };

    floatx4 acc[4][2];
    #pragma unroll
    for (int ms = 0; ms < 4; ms++)
        #pragma unroll
        for (int nt = 0; nt < 2; nt++) acc[ms][nt] = (floatx4){0,0,0,0};

    issue(0);
    issue(1);

    #pragma unroll
    for (int kc = 0; kc < NC; kc++) {
        if (kc + 2 < NC) issue(kc + 2);
        if (kc + 2 < NC)      waitv<2 * PER>();
        else if (kc + 1 < NC) waitv<PER>();
        else                  waitv<0>();
        barrier_raw();
        __builtin_amdgcn_sched_barrier(0);

        const char* Hb = Hs + (kc % 3) * 16384;
        const char* Db = Ds + (kc % 3) * DSTR;
        #pragma unroll
        for (int i = 0; i < 2; i++) {
            const int q = i * 4 + kq;
            bf16x8 a[4], bd[2];
            #pragma unroll
            for (int ms = 0; ms < 4; ms++) a[ms] = rdA(Hb, mh * 64 + ms * 16 + rsel, q);
            #pragma unroll
            for (int nt = 0; nt < 2; nt++) bd[nt] = rdB<DF>(Db, dq * 32 + nt * 16 + rsel, q);
            #pragma unroll
            for (int ms = 0; ms < 4; ms++)
                #pragma unroll
                for (int nt = 0; nt < 2; nt++)
                    acc[ms][nt] = __builtin_amdgcn_mfma_f32_16x16x32_bf16(a[ms], bd[nt], acc[ms][nt], 0, 0, 0);
        }
        barrier_raw();
    }

    #pragma unroll
    for (int ms = 0; ms < 4; ms++)
        #pragma unroll
        for (int nt = 0; nt < 2; nt++)
            #pragma unroll
            for (int r = 0; r < 4; r++) {
                int m = mh * 64 + ms * 16 + kq * 4 + r;
                int hr = hdst[m];
                if (hr >= 0)
                    Y[(size_t)hr * DIM + dt * 128 + dq * 32 + nt * 16 + rsel] = acc[ms][nt][r];
            }
}

__global__ __launch_bounds__(512, 1) void down4_kernel(
    const void* __restrict__ wd,
    const int* __restrict__ flags, const int* __restrict__ cnt,
    const int* __restrict__ tok_enc,
    const bf16_t* __restrict__ H, float* __restrict__ Y)
{
    __shared__ __align__(16) char Hs[3 * 16384];   // 48 KB
    __shared__ __align__(16) char Ds[3 * 32768];   // 96 KB (fp32 worst case)
    __shared__ int hsrc[128];
    __shared__ int hdst[128];
    const bool df = flags[5] != 0;
    if (df) down4_body<true >(wd, cnt, tok_enc, H, Y, Hs, Ds, hsrc, hdst);
    else    down4_body<false>(wd, cnt, tok_enc, H, Y, Hs, Ds, hsrc, hdst);
}

// weighted combine: out[t][d] = sum_k selw[t,k] * Y[t*3+k][d]
__global__ __launch_bounds__(256) void combine_kernel(
    const float* __restrict__ Y, const float* __restrict__ selw,
    float* __restrict__ outp)
{
    int idx = blockIdx.x * 256 + threadIdx.x;
    int t = idx >> 8;
    int d = (idx & 255) * 4;
    float w0 = selw[t * 3 + 0], w1 = selw[t * 3 + 1], w2 = selw[t * 3 + 2];
    float4 y0 = *(const float4*)(Y + (size_t)(t * 3 + 0) * DIM + d);
    float4 y1 = *(const float4*)(Y + (size_t)(t * 3 + 1) * DIM + d);
    float4 y2 = *(const float4*)(Y + (size_t)(t * 3 + 2) * DIM + d);
    float4 o;
    o.x = w0 * y0.x + w1 * y1.x + w2 * y2.x;
    o.y = w0 * y0.y + w1 * y1.y + w2 * y2.y;
    o.z = w0 * y0.z + w1 * y1.z + w2 * y2.z;
    o.w = w0 * y0.w + w1 * y1.w + w2 * y2.w;
    *(float4*)(outp + (size_t)t * DIM + d) = o;
}

// ---------------- fallback fused FFN ----------------
__global__ __launch_bounds__(256) void ffn_kernel(
    const void* __restrict__ x,
    const void* __restrict__ wg, const void* __restrict__ wu, const void* __restrict__ wd,
    const int* __restrict__ flags, const int* __restrict__ cnt, const int* __restrict__ tok_enc,
    const float* __restrict__ selw, float* __restrict__ outp)
{
    const int e = blockIdx.x, tile = blockIdx.y;
    int C = cnt[e]; if (C > T_TOK) C = T_TOK; if (C < 0) C = 0;
    if (tile * 16 >= C) return;
    const bool xf = flags[0] != 0, gf = flags[3] != 0, uf = flags[4] != 0, df = flags[5] != 0;

    __shared__ __align__(16) bf16_t Xs[16][1032];
    __shared__ __align__(16) bf16_t Hs[16][520];
    __shared__ int toks[16];
    __shared__ float wts[16];
    const int tid = threadIdx.x;
    if (tid < 16) {
        int idx = tile * 16 + tid, t = -1; float w = 0.f;
        if (idx < C) {
            int enc = tok_enc[e * T_TOK + idx];
            int tt = enc & 0xFFFF, kk = (enc >> 16) & 0xFFFF;
            if (tt < T_TOK && kk < 3) { t = tt; w = selw[tt * 3 + kk]; }
        }
        toks[tid] = t; wts[tid] = w;
    }
    __syncthreads();
    {
        int row = tid >> 4, chunk = tid & 15;
        int t = toks[row];
        bf16x8* dst = (bf16x8*)&Xs[row][chunk * 64];
        if (t >= 0) {
            #pragma unroll
            for (int i = 0; i < 8; i++)
                dst[i] = loadB8r(x, (size_t)t * DIM + chunk * 64 + i * 8, xf);
        } else {
            bf16x8 z;
            #pragma unroll
            for (int kz = 0; kz < 8; kz++) z[kz] = (bf16_t)0.0f;
            #pragma unroll
            for (int i = 0; i < 8; i++) dst[i] = z;
        }
    }
    __syncthreads();

    const int wave = tid >> 6, lane = tid & 63;
    const int rsel = lane & 15, kq = lane >> 4;
    const size_t eoffF = (size_t)e * FF * DIM;
    for (int nt = 0; nt < 8; nt++) {
        const int f0 = wave * 128 + nt * 16;
        const size_t boff = eoffF + (size_t)(f0 + rsel) * DIM + kq * 8;
        const bf16_t* ap = &Xs[rsel][kq * 8];
        floatx4 accg = {0.f,0.f,0.f,0.f};
        floatx4 accu = {0.f,0.f,0.f,0.f};
        for (int k0 = 0; k0 < DIM; k0 += 32) {
            bf16x8 a  = *(const bf16x8*)(ap + k0);
            bf16x8 bg = loadB8r(wg, boff + k0, gf);
            bf16x8 bu = loadB8r(wu, boff + k0, uf);
            accg = __builtin_amdgcn_mfma_f32_16x16x32_bf16(a, bg, accg, 0, 0, 0);
            accu = __builtin_amdgcn_mfma_f32_16x16x32_bf16(a, bu, accu, 0, 0, 0);
        }
        #pragma unroll
        for (int r = 0; r < 4; r++)
            Hs[kq * 4 + r][f0 + rsel] = (bf16_t)swiglu(accg[r], accu[r]);
    }
    __syncthreads();
    const size_t eoffD = (size_t)e * DIM * FF;
    for (int nt = 0; nt < 16; nt++) {
        const int d0 = wave * 256 + nt * 16;
        const size_t boff = eoffD + (size_t)(d0 + rsel) * FF + kq * 8;
        const bf16_t* ap = &Hs[rsel][kq * 8];
        floatx4 acc = {0.f,0.f,0.f,0.f};
        for (int k0 = 0; k0 < FF; k0 += 32) {
            bf16x8 a = *(const bf16x8*)(ap + k0);
            bf16x8 b = loadB8r(wd, boff + k0, df);
            acc = __builtin_amdgcn_mfma_f32_16x16x32_bf16(a, b, acc, 0, 0, 0);
        }
        #pragma unroll
        for (int r = 0; r < 4; r++) {
            int m = kq * 4 + r, t = toks[m];
            if (t >= 0) atomicAdd(outp + (size_t)t * DIM + d0 + rsel, acc[r] * wts[m]);
        }
    }
}

extern "C" void kernel_launch(void* const* d_in, const int* in_sizes, int n_in,
                              void* d_out, int out_size, void* d_ws, size_t ws_size,
                              hipStream_t stream)
{
    const void* x     = d_in[0];
    const void* w_out = d_in[1];
    const void* w_in  = d_in[2];
    const void* wg    = d_in[3];
    const void* wu    = d_in[4];
    const void* wd    = d_in[5];
    float* out  = (float*)d_out;
    float* selw = out + (size_t)T_TOK * DIM;

    char* ws = (char*)d_ws;
    int*    flags = (int*)(ws + FLAG_OFF);
    int*    cnt   = (int*)(ws + CNT_OFF);
    int*    tok   = (int*)(ws + TOK_OFF);
    int*    sel   = (int*)(ws + SEL_OFF);
    bf16_t* H     = (bf16_t*)(ws + H_OFF);
    bf16_t* xbf   = (bf16_t*)(ws + XBF_OFF);
    float*  Y     = (float*)(ws + Y_OFF);

    const bool full = ws_size >= (size_t)WS_FULL;

    if (!full)
        hipMemsetAsync(out, 0, (size_t)T_TOK * DIM * sizeof(float), stream);

    prep_kernel<<<dim3(T_TOK + 6), dim3(256), 0, stream>>>(
        x, w_out, w_in, wg, wu, wd, selw, sel, full ? xbf : (bf16_t*)nullptr, flags);

    bin2_kernel<<<dim3(NEXP), dim3(1024), 0, stream>>>(sel, cnt, tok);

    if (full) {
        gateup4_kernel<<<dim3(8, 8, 16), dim3(512), 0, stream>>>(
            xbf, wg, wu, flags, cnt, tok, H);
        down4_kernel<<<dim3(8, 8, 16), dim3(512), 0, stream>>>(
            wd, flags, cnt, tok, H, Y);
        combine_kernel<<<dim3(T_TOK * DIM / 1024), dim3(256), 0, stream>>>(Y, selw, out);
    } else {
        ffn_kernel<<<dim3(NEXP, 64), dim3(256), 0, stream>>>(
            x, wg, wu, wd, flags, cnt, tok, selw, out);
    }
}

// Round 7
// 191.779 us; speedup vs baseline: 1.9426x; 1.0507x over previous
//
#include <hip/hip_runtime.h>
#include <hip/hip_bf16.h>

typedef __bf16 bf16_t;
typedef __bf16 bf16x8 __attribute__((ext_vector_type(8)));
typedef float floatx4 __attribute__((ext_vector_type(4)));
typedef unsigned int u32;

#define T_TOK 1024
#define DIM   1024
#define FF    512
#define NEXP  16

// ws layout
#define FLAG_OFF 0                 // int[6]
#define CNT_OFF  64                // int[16]
#define TOK_OFF  256               // int[16*1024]
#define SEL_OFF  65792             // int[1024*3]
#define H_OFF    78080             // bf16[3072][512] (3 MB)
#define XBF_OFF  (H_OFF + (size_t)3072*512*2)        // bf16 x (2 MB)
#define WGB_OFF  (XBF_OFF + (size_t)T_TOK*DIM*2)     // bf16 wg (16 MB)
#define WUB_OFF  (WGB_OFF + (size_t)NEXP*FF*DIM*2)   // bf16 wu (16 MB)
#define WDB_OFF  (WUB_OFF + (size_t)NEXP*FF*DIM*2)   // bf16 wd (16 MB)
#define Y_OFF    (WDB_OFF + (size_t)NEXP*DIM*FF*2)   // fp32 Y[3072][1024] (12 MB)
#define WS_FULL  (Y_OFF + (size_t)3072*DIM*4)

__device__ inline float swiglu(float g, float u) {
    float a = fminf(fmaxf(-g, -60.f), 60.f);
    return g * u / (1.0f + __expf(a));
}

// async 16B global->LDS; dst wave-uniform base (HW adds lane*16)
__device__ __forceinline__ void gload_lds16(const void* g, void* l) {
    __builtin_amdgcn_global_load_lds((const __attribute__((address_space(1))) u32*)g,
                                     (__attribute__((address_space(3))) u32*)l, 16, 0, 0);
}

template<int N> __device__ __forceinline__ void waitv() {
    asm volatile("s_waitcnt vmcnt(%0)" :: "n"(N) : "memory");
}
__device__ __forceinline__ void barrier_raw() { __builtin_amdgcn_s_barrier(); }

__device__ __forceinline__ bf16x8 cvt8(float4 a, float4 b) {
    bf16x8 r;
    r[0]=(bf16_t)a.x; r[1]=(bf16_t)a.y; r[2]=(bf16_t)a.z; r[3]=(bf16_t)a.w;
    r[4]=(bf16_t)b.x; r[5]=(bf16_t)b.y; r[6]=(bf16_t)b.z; r[7]=(bf16_t)b.w;
    return r;
}

// bf16 tile read: row stride 128 B (64 elems), 16B slot q stored at q^(r&7)
__device__ __forceinline__ bf16x8 rdT(const char* L, int r, int q) {
    return *(const bf16x8*)(L + r * 128 + ((q ^ (r & 7)) << 4));
}

// ---- runtime-typed loader (fallback only) ----
__device__ inline bf16x8 loadB8r(const void* base, size_t off, bool f32) {
    if (f32) {
        const float4* p = (const float4*)((const float*)base + off);
        return cvt8(p[0], p[1]);
    } else {
        return *(const bf16x8*)((const bf16_t*)base + off);
    }
}

// block-wide fp32-vs-bf16 detect (scan first 4096 halfwords)
__device__ int blk_f32(const void* p, int tid, int* tmp) {
    const unsigned short* h = (const unsigned short*)p;
    unsigned bad = 0;
    for (int i = tid; i < 4096; i += 256) {
        unsigned e = ((unsigned)h[i] >> 7) & 0xFFu;
        if (e >= 0x90u) bad = 1;
    }
    unsigned long long bl = __ballot(bad != 0);
    __syncthreads();
    if ((tid & 63) == 0) tmp[tid >> 6] = (bl != 0ull) ? 1 : 0;
    __syncthreads();
    return tmp[0] | tmp[1] | tmp[2] | tmp[3];
}

// ---------------- prep2: router [0,1024) + flags [1024,1030) + weight-cvt [1030,...) ----------------
__global__ __launch_bounds__(256) void prep2_kernel(
    const void* __restrict__ x, const void* __restrict__ w_out, const void* __restrict__ w_in,
    const void* __restrict__ wg, const void* __restrict__ wu, const void* __restrict__ wd,
    float* __restrict__ selw_out, int* __restrict__ sel_ids,
    bf16_t* __restrict__ xb, int* __restrict__ flags,
    bf16_t* __restrict__ wgb, bf16_t* __restrict__ wub, bf16_t* __restrict__ wdb)
{
    const int b = blockIdx.x;
    const int tid = threadIdx.x;
    __shared__ int tmp[4];
    __shared__ float Ls[24];

    if (b >= T_TOK + 6) {
        // weight fp32->bf16 convert; self-detect from first 8KB of the tensor
        const int c = b - (T_TOK + 6);
        const int z = c >> 12, i = c & 4095;
        const void* src; bf16_t* dst;
        if (z == 0)      { src = wg; dst = wgb; }
        else if (z == 1) { src = wu; dst = wub; }
        else             { src = wd; dst = wdb; }
        const unsigned short* h = (const unsigned short*)src;
        unsigned bad = 0;
        for (int k = tid; k < 4096; k += 256) {
            unsigned ex = ((unsigned)h[k] >> 7) & 0xFFu;
            if (ex >= 0x90u) bad = 1;
        }
        unsigned long long bl = __ballot(bad != 0);
        if ((tid & 63) == 0) tmp[tid >> 6] = (bl != 0ull) ? 1 : 0;
        __syncthreads();
        if (!(tmp[0] | tmp[1] | tmp[2] | tmp[3])) return;   // already bf16
        size_t off = ((size_t)i * 256 + tid) * 8;
        const float4* p = (const float4*)((const float*)src + off);
        float4 a = p[0], bb = p[1];
        *(bf16x8*)(dst + off) = cvt8(a, bb);
        return;
    }

    if (b >= T_TOK) {
        const int j = b - T_TOK;
        const void* ps[6] = {x, w_out, w_in, wg, wu, wd};
        const unsigned short* h = (const unsigned short*)ps[j];
        unsigned bad = 0;
        for (int i = tid; i < 4096; i += 256) {
            unsigned e = ((unsigned)h[i] >> 7) & 0xFFu;
            if (e >= 0x90u) bad = 1;
        }
        unsigned long long bl = __ballot(bad != 0);
        if ((tid & 63) == 0) tmp[tid >> 6] = (bl != 0ull) ? 1 : 0;
        __syncthreads();
        if (tid == 0) flags[j] = tmp[0] | tmp[1] | tmp[2] | tmp[3];
        return;
    }

    // ---- router for token b ----
    const bool xf  = blk_f32(x, tid, tmp) != 0;
    const bool gof = blk_f32(w_out, tid, tmp) != 0;
    const bool gif = blk_f32(w_in, tid, tmp) != 0;

    const int wave = tid >> 6, lane = tid & 63;
    const int t = b;

    float xv[16];
    if (xf) {
        const float* xp = (const float*)x + (size_t)t * DIM;
        #pragma unroll
        for (int i = 0; i < 16; i++) xv[i] = xp[lane + 64 * i];
    } else {
        const bf16_t* xp = (const bf16_t*)x + (size_t)t * DIM;
        #pragma unroll
        for (int i = 0; i < 16; i++) xv[i] = (float)xp[lane + 64 * i];
    }

    if (wave == 0 && xb) {
        #pragma unroll
        for (int i = 0; i < 16; i++)
            xb[(size_t)t * DIM + lane + 64 * i] = (bf16_t)xv[i];
    }

    #pragma unroll
    for (int jj = 0; jj < 6; jj++) {
        const int j = wave * 6 + jj;
        const void* gb; int row; bool gf;
        if (j < 8) { gb = w_out; row = j;     gf = gof; }
        else       { gb = w_in;  row = j - 8; gf = gif; }
        float s = 0.f;
        if (gf) {
            const float* gp = (const float*)gb + (size_t)row * DIM;
            #pragma unroll
            for (int i = 0; i < 16; i++) s += xv[i] * gp[lane + 64 * i];
        } else {
            const bf16_t* gp = (const bf16_t*)gb + (size_t)row * DIM;
            #pragma unroll
            for (int i = 0; i < 16; i++) s += xv[i] * (float)gp[lane + 64 * i];
        }
        #pragma unroll
        for (int m = 32; m >= 1; m >>= 1) s += __shfl_xor(s, m, 64);
        if (lane == 0) Ls[j] = s;
    }
    __syncthreads();

    if (tid == 0) {
        const float* logits = Ls;
        float mx = logits[0];
        for (int o = 1; o < 8; o++) mx = fmaxf(mx, logits[o]);
        float p[8];
        for (int o = 0; o < 8; o++) p[o] = __expf(logits[o] - mx);
        int i0 = 0;
        for (int o = 1; o < 8; o++) if (logits[o] > logits[i0]) i0 = o;
        int i1 = (i0 == 0) ? 1 : 0;
        for (int o = 0; o < 8; o++) if (o != i0 && logits[o] > logits[i1]) i1 = o;
        float rsum = p[i0] + p[i1];
        float rw0 = p[i0] / rsum, rw1 = p[i1] / rsum;

        float a0 = logits[8 + i0 * 2], a1 = logits[8 + i0 * 2 + 1];
        int j00 = (a1 > a0) ? 1 : 0;
        float b0 = logits[8 + i1 * 2], b1 = logits[8 + i1 * 2 + 1];
        int j10 = (b1 > b0) ? 1 : 0;

        int   ids[3] = { i0 * 2 + j00, i0 * 2 + (1 - j00), i1 * 2 + j10 };
        float w[3]   = { rw0, rw0, rw1 };

        #pragma unroll
        for (int k = 0; k < 3; k++) {
            selw_out[t * 3 + k] = w[k];
            sel_ids[t * 3 + k]  = ids[k];
        }
    }
}

// ---------------- binning: 16 blocks (1/expert), ballot prefix ----------------
__global__ __launch_bounds__(1024) void bin2_kernel(
    const int* __restrict__ sel_ids,
    int* __restrict__ cnt, int* __restrict__ tok_enc)
{
    const int e = blockIdx.x, tid = threadIdx.x;
    const int wave = tid >> 6, lane = tid & 63;
    __shared__ int wbase[16];

    int my = -1;
    #pragma unroll
    for (int k = 0; k < 3; k++) {
        int id = sel_ids[tid * 3 + k];
        if (id == e) my = tid | (k << 16);
    }
    unsigned long long b = __ballot(my >= 0);
    if (lane == 0) wbase[wave] = __popcll(b);
    __syncthreads();
    if (tid == 0) {
        int s = 0;
        for (int w = 0; w < 16; w++) { int c = wbase[w]; wbase[w] = s; s += c; }
        cnt[e] = s;
    }
    __syncthreads();
    if (my >= 0) {
        int pos = wbase[wave] + __popcll(b & ((1ull << lane) - 1ull));
        if (pos < T_TOK) tok_enc[e * T_TOK + pos] = my;
    }
}

// ================= FULL path: bf16 DMA pipeline, 73 KB LDS, 2 blocks/CU =================

// gate+up -> H : grid (ft=16 x 32f, mt=8 x 128tok, e=16); 8 waves = 4mh x 2fq
__global__ __launch_bounds__(512, 4) void gateup5_kernel(
    const bf16_t* __restrict__ xb,
    const void* __restrict__ wg, const void* __restrict__ wu,
    const bf16_t* __restrict__ wgb, const bf16_t* __restrict__ wub,
    const int* __restrict__ flags, const int* __restrict__ cnt,
    const int* __restrict__ tok_enc, bf16_t* __restrict__ H)
{
    __shared__ __align__(16) char Xs[3 * 16384];   // 48 KB
    __shared__ __align__(16) char Gs[3 * 4096];    // 12 KB
    __shared__ __align__(16) char Us[3 * 4096];    // 12 KB
    __shared__ int toks[128];
    __shared__ int hrow[128];

    const int ft = blockIdx.x, mt = blockIdx.y, e = blockIdx.z;
    int C = cnt[e]; if (C > T_TOK) C = T_TOK; if (C < 0) C = 0;
    if (mt * 128 >= C) return;

    const bf16_t* wgp = (flags[3] != 0) ? wgb : (const bf16_t*)wg;
    const bf16_t* wup = (flags[4] != 0) ? wub : (const bf16_t*)wu;

    const int tid = threadIdx.x;
    if (tid < 128) {
        int idx = mt * 128 + tid, t = 0, hr = -1;
        if (idx < C) {
            int enc = tok_enc[e * T_TOK + idx];
            int tt = enc & 0xFFFF, kk = (enc >> 16) & 0xFFFF;
            if (tt < T_TOK && kk < 3) { t = tt; hr = tt * 3 + kk; }
        }
        toks[tid] = t; hrow[tid] = hr;
    }
    __syncthreads();

    const int wave = tid >> 6, lane = tid & 63;
    const int mh = wave >> 1, fq = wave & 1;
    const int rsel = lane & 15, kq = lane >> 4;

    constexpr int NC  = 16;   // DIM/64
    constexpr int PER = 3;    // DMAs per wave per chunk (2 X + 1 W)

    // X: 2 instr/wave (wave w -> rows 16w..16w+15)
    const bf16_t* px[2];
    #pragma unroll
    for (int j = 0; j < 2; j++) {
        int n = (2 * wave + j) * 64 + lane, r = n >> 3, s = n & 7;
        px[j] = xb + (size_t)toks[r] * DIM + ((s ^ (r & 7)) << 3);
    }
    // W: 1 instr/wave; waves 0-3 -> G rows 8w.., waves 4-7 -> U rows 8(w-4)..
    const bf16_t* pw;
    {
        int wv = wave & 3;
        int n = wv * 64 + lane, r = n >> 3, s = n & 7;
        int row = e * FF + ft * 32 + r;
        pw = (wave < 4 ? wgp : wup) + (size_t)row * DIM + ((s ^ (r & 7)) << 3);
    }
    char* wdst = (wave < 4 ? Gs : Us);
    const int wslot = (wave & 3) * 1024;

    auto issue = [&](int kc) {
        const int buf = kc % 3;
        gload_lds16(px[0] + kc * 64, Xs + buf * 16384 + (2 * wave) * 1024);
        gload_lds16(px[1] + kc * 64, Xs + buf * 16384 + (2 * wave + 1) * 1024);
        gload_lds16(pw + kc * 64, wdst + buf * 4096 + wslot);
    };

    floatx4 ag[2], au[2];
    #pragma unroll
    for (int ms = 0; ms < 2; ms++) { ag[ms] = (floatx4){0,0,0,0}; au[ms] = (floatx4){0,0,0,0}; }

    issue(0);
    issue(1);

    #pragma unroll
    for (int kc = 0; kc < NC; kc++) {
        if (kc + 2 < NC) issue(kc + 2);
        if (kc + 2 < NC)      waitv<2 * PER>();
        else if (kc + 1 < NC) waitv<PER>();
        else                  waitv<0>();
        barrier_raw();
        __builtin_amdgcn_sched_barrier(0);

        const char* X = Xs + (kc % 3) * 16384;
        const char* G = Gs + (kc % 3) * 4096;
        const char* U = Us + (kc % 3) * 4096;
        #pragma unroll
        for (int i = 0; i < 2; i++) {
            const int q = i * 4 + kq;
            bf16x8 a0 = rdT(X, mh * 32 + rsel, q);
            bf16x8 a1 = rdT(X, mh * 32 + 16 + rsel, q);
            bf16x8 bg = rdT(G, fq * 16 + rsel, q);
            bf16x8 bu = rdT(U, fq * 16 + rsel, q);
            ag[0] = __builtin_amdgcn_mfma_f32_16x16x32_bf16(a0, bg, ag[0], 0, 0, 0);
            au[0] = __builtin_amdgcn_mfma_f32_16x16x32_bf16(a0, bu, au[0], 0, 0, 0);
            ag[1] = __builtin_amdgcn_mfma_f32_16x16x32_bf16(a1, bg, ag[1], 0, 0, 0);
            au[1] = __builtin_amdgcn_mfma_f32_16x16x32_bf16(a1, bu, au[1], 0, 0, 0);
        }
        barrier_raw();
    }

    const int f = ft * 32 + fq * 16 + rsel;
    #pragma unroll
    for (int ms = 0; ms < 2; ms++)
        #pragma unroll
        for (int r = 0; r < 4; r++) {
            int m = mh * 32 + ms * 16 + kq * 4 + r;
            int hr = hrow[m];
            if (hr >= 0)
                H[(size_t)hr * FF + f] = (bf16_t)swiglu(ag[ms][r], au[ms][r]);
        }
}

// down-proj -> Y : grid (dt=16 x 64d, mt=8 x 128tok, e=16); 8 waves = 4mh x 2dq
__global__ __launch_bounds__(512, 4) void down5_kernel(
    const void* __restrict__ wd, const bf16_t* __restrict__ wdb,
    const int* __restrict__ flags, const int* __restrict__ cnt,
    const int* __restrict__ tok_enc,
    const bf16_t* __restrict__ H, float* __restrict__ Y)
{
    __shared__ __align__(16) char Hs[3 * 16384];   // 48 KB
    __shared__ __align__(16) char Ds[3 * 8192];    // 24 KB
    __shared__ int hsrc[128];
    __shared__ int hdst[128];

    const int dt = blockIdx.x, mt = blockIdx.y, e = blockIdx.z;
    int C = cnt[e]; if (C > T_TOK) C = T_TOK; if (C < 0) C = 0;
    if (mt * 128 >= C) return;

    const bf16_t* wdp = (flags[5] != 0) ? wdb : (const bf16_t*)wd;

    const int tid = threadIdx.x;
    if (tid < 128) {
        int idx = mt * 128 + tid, hr = -1;
        if (idx < C) {
            int enc = tok_enc[e * T_TOK + idx];
            int tt = enc & 0xFFFF, kk = (enc >> 16) & 0xFFFF;
            if (tt < T_TOK && kk < 3) hr = tt * 3 + kk;
        }
        hsrc[tid] = (hr >= 0) ? hr : 0;
        hdst[tid] = hr;
    }
    __syncthreads();

    const int wave = tid >> 6, lane = tid & 63;
    const int mh = wave >> 1, dq = wave & 1;
    const int rsel = lane & 15, kq = lane >> 4;

    constexpr int NC  = 8;    // FF/64
    constexpr int PER = 3;    // 2 H + 1 D

    const bf16_t* ph[2];
    #pragma unroll
    for (int j = 0; j < 2; j++) {
        int n = (2 * wave + j) * 64 + lane, r = n >> 3, s = n & 7;
        ph[j] = H + (size_t)hsrc[r] * FF + ((s ^ (r & 7)) << 3);
    }
    const bf16_t* pd;
    {
        int n = wave * 64 + lane, r = n >> 3, s = n & 7;
        int row = e * DIM + dt * 64 + r;
        pd = wdp + (size_t)row * FF + ((s ^ (r & 7)) << 3);
    }

    auto issue = [&](int kc) {
        const int buf = kc % 3;
        gload_lds16(ph[0] + kc * 64, Hs + buf * 16384 + (2 * wave) * 1024);
        gload_lds16(ph[1] + kc * 64, Hs + buf * 16384 + (2 * wave + 1) * 1024);
        gload_lds16(pd + kc * 64, Ds + buf * 8192 + wave * 1024);
    };

    floatx4 acc[2][2];
    #pragma unroll
    for (int ms = 0; ms < 2; ms++)
        #pragma unroll
        for (int nt = 0; nt < 2; nt++) acc[ms][nt] = (floatx4){0,0,0,0};

    issue(0);
    issue(1);

    #pragma unroll
    for (int kc = 0; kc < NC; kc++) {
        if (kc + 2 < NC) issue(kc + 2);
        if (kc + 2 < NC)      waitv<2 * PER>();
        else if (kc + 1 < NC) waitv<PER>();
        else                  waitv<0>();
        barrier_raw();
        __builtin_amdgcn_sched_barrier(0);

        const char* Hb = Hs + (kc % 3) * 16384;
        const char* Db = Ds + (kc % 3) * 8192;
        #pragma unroll
        for (int i = 0; i < 2; i++) {
            const int q = i * 4 + kq;
            bf16x8 a0 = rdT(Hb, mh * 32 + rsel, q);
            bf16x8 a1 = rdT(Hb, mh * 32 + 16 + rsel, q);
            bf16x8 b0 = rdT(Db, dq * 32 + rsel, q);
            bf16x8 b1 = rdT(Db, dq * 32 + 16 + rsel, q);
            acc[0][0] = __builtin_amdgcn_mfma_f32_16x16x32_bf16(a0, b0, acc[0][0], 0, 0, 0);
            acc[0][1] = __builtin_amdgcn_mfma_f32_16x16x32_bf16(a0, b1, acc[0][1], 0, 0, 0);
            acc[1][0] = __builtin_amdgcn_mfma_f32_16x16x32_bf16(a1, b0, acc[1][0], 0, 0, 0);
            acc[1][1] = __builtin_amdgcn_mfma_f32_16x16x32_bf16(a1, b1, acc[1][1], 0, 0, 0);
        }
        barrier_raw();
    }

    #pragma unroll
    for (int ms = 0; ms < 2; ms++)
        #pragma unroll
        for (int nt = 0; nt < 2; nt++)
            #pragma unroll
            for (int r = 0; r < 4; r++) {
                int m = mh * 32 + ms * 16 + kq * 4 + r;
                int hr = hdst[m];
                if (hr >= 0)
                    Y[(size_t)hr * DIM + dt * 64 + dq * 32 + nt * 16 + rsel] = acc[ms][nt][r];
            }
}

// weighted combine: out[t][d] = sum_k selw[t,k] * Y[t*3+k][d]
__global__ __launch_bounds__(256) void combine_kernel(
    const float* __restrict__ Y, const float* __restrict__ selw,
    float* __restrict__ outp)
{
    int idx = blockIdx.x * 256 + threadIdx.x;
    int t = idx >> 8;
    int d = (idx & 255) * 4;
    float w0 = selw[t * 3 + 0], w1 = selw[t * 3 + 1], w2 = selw[t * 3 + 2];
    float4 y0 = *(const float4*)(Y + (size_t)(t * 3 + 0) * DIM + d);
    float4 y1 = *(const float4*)(Y + (size_t)(t * 3 + 1) * DIM + d);
    float4 y2 = *(const float4*)(Y + (size_t)(t * 3 + 2) * DIM + d);
    float4 o;
    o.x = w0 * y0.x + w1 * y1.x + w2 * y2.x;
    o.y = w0 * y0.y + w1 * y1.y + w2 * y2.y;
    o.z = w0 * y0.z + w1 * y1.z + w2 * y2.z;
    o.w = w0 * y0.w + w1 * y1.w + w2 * y2.w;
    *(float4*)(outp + (size_t)t * DIM + d) = o;
}

// ---------------- fallback fused FFN ----------------
__global__ __launch_bounds__(256) void ffn_kernel(
    const void* __restrict__ x,
    const void* __restrict__ wg, const void* __restrict__ wu, const void* __restrict__ wd,
    const int* __restrict__ flags, const int* __restrict__ cnt, const int* __restrict__ tok_enc,
    const float* __restrict__ selw, float* __restrict__ outp)
{
    const int e = blockIdx.x, tile = blockIdx.y;
    int C = cnt[e]; if (C > T_TOK) C = T_TOK; if (C < 0) C = 0;
    if (tile * 16 >= C) return;
    const bool xf = flags[0] != 0, gf = flags[3] != 0, uf = flags[4] != 0, df = flags[5] != 0;

    __shared__ __align__(16) bf16_t Xs[16][1032];
    __shared__ __align__(16) bf16_t Hs[16][520];
    __shared__ int toks[16];
    __shared__ float wts[16];
    const int tid = threadIdx.x;
    if (tid < 16) {
        int idx = tile * 16 + tid, t = -1; float w = 0.f;
        if (idx < C) {
            int enc = tok_enc[e * T_TOK + idx];
            int tt = enc & 0xFFFF, kk = (enc >> 16) & 0xFFFF;
            if (tt < T_TOK && kk < 3) { t = tt; w = selw[tt * 3 + kk]; }
        }
        toks[tid] = t; wts[tid] = w;
    }
    __syncthreads();
    {
        int row = tid >> 4, chunk = tid & 15;
        int t = toks[row];
        bf16x8* dst = (bf16x8*)&Xs[row][chunk * 64];
        if (t >= 0) {
            #pragma unroll
            for (int i = 0; i < 8; i++)
                dst[i] = loadB8r(x, (size_t)t * DIM + chunk * 64 + i * 8, xf);
        } else {
            bf16x8 z;
            #pragma unroll
            for (int kz = 0; kz < 8; kz++) z[kz] = (bf16_t)0.0f;
            #pragma unroll
            for (int i = 0; i < 8; i++) dst[i] = z;
        }
    }
    __syncthreads();

    const int wave = tid >> 6, lane = tid & 63;
    const int rsel = lane & 15, kq = lane >> 4;
    const size_t eoffF = (size_t)e * FF * DIM;
    for (int nt = 0; nt < 8; nt++) {
        const int f0 = wave * 128 + nt * 16;
        const size_t boff = eoffF + (size_t)(f0 + rsel) * DIM + kq * 8;
        const bf16_t* ap = &Xs[rsel][kq * 8];
        floatx4 accg = {0.f,0.f,0.f,0.f};
        floatx4 accu = {0.f,0.f,0.f,0.f};
        for (int k0 = 0; k0 < DIM; k0 += 32) {
            bf16x8 a  = *(const bf16x8*)(ap + k0);
            bf16x8 bg = loadB8r(wg, boff + k0, gf);
            bf16x8 bu = loadB8r(wu, boff + k0, uf);
            accg = __builtin_amdgcn_mfma_f32_16x16x32_bf16(a, bg, accg, 0, 0, 0);
            accu = __builtin_amdgcn_mfma_f32_16x16x32_bf16(a, bu, accu, 0, 0, 0);
        }
        #pragma unroll
        for (int r = 0; r < 4; r++)
            Hs[kq * 4 + r][f0 + rsel] = (bf16_t)swiglu(accg[r], accu[r]);
    }
    __syncthreads();
    const size_t eoffD = (size_t)e * DIM * FF;
    for (int nt = 0; nt < 16; nt++) {
        const int d0 = wave * 256 + nt * 16;
        const size_t boff = eoffD + (size_t)(d0 + rsel) * FF + kq * 8;
        const bf16_t* ap = &Hs[rsel][kq * 8];
        floatx4 acc = {0.f,0.f,0.f,0.f};
        for (int k0 = 0; k0 < FF; k0 += 32) {
            bf16x8 a = *(const bf16x8*)(ap + k0);
            bf16x8 b = loadB8r(wd, boff + k0, df);
            acc = __builtin_amdgcn_mfma_f32_16x16x32_bf16(a, b, acc, 0, 0, 0);
        }
        #pragma unroll
        for (int r = 0; r < 4; r++) {
            int m = kq * 4 + r, t = toks[m];
            if (t >= 0) atomicAdd(outp + (size_t)t * DIM + d0 + rsel, acc[r] * wts[m]);
        }
    }
}

extern "C" void kernel_launch(void* const* d_in, const int* in_sizes, int n_in,
                              void* d_out, int out_size, void* d_ws, size_t ws_size,
                              hipStream_t stream)
{
    const void* x     = d_in[0];
    const void* w_out = d_in[1];
    const void* w_in  = d_in[2];
    const void* wg    = d_in[3];
    const void* wu    = d_in[4];
    const void* wd    = d_in[5];
    float* out  = (float*)d_out;
    float* selw = out + (size_t)T_TOK * DIM;

    char* ws = (char*)d_ws;
    int*    flags = (int*)(ws + FLAG_OFF);
    int*    cnt   = (int*)(ws + CNT_OFF);
    int*    tok   = (int*)(ws + TOK_OFF);
    int*    sel   = (int*)(ws + SEL_OFF);
    bf16_t* H     = (bf16_t*)(ws + H_OFF);
    bf16_t* xbf   = (bf16_t*)(ws + XBF_OFF);
    bf16_t* wgb   = (bf16_t*)(ws + WGB_OFF);
    bf16_t* wub   = (bf16_t*)(ws + WUB_OFF);
    bf16_t* wdb   = (bf16_t*)(ws + WDB_OFF);
    float*  Y     = (float*)(ws + Y_OFF);

    const bool full = ws_size >= (size_t)WS_FULL;

    if (!full)
        hipMemsetAsync(out, 0, (size_t)T_TOK * DIM * sizeof(float), stream);

    const int nblk = (T_TOK + 6) + (full ? 3 * 4096 : 0);
    prep2_kernel<<<dim3(nblk), dim3(256), 0, stream>>>(
        x, w_out, w_in, wg, wu, wd, selw, sel,
        full ? xbf : (bf16_t*)nullptr, flags, wgb, wub, wdb);

    bin2_kernel<<<dim3(NEXP), dim3(1024), 0, stream>>>(sel, cnt, tok);

    if (full) {
        gateup5_kernel<<<dim3(16, 8, 16), dim3(512), 0, stream>>>(
            xbf, wg, wu, wgb, wub, flags, cnt, tok, H);
        down5_kernel<<<dim3(16, 8, 16), dim3(512), 0, stream>>>(
            wd, wdb, flags, cnt, tok, H, Y);
        combine_kernel<<<dim3(T_TOK * DIM / 1024), dim3(256), 0, stream>>>(Y, selw, out);
    } else {
        ffn_kernel<<<dim3(NEXP, 64), dim3(256), 0, stream>>>(
            x, wg, wu, wd, flags, cnt, tok, selw, out);
    }
}

// Round 8
// 187.083 us; speedup vs baseline: 1.9914x; 1.0251x over previous
//
#include <hip/hip_runtime.h>
#include <hip/hip_bf16.h>

typedef __bf16 bf16_t;
typedef __bf16 bf16x8 __attribute__((ext_vector_type(8)));
typedef float floatx4 __attribute__((ext_vector_type(4)));
typedef unsigned int u32;

#define T_TOK 1024
#define DIM   1024
#define FF    512
#define NEXP  16

// ws layout
#define FLAG_OFF 0                 // int[6]
#define CNT_OFF  64                // int[16]
#define TOK_OFF  256               // int[16*1024]
#define SEL_OFF  65792             // int[1024*3]
#define H_OFF    78080             // bf16[3072][512] (3 MB)
#define XBF_OFF  (H_OFF + (size_t)3072*512*2)     // bf16 x (2 MB)
#define Y_OFF    (XBF_OFF + (size_t)T_TOK*DIM*2)  // fp32 Y[3072][1024] (12 MB)
#define WS_FULL  (Y_OFF + (size_t)3072*DIM*4)

__device__ inline float swiglu(float g, float u) {
    float a = fminf(fmaxf(-g, -60.f), 60.f);
    return g * u / (1.0f + __expf(a));
}

// async 16B global->LDS; dst wave-uniform base (HW adds lane*16)
__device__ __forceinline__ void gload_lds16(const void* g, void* l) {
    __builtin_amdgcn_global_load_lds((const __attribute__((address_space(1))) u32*)g,
                                     (__attribute__((address_space(3))) u32*)l, 16, 0, 0);
}

template<int N> __device__ __forceinline__ void waitv() {
    asm volatile("s_waitcnt vmcnt(%0)" :: "n"(N) : "memory");
}
__device__ __forceinline__ void barrier_raw() { __builtin_amdgcn_s_barrier(); }

__device__ __forceinline__ bf16x8 cvt8(float4 a, float4 b) {
    bf16x8 r;
    r[0]=(bf16_t)a.x; r[1]=(bf16_t)a.y; r[2]=(bf16_t)a.z; r[3]=(bf16_t)a.w;
    r[4]=(bf16_t)b.x; r[5]=(bf16_t)b.y; r[6]=(bf16_t)b.z; r[7]=(bf16_t)b.w;
    return r;
}

// bf16 tile read: row stride 128 B (8 x 16B slots), slot q stored at q^(r&7)
__device__ __forceinline__ bf16x8 rdT(const char* L, int r, int q) {
    return *(const bf16x8*)(L + r * 128 + ((q ^ (r & 7)) << 4));
}
// weight tile read: fp32 rows = 256B (16 slots, swz r&15) with on-read cvt; bf16 rows = 128B
template<bool F32>
__device__ __forceinline__ bf16x8 rdW(const char* L, int r, int q) {
    if constexpr (F32) {
        const float* p = (const float*)(L + r * 256);
        float4 a = *(const float4*)(p + ((((2 * q)    ) ^ (r & 15)) << 2));
        float4 b = *(const float4*)(p + ((((2 * q) + 1) ^ (r & 15)) << 2));
        return cvt8(a, b);
    } else {
        return *(const bf16x8*)(L + r * 128 + ((q ^ (r & 7)) << 4));
    }
}

// ---- runtime-typed loader (router + fallback) ----
__device__ inline bf16x8 loadB8r(const void* base, size_t off, bool f32) {
    if (f32) {
        const float4* p = (const float4*)((const float*)base + off);
        return cvt8(p[0], p[1]);
    } else {
        return *(const bf16x8*)((const bf16_t*)base + off);
    }
}

// ---------------- per-input dtype detect ----------------
__global__ __launch_bounds__(64) void detect_kernel(
    const void* p0, const void* p1, const void* p2,
    const void* p3, const void* p4, const void* p5,
    int* __restrict__ flags)
{
    const void* ps[6] = {p0, p1, p2, p3, p4, p5};
    int j = blockIdx.x;
    int lane = threadIdx.x;
    const unsigned short* h = (const unsigned short*)ps[j];
    unsigned int bad = 0;
    for (int i = lane; i < 4096; i += 64) {
        unsigned int e = ((unsigned int)h[i] >> 7) & 0xFFu;
        if (e >= 0x90u) bad = 1;
    }
    unsigned long long b = __ballot(bad);
    if (lane == 0) flags[j] = (b != 0ull) ? 1 : 0;
}

// ---------------- Router: 1 token/block, 24 logits split over 4 waves ----------------
__global__ __launch_bounds__(256) void router4_kernel(
    const void* __restrict__ x,
    const void* __restrict__ w_out,
    const void* __restrict__ w_in,
    float* __restrict__ selw_out,
    const int* __restrict__ flags,
    int* __restrict__ sel_ids,
    bf16_t* __restrict__ xb)
{
    const bool xf  = flags[0] != 0;
    const bool gof = flags[1] != 0;
    const bool gif = flags[2] != 0;
    const int tid = threadIdx.x;
    const int wave = tid >> 6, lane = tid & 63;
    const int t = blockIdx.x;

    __shared__ float Ls[24];

    float xv[16];
    if (xf) {
        const float* xp = (const float*)x + (size_t)t * DIM;
        #pragma unroll
        for (int i = 0; i < 16; i++) xv[i] = xp[lane + 64 * i];
    } else {
        const bf16_t* xp = (const bf16_t*)x + (size_t)t * DIM;
        #pragma unroll
        for (int i = 0; i < 16; i++) xv[i] = (float)xp[lane + 64 * i];
    }

    if (wave == 0 && xb) {
        #pragma unroll
        for (int i = 0; i < 16; i++)
            xb[(size_t)t * DIM + lane + 64 * i] = (bf16_t)xv[i];
    }

    #pragma unroll
    for (int jj = 0; jj < 6; jj++) {
        const int j = wave * 6 + jj;
        const void* gb; int row; bool gf;
        if (j < 8) { gb = w_out; row = j;     gf = gof; }
        else       { gb = w_in;  row = j - 8; gf = gif; }
        float s = 0.f;
        if (gf) {
            const float* gp = (const float*)gb + (size_t)row * DIM;
            #pragma unroll
            for (int i = 0; i < 16; i++) s += xv[i] * gp[lane + 64 * i];
        } else {
            const bf16_t* gp = (const bf16_t*)gb + (size_t)row * DIM;
            #pragma unroll
            for (int i = 0; i < 16; i++) s += xv[i] * (float)gp[lane + 64 * i];
        }
        #pragma unroll
        for (int m = 32; m >= 1; m >>= 1) s += __shfl_xor(s, m, 64);
        if (lane == 0) Ls[j] = s;
    }
    __syncthreads();

    if (tid == 0) {
        const float* logits = Ls;
        float mx = logits[0];
        for (int o = 1; o < 8; o++) mx = fmaxf(mx, logits[o]);
        float p[8];
        for (int o = 0; o < 8; o++) p[o] = __expf(logits[o] - mx);
        int i0 = 0;
        for (int o = 1; o < 8; o++) if (logits[o] > logits[i0]) i0 = o;
        int i1 = (i0 == 0) ? 1 : 0;
        for (int o = 0; o < 8; o++) if (o != i0 && logits[o] > logits[i1]) i1 = o;
        float rsum = p[i0] + p[i1];
        float rw0 = p[i0] / rsum, rw1 = p[i1] / rsum;

        float a0 = logits[8 + i0 * 2], a1 = logits[8 + i0 * 2 + 1];
        int j00 = (a1 > a0) ? 1 : 0;
        float b0 = logits[8 + i1 * 2], b1 = logits[8 + i1 * 2 + 1];
        int j10 = (b1 > b0) ? 1 : 0;

        int   ids[3] = { i0 * 2 + j00, i0 * 2 + (1 - j00), i1 * 2 + j10 };
        float w[3]   = { rw0, rw0, rw1 };

        #pragma unroll
        for (int k = 0; k < 3; k++) {
            selw_out[t * 3 + k] = w[k];
            sel_ids[t * 3 + k]  = ids[k];
        }
    }
}

// ---------------- binning: 16 blocks (1/expert), ballot prefix ----------------
__global__ __launch_bounds__(1024) void bin2_kernel(
    const int* __restrict__ sel_ids,
    int* __restrict__ cnt, int* __restrict__ tok_enc)
{
    const int e = blockIdx.x, tid = threadIdx.x;
    const int wave = tid >> 6, lane = tid & 63;
    __shared__ int wbase[16];

    int my = -1;
    #pragma unroll
    for (int k = 0; k < 3; k++) {
        int id = sel_ids[tid * 3 + k];
        if (id == e) my = tid | (k << 16);
    }
    unsigned long long b = __ballot(my >= 0);
    if (lane == 0) wbase[wave] = __popcll(b);
    __syncthreads();
    if (tid == 0) {
        int s = 0;
        for (int w = 0; w < 16; w++) { int c = wbase[w]; wbase[w] = s; s += c; }
        cnt[e] = s;
    }
    __syncthreads();
    if (my >= 0) {
        int pos = wbase[wave] + __popcll(b & ((1ull << lane) - 1ull));
        if (pos < T_TOK) tok_enc[e * T_TOK + pos] = my;
    }
}

// ================= FULL path: direct-dtype DMA pipeline, 64 KB LDS dbuf, 2 blocks/CU =================

// gate+up -> H : grid (ft=16 x 32f, mt=8 x 128tok, e=16); 8 waves = 4mh x 2fq
template<bool GF, bool UF>
__device__ __forceinline__ void gateup6_body(
    const bf16_t* __restrict__ xb,
    const void* __restrict__ wg, const void* __restrict__ wu,
    const int* __restrict__ cnt, const int* __restrict__ tok_enc,
    bf16_t* __restrict__ H,
    char* Xs, char* Gs, char* Us, int* toks, int* hrow)
{
    const int ft = blockIdx.x, mt = blockIdx.y, e = blockIdx.z;
    int C = cnt[e]; if (C > T_TOK) C = T_TOK; if (C < 0) C = 0;
    if (mt * 128 >= C) return;

    const int tid = threadIdx.x;
    if (tid < 128) {
        int idx = mt * 128 + tid, t = 0, hr = -1;
        if (idx < C) {
            int enc = tok_enc[e * T_TOK + idx];
            int tt = enc & 0xFFFF, kk = (enc >> 16) & 0xFFFF;
            if (tt < T_TOK && kk < 3) { t = tt; hr = tt * 3 + kk; }
        }
        toks[tid] = t; hrow[tid] = hr;
    }
    __syncthreads();

    const int wave = tid >> 6, lane = tid & 63;
    const int mh = wave >> 1, fq = wave & 1;
    const int rsel = lane & 15, kq = lane >> 4;

    constexpr int NC = 16;                        // DIM/64
    constexpr int GSTR = GF ? 8192 : 4096;        // per-chunk W bytes
    constexpr int USTR = UF ? 8192 : 4096;
    constexpr int PG = 2 + (GF ? 2 : 1);          // per-wave DMAs (waves 0-3)
    constexpr int PU = 2 + (UF ? 2 : 1);          // per-wave DMAs (waves 4-7)
    const int wrow0 = e * FF + ft * 32;

    // X: 2 instr/wave -> rows 16w..16w+15
    const bf16_t* px[2];
    #pragma unroll
    for (int j = 0; j < 2; j++) {
        int n = (2 * wave + j) * 64 + lane, r = n >> 3, s = n & 7;
        px[j] = xb + (size_t)toks[r] * DIM + ((s ^ (r & 7)) << 3);
    }
    // W: waves 0-3 stage G, waves 4-7 stage U
    const int wv = wave & 3;
    const void* pw0; const void* pw1 = nullptr;   // up to 2 instr per wave
    char* wdst;
    int woff0, woff1 = 0;
    if (wave < 4) {
        wdst = Gs;
        if constexpr (GF) {
            int n0 = (2 * wv) * 64 + lane, r0 = n0 >> 4, s0 = n0 & 15;
            int n1 = (2 * wv + 1) * 64 + lane, r1 = n1 >> 4, s1 = n1 & 15;
            pw0 = (const float*)wg + (size_t)(wrow0 + r0) * DIM + ((s0 ^ (r0 & 15)) << 2);
            pw1 = (const float*)wg + (size_t)(wrow0 + r1) * DIM + ((s1 ^ (r1 & 15)) << 2);
            woff0 = (2 * wv) * 1024; woff1 = (2 * wv + 1) * 1024;
        } else {
            int n = wv * 64 + lane, r = n >> 3, s = n & 7;
            pw0 = (const bf16_t*)wg + (size_t)(wrow0 + r) * DIM + ((s ^ (r & 7)) << 3);
            woff0 = wv * 1024;
        }
    } else {
        wdst = Us;
        if constexpr (UF) {
            int n0 = (2 * wv) * 64 + lane, r0 = n0 >> 4, s0 = n0 & 15;
            int n1 = (2 * wv + 1) * 64 + lane, r1 = n1 >> 4, s1 = n1 & 15;
            pw0 = (const float*)wu + (size_t)(wrow0 + r0) * DIM + ((s0 ^ (r0 & 15)) << 2);
            pw1 = (const float*)wu + (size_t)(wrow0 + r1) * DIM + ((s1 ^ (r1 & 15)) << 2);
            woff0 = (2 * wv) * 1024; woff1 = (2 * wv + 1) * 1024;
        } else {
            int n = wv * 64 + lane, r = n >> 3, s = n & 7;
            pw0 = (const bf16_t*)wu + (size_t)(wrow0 + r) * DIM + ((s ^ (r & 7)) << 3);
            woff0 = wv * 1024;
        }
    }
    const bool wf = (wave < 4) ? GF : UF;
    const int wstr = (wave < 4) ? GSTR : USTR;

    auto issue = [&](int kc) {
        const int buf = kc & 1;
        gload_lds16(px[0] + kc * 64, Xs + buf * 16384 + (2 * wave) * 1024);
        gload_lds16(px[1] + kc * 64, Xs + buf * 16384 + (2 * wave + 1) * 1024);
        if (wf) {
            gload_lds16((const float*)pw0 + kc * 64, wdst + buf * wstr + woff0);
            gload_lds16((const float*)pw1 + kc * 64, wdst + buf * wstr + woff1);
        } else {
            gload_lds16((const bf16_t*)pw0 + kc * 64, wdst + buf * wstr + woff0);
        }
    };

    floatx4 ag[2], au[2];
    #pragma unroll
    for (int ms = 0; ms < 2; ms++) { ag[ms] = (floatx4){0,0,0,0}; au[ms] = (floatx4){0,0,0,0}; }

    issue(0);

    #pragma unroll
    for (int kc = 0; kc < NC; kc++) {
        if (kc + 1 < NC) {
            issue(kc + 1);
            if (wave < 4) waitv<PG>(); else waitv<PU>();
        } else {
            waitv<0>();
        }
        barrier_raw();
        __builtin_amdgcn_sched_barrier(0);

        const char* X = Xs + (kc & 1) * 16384;
        const char* G = Gs + (kc & 1) * GSTR;
        const char* U = Us + (kc & 1) * USTR;
        #pragma unroll
        for (int i = 0; i < 2; i++) {
            const int q = i * 4 + kq;
            bf16x8 a0 = rdT(X, mh * 32 + rsel, q);
            bf16x8 a1 = rdT(X, mh * 32 + 16 + rsel, q);
            bf16x8 bg = rdW<GF>(G, fq * 16 + rsel, q);
            bf16x8 bu = rdW<UF>(U, fq * 16 + rsel, q);
            ag[0] = __builtin_amdgcn_mfma_f32_16x16x32_bf16(a0, bg, ag[0], 0, 0, 0);
            au[0] = __builtin_amdgcn_mfma_f32_16x16x32_bf16(a0, bu, au[0], 0, 0, 0);
            ag[1] = __builtin_amdgcn_mfma_f32_16x16x32_bf16(a1, bg, ag[1], 0, 0, 0);
            au[1] = __builtin_amdgcn_mfma_f32_16x16x32_bf16(a1, bu, au[1], 0, 0, 0);
        }
        barrier_raw();
    }

    const int f = ft * 32 + fq * 16 + rsel;
    #pragma unroll
    for (int ms = 0; ms < 2; ms++)
        #pragma unroll
        for (int r = 0; r < 4; r++) {
            int m = mh * 32 + ms * 16 + kq * 4 + r;
            int hr = hrow[m];
            if (hr >= 0)
                H[(size_t)hr * FF + f] = (bf16_t)swiglu(ag[ms][r], au[ms][r]);
        }
}

__global__ __launch_bounds__(512, 4) void gateup6_kernel(
    const bf16_t* __restrict__ xb,
    const void* __restrict__ wg, const void* __restrict__ wu,
    const int* __restrict__ flags, const int* __restrict__ cnt,
    const int* __restrict__ tok_enc, bf16_t* __restrict__ H)
{
    __shared__ __align__(16) char Xs[2 * 16384];   // 32 KB
    __shared__ __align__(16) char Gs[2 * 8192];    // 16 KB (fp32 worst case)
    __shared__ __align__(16) char Us[2 * 8192];    // 16 KB
    __shared__ int toks[128];
    __shared__ int hrow[128];
    const bool gf = flags[3] != 0, uf = flags[4] != 0;
    if (gf) {
        if (uf) gateup6_body<true,  true >(xb, wg, wu, cnt, tok_enc, H, Xs, Gs, Us, toks, hrow);
        else    gateup6_body<true,  false>(xb, wg, wu, cnt, tok_enc, H, Xs, Gs, Us, toks, hrow);
    } else {
        if (uf) gateup6_body<false, true >(xb, wg, wu, cnt, tok_enc, H, Xs, Gs, Us, toks, hrow);
        else    gateup6_body<false, false>(xb, wg, wu, cnt, tok_enc, H, Xs, Gs, Us, toks, hrow);
    }
}

// down-proj -> Y : grid (dt=16 x 64d, mt=8 x 128tok, e=16); 8 waves = 4mh x 2dq
template<bool DF>
__device__ __forceinline__ void down6_body(
    const void* __restrict__ wd,
    const int* __restrict__ cnt, const int* __restrict__ tok_enc,
    const bf16_t* __restrict__ H, float* __restrict__ Y,
    char* Hs, char* Ds, int* hsrc, int* hdst)
{
    const int dt = blockIdx.x, mt = blockIdx.y, e = blockIdx.z;
    int C = cnt[e]; if (C > T_TOK) C = T_TOK; if (C < 0) C = 0;
    if (mt * 128 >= C) return;

    const int tid = threadIdx.x;
    if (tid < 128) {
        int idx = mt * 128 + tid, hr = -1;
        if (idx < C) {
            int enc = tok_enc[e * T_TOK + idx];
            int tt = enc & 0xFFFF, kk = (enc >> 16) & 0xFFFF;
            if (tt < T_TOK && kk < 3) hr = tt * 3 + kk;
        }
        hsrc[tid] = (hr >= 0) ? hr : 0;
        hdst[tid] = hr;
    }
    __syncthreads();

    const int wave = tid >> 6, lane = tid & 63;
    const int mh = wave >> 1, dq = wave & 1;
    const int rsel = lane & 15, kq = lane >> 4;

    constexpr int NC = 8;                          // FF/64
    constexpr int DSTR = DF ? 16384 : 8192;
    constexpr int PER = 2 + (DF ? 2 : 1);
    const int wrow0 = e * DIM + dt * 64;

    const bf16_t* ph[2];
    #pragma unroll
    for (int j = 0; j < 2; j++) {
        int n = (2 * wave + j) * 64 + lane, r = n >> 3, s = n & 7;
        ph[j] = H + (size_t)hsrc[r] * FF + ((s ^ (r & 7)) << 3);
    }
    const void* pd0; const void* pd1 = nullptr;
    int doff0, doff1 = 0;
    if constexpr (DF) {
        int n0 = (2 * wave) * 64 + lane, r0 = n0 >> 4, s0 = n0 & 15;
        int n1 = (2 * wave + 1) * 64 + lane, r1 = n1 >> 4, s1 = n1 & 15;
        pd0 = (const float*)wd + (size_t)(wrow0 + r0) * FF + ((s0 ^ (r0 & 15)) << 2);
        pd1 = (const float*)wd + (size_t)(wrow0 + r1) * FF + ((s1 ^ (r1 & 15)) << 2);
        doff0 = (2 * wave) * 1024; doff1 = (2 * wave + 1) * 1024;
    } else {
        int n = wave * 64 + lane, r = n >> 3, s = n & 7;
        pd0 = (const bf16_t*)wd + (size_t)(wrow0 + r) * FF + ((s ^ (r & 7)) << 3);
        doff0 = wave * 1024;
    }

    auto issue = [&](int kc) {
        const int buf = kc & 1;
        gload_lds16(ph[0] + kc * 64, Hs + buf * 16384 + (2 * wave) * 1024);
        gload_lds16(ph[1] + kc * 64, Hs + buf * 16384 + (2 * wave + 1) * 1024);
        if constexpr (DF) {
            gload_lds16((const float*)pd0 + kc * 64, Ds + buf * DSTR + doff0);
            gload_lds16((const float*)pd1 + kc * 64, Ds + buf * DSTR + doff1);
        } else {
            gload_lds16((const bf16_t*)pd0 + kc * 64, Ds + buf * DSTR + doff0);
        }
    };

    floatx4 acc[2][2];
    #pragma unroll
    for (int ms = 0; ms < 2; ms++)
        #pragma unroll
        for (int nt = 0; nt < 2; nt++) acc[ms][nt] = (floatx4){0,0,0,0};

    issue(0);

    #pragma unroll
    for (int kc = 0; kc < NC; kc++) {
        if (kc + 1 < NC) { issue(kc + 1); waitv<PER>(); }
        else             { waitv<0>(); }
        barrier_raw();
        __builtin_amdgcn_sched_barrier(0);

        const char* Hb = Hs + (kc & 1) * 16384;
        const char* Db = Ds + (kc & 1) * DSTR;
        #pragma unroll
        for (int i = 0; i < 2; i++) {
            const int q = i * 4 + kq;
            bf16x8 a0 = rdT(Hb, mh * 32 + rsel, q);
            bf16x8 a1 = rdT(Hb, mh * 32 + 16 + rsel, q);
            bf16x8 b0 = rdW<DF>(Db, dq * 32 + rsel, q);
            bf16x8 b1 = rdW<DF>(Db, dq * 32 + 16 + rsel, q);
            acc[0][0] = __builtin_amdgcn_mfma_f32_16x16x32_bf16(a0, b0, acc[0][0], 0, 0, 0);
            acc[0][1] = __builtin_amdgcn_mfma_f32_16x16x32_bf16(a0, b1, acc[0][1], 0, 0, 0);
            acc[1][0] = __builtin_amdgcn_mfma_f32_16x16x32_bf16(a1, b0, acc[1][0], 0, 0, 0);
            acc[1][1] = __builtin_amdgcn_mfma_f32_16x16x32_bf16(a1, b1, acc[1][1], 0, 0, 0);
        }
        barrier_raw();
    }

    #pragma unroll
    for (int ms = 0; ms < 2; ms++)
        #pragma unroll
        for (int nt = 0; nt < 2; nt++)
            #pragma unroll
            for (int r = 0; r < 4; r++) {
                int m = mh * 32 + ms * 16 + kq * 4 + r;
                int hr = hdst[m];
                if (hr >= 0)
                    Y[(size_t)hr * DIM + dt * 64 + dq * 32 + nt * 16 + rsel] = acc[ms][nt][r];
            }
}

__global__ __launch_bounds__(512, 4) void down6_kernel(
    const void* __restrict__ wd,
    const int* __restrict__ flags, const int* __restrict__ cnt,
    const int* __restrict__ tok_enc,
    const bf16_t* __restrict__ H, float* __restrict__ Y)
{
    __shared__ __align__(16) char Hs[2 * 16384];   // 32 KB
    __shared__ __align__(16) char Ds[2 * 16384];   // 32 KB (fp32 worst case)
    __shared__ int hsrc[128];
    __shared__ int hdst[128];
    const bool df = flags[5] != 0;
    if (df) down6_body<true >(wd, cnt, tok_enc, H, Y, Hs, Ds, hsrc, hdst);
    else    down6_body<false>(wd, cnt, tok_enc, H, Y, Hs, Ds, hsrc, hdst);
}

// weighted combine: out[t][d] = sum_k selw[t,k] * Y[t*3+k][d]
__global__ __launch_bounds__(256) void combine_kernel(
    const float* __restrict__ Y, const float* __restrict__ selw,
    float* __restrict__ outp)
{
    int idx = blockIdx.x * 256 + threadIdx.x;
    int t = idx >> 8;
    int d = (idx & 255) * 4;
    float w0 = selw[t * 3 + 0], w1 = selw[t * 3 + 1], w2 = selw[t * 3 + 2];
    float4 y0 = *(const float4*)(Y + (size_t)(t * 3 + 0) * DIM + d);
    float4 y1 = *(const float4*)(Y + (size_t)(t * 3 + 1) * DIM + d);
    float4 y2 = *(const float4*)(Y + (size_t)(t * 3 + 2) * DIM + d);
    float4 o;
    o.x = w0 * y0.x + w1 * y1.x + w2 * y2.x;
    o.y = w0 * y0.y + w1 * y1.y + w2 * y2.y;
    o.z = w0 * y0.z + w1 * y1.z + w2 * y2.z;
    o.w = w0 * y0.w + w1 * y1.w + w2 * y2.w;
    *(float4*)(outp + (size_t)t * DIM + d) = o;
}

// ---------------- fallback fused FFN ----------------
__global__ __launch_bounds__(256) void ffn_kernel(
    const void* __restrict__ x,
    const void* __restrict__ wg, const void* __restrict__ wu, const void* __restrict__ wd,
    const int* __restrict__ flags, const int* __restrict__ cnt, const int* __restrict__ tok_enc,
    const float* __restrict__ selw, float* __restrict__ outp)
{
    const int e = blockIdx.x, tile = blockIdx.y;
    int C = cnt[e]; if (C > T_TOK) C = T_TOK; if (C < 0) C = 0;
    if (tile * 16 >= C) return;
    const bool xf = flags[0] != 0, gf = flags[3] != 0, uf = flags[4] != 0, df = flags[5] != 0;

    __shared__ __align__(16) bf16_t Xs[16][1032];
    __shared__ __align__(16) bf16_t Hs[16][520];
    __shared__ int toks[16];
    __shared__ float wts[16];
    const int tid = threadIdx.x;
    if (tid < 16) {
        int idx = tile * 16 + tid, t = -1; float w = 0.f;
        if (idx < C) {
            int enc = tok_enc[e * T_TOK + idx];
            int tt = enc & 0xFFFF, kk = (enc >> 16) & 0xFFFF;
            if (tt < T_TOK && kk < 3) { t = tt; w = selw[tt * 3 + kk]; }
        }
        toks[tid] = t; wts[tid] = w;
    }
    __syncthreads();
    {
        int row = tid >> 4, chunk = tid & 15;
        int t = toks[row];
        bf16x8* dst = (bf16x8*)&Xs[row][chunk * 64];
        if (t >= 0) {
            #pragma unroll
            for (int i = 0; i < 8; i++)
                dst[i] = loadB8r(x, (size_t)t * DIM + chunk * 64 + i * 8, xf);
        } else {
            bf16x8 z;
            #pragma unroll
            for (int kz = 0; kz < 8; kz++) z[kz] = (bf16_t)0.0f;
            #pragma unroll
            for (int i = 0; i < 8; i++) dst[i] = z;
        }
    }
    __syncthreads();

    const int wave = tid >> 6, lane = tid & 63;
    const int rsel = lane & 15, kq = lane >> 4;
    const size_t eoffF = (size_t)e * FF * DIM;
    for (int nt = 0; nt < 8; nt++) {
        const int f0 = wave * 128 + nt * 16;
        const size_t boff = eoffF + (size_t)(f0 + rsel) * DIM + kq * 8;
        const bf16_t* ap = &Xs[rsel][kq * 8];
        floatx4 accg = {0.f,0.f,0.f,0.f};
        floatx4 accu = {0.f,0.f,0.f,0.f};
        for (int k0 = 0; k0 < DIM; k0 += 32) {
            bf16x8 a  = *(const bf16x8*)(ap + k0);
            bf16x8 bg = loadB8r(wg, boff + k0, gf);
            bf16x8 bu = loadB8r(wu, boff + k0, uf);
            accg = __builtin_amdgcn_mfma_f32_16x16x32_bf16(a, bg, accg, 0, 0, 0);
            accu = __builtin_amdgcn_mfma_f32_16x16x32_bf16(a, bu, accu, 0, 0, 0);
        }
        #pragma unroll
        for (int r = 0; r < 4; r++)
            Hs[kq * 4 + r][f0 + rsel] = (bf16_t)swiglu(accg[r], accu[r]);
    }
    __syncthreads();
    const size_t eoffD = (size_t)e * DIM * FF;
    for (int nt = 0; nt < 16; nt++) {
        const int d0 = wave * 256 + nt * 16;
        const size_t boff = eoffD + (size_t)(d0 + rsel) * FF + kq * 8;
        const bf16_t* ap = &Hs[rsel][kq * 8];
        floatx4 acc = {0.f,0.f,0.f,0.f};
        for (int k0 = 0; k0 < FF; k0 += 32) {
            bf16x8 a = *(const bf16x8*)(ap + k0);
            bf16x8 b = loadB8r(wd, boff + k0, df);
            acc = __builtin_amdgcn_mfma_f32_16x16x32_bf16(a, b, acc, 0, 0, 0);
        }
        #pragma unroll
        for (int r = 0; r < 4; r++) {
            int m = kq * 4 + r, t = toks[m];
            if (t >= 0) atomicAdd(outp + (size_t)t * DIM + d0 + rsel, acc[r] * wts[m]);
        }
    }
}

extern "C" void kernel_launch(void* const* d_in, const int* in_sizes, int n_in,
                              void* d_out, int out_size, void* d_ws, size_t ws_size,
                              hipStream_t stream)
{
    const void* x     = d_in[0];
    const void* w_out = d_in[1];
    const void* w_in  = d_in[2];
    const void* wg    = d_in[3];
    const void* wu    = d_in[4];
    const void* wd    = d_in[5];
    float* out  = (float*)d_out;
    float* selw = out + (size_t)T_TOK * DIM;

    char* ws = (char*)d_ws;
    int*    flags = (int*)(ws + FLAG_OFF);
    int*    cnt   = (int*)(ws + CNT_OFF);
    int*    tok   = (int*)(ws + TOK_OFF);
    int*    sel   = (int*)(ws + SEL_OFF);
    bf16_t* H     = (bf16_t*)(ws + H_OFF);
    bf16_t* xbf   = (bf16_t*)(ws + XBF_OFF);
    float*  Y     = (float*)(ws + Y_OFF);

    const bool full = ws_size >= (size_t)WS_FULL;

    if (!full)
        hipMemsetAsync(out, 0, (size_t)T_TOK * DIM * sizeof(float), stream);

    detect_kernel<<<dim3(6), dim3(64), 0, stream>>>(x, w_out, w_in, wg, wu, wd, flags);

    router4_kernel<<<dim3(T_TOK), dim3(256), 0, stream>>>(
        x, w_out, w_in, selw, flags, sel, full ? xbf : (bf16_t*)nullptr);

    bin2_kernel<<<dim3(NEXP), dim3(1024), 0, stream>>>(sel, cnt, tok);

    if (full) {
        gateup6_kernel<<<dim3(16, 8, 16), dim3(512), 0, stream>>>(
            xbf, wg, wu, flags, cnt, tok, H);
        down6_kernel<<<dim3(16, 8, 16), dim3(512), 0, stream>>>(
            wd, flags, cnt, tok, H, Y);
        combine_kernel<<<dim3(T_TOK * DIM / 1024), dim3(256), 0, stream>>>(Y, selw, out);
    } else {
        ffn_kernel<<<dim3(NEXP, 64), dim3(256), 0, stream>>>(
            x, wg, wu, wd, flags, cnt, tok, selw, out);
    }
}